// Round 1
// baseline (3120.715 us; speedup 1.0000x reference)
//
#include <hip/hip_runtime.h>

#define H 64
#define NODES_PER_BLK 16

__device__ __forceinline__ float silu_f(float v) { return v / (1.0f + __expf(-v)); }

// ---------------- Embedding: x = silu(concat(onehot, pos) @ embW + embB) ----------------
// block = 256 threads, 16 nodes/block. Stage W [121][64] and 16 input rows in LDS.
__global__ __launch_bounds__(256) void k_embed(
    const float* __restrict__ oneh, const float* __restrict__ pos,
    const float* __restrict__ W, const float* __restrict__ bvec,
    float* __restrict__ x, float* __restrict__ x0, int N)
{
    __shared__ float Wl[121 * 64];
    __shared__ float xin[NODES_PER_BLK * 121];
    const int t = threadIdx.x;
    for (int i = t; i < 121 * 64; i += 256) Wl[i] = W[i];
    const int n0 = blockIdx.x * NODES_PER_BLK;
    for (int i = t; i < NODES_PER_BLK * 121; i += 256) {
        int node = n0 + i / 121;
        int k = i % 121;
        float v = 0.f;
        if (node < N) v = (k < 118) ? oneh[(size_t)node * 118 + k] : pos[(size_t)node * 3 + (k - 118)];
        xin[i] = v;
    }
    __syncthreads();
    const int h = t & 63, ni = t >> 6;
    const float bb = bvec[h];
    #pragma unroll
    for (int j = 0; j < 4; ++j) {
        int node = ni + 4 * j;          // local node idx 0..15
        int gnode = n0 + node;
        if (gnode >= N) continue;
        float acc = bb;
        #pragma unroll 11
        for (int k = 0; k < 121; ++k)
            acc = fmaf(xin[node * 121 + k], Wl[k * 64 + h], acc);
        float v = silu_f(acc);
        x[(size_t)gnode * H + h] = v;
        x0[(size_t)gnode * H + h] = v;
    }
}

// ---------------- Per-layer node transform: A = x@Wt + ib ; B = x@Wb ----------------
// Wg is interact_W[l] laid out [128][64]; rows 0..63 -> A (src side), rows 64..127 -> B (dst side).
__global__ __launch_bounds__(256) void k_interact(
    const float* __restrict__ x, const float* __restrict__ Wg, const float* __restrict__ ib,
    float* __restrict__ A, float* __restrict__ B, int N)
{
    __shared__ float Wl[128 * 64];
    __shared__ float xl[NODES_PER_BLK * 64];
    const int t = threadIdx.x;
    for (int i = t; i < 128 * 64; i += 256) Wl[i] = Wg[i];
    const int n0 = blockIdx.x * NODES_PER_BLK;
    for (int i = t; i < NODES_PER_BLK * 64; i += 256) {
        int g = n0 * 64 + i;
        xl[i] = (g < N * 64) ? x[g] : 0.f;
    }
    __syncthreads();
    const int h = t & 63, ni = t >> 6;
    const float bias = ib[h];
    #pragma unroll
    for (int j = 0; j < 4; ++j) {
        int node = ni + 4 * j;
        int gnode = n0 + node;
        if (gnode >= N) continue;
        float acca = bias, accb = 0.f;
        #pragma unroll 8
        for (int k = 0; k < 64; ++k) {
            float xv = xl[node * 64 + k];
            acca = fmaf(xv, Wl[k * 64 + h], acca);
            accb = fmaf(xv, Wl[(64 + k) * 64 + h], accb);
        }
        A[(size_t)gnode * H + h] = acca;
        B[(size_t)gnode * H + h] = accb;
    }
}

// ---------------- Edge pass: m[src] += silu(A[src] + B[dst]) ----------------
// Task = (edge, quarter-row of 4 floats). float4 loads, 4 scalar atomics.
__global__ __launch_bounds__(256) void k_edge(
    const int* __restrict__ src, const int* __restrict__ dst,
    const float* __restrict__ A, const float* __restrict__ B,
    float* __restrict__ m, int E)
{
    const int stride = gridDim.x * blockDim.x;
    const int total = E * 16;
    for (int i = blockIdx.x * blockDim.x + threadIdx.x; i < total; i += stride) {
        int e = i >> 4;
        int q = i & 15;
        int s = src[e];
        int d = dst[e];
        const float4 av = *reinterpret_cast<const float4*>(A + (size_t)s * H + q * 4);
        const float4 bv = *reinterpret_cast<const float4*>(B + (size_t)d * H + q * 4);
        float4 v;
        v.x = silu_f(av.x + bv.x);
        v.y = silu_f(av.y + bv.y);
        v.z = silu_f(av.z + bv.z);
        v.w = silu_f(av.w + bv.w);
        float* mp = m + (size_t)s * H + q * 4;
        atomicAdd(mp + 0, v.x);
        atomicAdd(mp + 1, v.y);
        atomicAdd(mp + 2, v.z);
        atomicAdd(mp + 3, v.w);
    }
}

// ---------------- Update: x += silu((x + 0.25*m) @ uW + ub) ----------------
__global__ __launch_bounds__(256) void k_update(
    float* __restrict__ x, const float* __restrict__ m,
    const float* __restrict__ Wg, const float* __restrict__ ub, int N)
{
    __shared__ float Wl[64 * 64];
    __shared__ float xl[NODES_PER_BLK * 64];
    __shared__ float ml[NODES_PER_BLK * 64];
    const int t = threadIdx.x;
    for (int i = t; i < 64 * 64; i += 256) Wl[i] = Wg[i];
    const int n0 = blockIdx.x * NODES_PER_BLK;
    for (int i = t; i < NODES_PER_BLK * 64; i += 256) {
        int g = n0 * 64 + i;
        xl[i] = (g < N * 64) ? x[g] : 0.f;
        ml[i] = (g < N * 64) ? m[g] : 0.f;
    }
    __syncthreads();
    const int h = t & 63, ni = t >> 6;
    const float bias = ub[h];
    #pragma unroll
    for (int j = 0; j < 4; ++j) {
        int node = ni + 4 * j;
        int gnode = n0 + node;
        if (gnode >= N) continue;
        float acc = bias;
        #pragma unroll 8
        for (int k = 0; k < 64; ++k) {
            float tv = fmaf(0.25f, ml[node * 64 + k], xl[node * 64 + k]);  // inv_sqrt(16) = 0.25
            acc = fmaf(tv, Wl[k * 64 + h], acc);
        }
        x[(size_t)gnode * H + h] = xl[node * 64 + h] + silu_f(acc);
    }
}

// ---------------- Output: out = (x + x0) @ outW + outB ----------------
// 4 nodes per block of 256; 64 lanes per node, shuffle-reduce 3 dot products.
__global__ __launch_bounds__(256) void k_out(
    const float* __restrict__ x, const float* __restrict__ x0,
    const float* __restrict__ W, const float* __restrict__ ob,
    float* __restrict__ out, int N)
{
    const int t = threadIdx.x;
    const int h = t & 63, ni = t >> 6;
    const int node = blockIdx.x * 4 + ni;
    if (node >= N) return;
    float v = x[(size_t)node * H + h] + x0[(size_t)node * H + h];
    float p0 = v * W[h * 3 + 0];
    float p1 = v * W[h * 3 + 1];
    float p2 = v * W[h * 3 + 2];
    #pragma unroll
    for (int off = 32; off; off >>= 1) {
        p0 += __shfl_down(p0, off);
        p1 += __shfl_down(p1, off);
        p2 += __shfl_down(p2, off);
    }
    if (h == 0) {
        out[node * 3 + 0] = p0 + ob[0];
        out[node * 3 + 1] = p1 + ob[1];
        out[node * 3 + 2] = p2 + ob[2];
    }
}

extern "C" void kernel_launch(void* const* d_in, const int* in_sizes, int n_in,
                              void* d_out, int out_size, void* d_ws, size_t ws_size,
                              hipStream_t stream)
{
    const float* oneh = (const float*)d_in[0];
    const float* pos  = (const float*)d_in[1];
    const int*   ei   = (const int*)d_in[2];
    const float* embW = (const float*)d_in[3];
    const float* embB = (const float*)d_in[4];
    const float* iW   = (const float*)d_in[5];   // [4][128][64]
    const float* iB   = (const float*)d_in[6];   // [4][64]
    const float* uW   = (const float*)d_in[7];   // [4][64][64]
    const float* uB   = (const float*)d_in[8];   // [4][64]
    const float* oW   = (const float*)d_in[9];   // [64][3]
    const float* oB   = (const float*)d_in[10];  // [3]

    const int N = in_sizes[0] / 118;
    const int E = in_sizes[2] / 2;

    float* ws = (float*)d_ws;
    const size_t NH = (size_t)N * H;
    float* x  = ws;
    float* x0 = ws + NH;
    float* A  = ws + 2 * NH;
    float* B  = ws + 3 * NH;
    float* m  = ws + 4 * NH;

    const int nb = (N + NODES_PER_BLK - 1) / NODES_PER_BLK;

    k_embed<<<nb, 256, 0, stream>>>(oneh, pos, embW, embB, x, x0, N);

    for (int l = 0; l < 4; ++l) {
        k_interact<<<nb, 256, 0, stream>>>(x, iW + (size_t)l * 128 * 64, iB + l * 64, A, B, N);
        hipMemsetAsync(m, 0, NH * sizeof(float), stream);
        k_edge<<<2048, 256, 0, stream>>>(ei, ei + E, A, B, m, E);
        k_update<<<nb, 256, 0, stream>>>(x, m, uW + (size_t)l * 64 * 64, uB + l * 64, N);
    }

    k_out<<<(N + 3) / 4, 256, 0, stream>>>(x, x0, oW, oB, (float*)d_out, N);
}

// Round 2
// 882.015 us; speedup vs baseline: 3.5382x; 3.5382x over previous
//
#include <hip/hip_runtime.h>

#define H 64
#define NODES_PER_BLK 16

__device__ __forceinline__ float silu_f(float v) { return v / (1.0f + __expf(-v)); }

// ---------------- CSR build ----------------
__global__ __launch_bounds__(256) void k_hist(const int* __restrict__ src, int* __restrict__ cnt, int E)
{
    int stride = gridDim.x * blockDim.x;
    for (int e = blockIdx.x * blockDim.x + threadIdx.x; e < E; e += stride)
        atomicAdd(&cnt[src[e]], 1);
}

// Single-block exclusive scan over cnt[0..n) -> rp[0..n], also copies to cur.
__global__ __launch_bounds__(1024) void k_scan(const int* __restrict__ cnt,
                                               int* __restrict__ rp, int* __restrict__ cur, int n)
{
    __shared__ int part[1024];
    const int t = threadIdx.x;
    const int chunk = (n + 1023) / 1024;
    const int b = t * chunk;
    const int e = min(b + chunk, n);
    int s = 0;
    for (int i = b; i < e; ++i) s += cnt[i];
    part[t] = s;
    __syncthreads();
    for (int off = 1; off < 1024; off <<= 1) {
        int v = (t >= off) ? part[t - off] : 0;
        __syncthreads();
        part[t] += v;
        __syncthreads();
    }
    int run = (t > 0) ? part[t - 1] : 0;   // exclusive prefix of this thread's chunk
    for (int i = b; i < e; ++i) {
        rp[i] = run;
        cur[i] = run;
        run += cnt[i];
    }
    if (t == 1023) rp[n] = part[1023];
}

__global__ __launch_bounds__(256) void k_scatter(const int* __restrict__ src, const int* __restrict__ dst,
                                                 int* __restrict__ cur, int* __restrict__ col, int E)
{
    int stride = gridDim.x * blockDim.x;
    for (int e = blockIdx.x * blockDim.x + threadIdx.x; e < E; e += stride) {
        int s = src[e];
        int pos = atomicAdd(&cur[s], 1);
        col[pos] = dst[e];
    }
}

// ---------------- Embedding: x = silu(concat(onehot, pos) @ embW + embB) ----------------
__global__ __launch_bounds__(256) void k_embed(
    const float* __restrict__ oneh, const float* __restrict__ pos,
    const float* __restrict__ W, const float* __restrict__ bvec,
    float* __restrict__ x, float* __restrict__ x0, int N)
{
    __shared__ float Wl[121 * 64];
    __shared__ float xin[NODES_PER_BLK * 121];
    const int t = threadIdx.x;
    for (int i = t; i < 121 * 64; i += 256) Wl[i] = W[i];
    const int n0 = blockIdx.x * NODES_PER_BLK;
    for (int i = t; i < NODES_PER_BLK * 121; i += 256) {
        int node = n0 + i / 121;
        int k = i % 121;
        float v = 0.f;
        if (node < N) v = (k < 118) ? oneh[(size_t)node * 118 + k] : pos[(size_t)node * 3 + (k - 118)];
        xin[i] = v;
    }
    __syncthreads();
    const int h = t & 63, ni = t >> 6;
    const float bb = bvec[h];
    #pragma unroll
    for (int j = 0; j < 4; ++j) {
        int node = ni + 4 * j;
        int gnode = n0 + node;
        if (gnode >= N) continue;
        float acc = bb;
        #pragma unroll 11
        for (int k = 0; k < 121; ++k)
            acc = fmaf(xin[node * 121 + k], Wl[k * 64 + h], acc);
        float v = silu_f(acc);
        x[(size_t)gnode * H + h] = v;
        x0[(size_t)gnode * H + h] = v;
    }
}

// ---------------- Per-layer node transform: A = x@Wt + ib ; B = x@Wb ----------------
__global__ __launch_bounds__(256) void k_interact(
    const float* __restrict__ x, const float* __restrict__ Wg, const float* __restrict__ ib,
    float* __restrict__ A, float* __restrict__ B, int N)
{
    __shared__ float Wl[128 * 64];
    __shared__ float xl[NODES_PER_BLK * 64];
    const int t = threadIdx.x;
    for (int i = t; i < 128 * 64; i += 256) Wl[i] = Wg[i];
    const int n0 = blockIdx.x * NODES_PER_BLK;
    for (int i = t; i < NODES_PER_BLK * 64; i += 256) {
        int g = n0 * 64 + i;
        xl[i] = (g < N * 64) ? x[g] : 0.f;
    }
    __syncthreads();
    const int h = t & 63, ni = t >> 6;
    const float bias = ib[h];
    #pragma unroll
    for (int j = 0; j < 4; ++j) {
        int node = ni + 4 * j;
        int gnode = n0 + node;
        if (gnode >= N) continue;
        float acca = bias, accb = 0.f;
        #pragma unroll 8
        for (int k = 0; k < 64; ++k) {
            float xv = xl[node * 64 + k];
            acca = fmaf(xv, Wl[k * 64 + h], acca);
            accb = fmaf(xv, Wl[(64 + k) * 64 + h], accb);
        }
        A[(size_t)gnode * H + h] = acca;
        B[(size_t)gnode * H + h] = accb;
    }
}

// ---------------- Edge pass (CSR, no atomics): m[i][h] = sum_j silu(A[i][h] + B[col[j]][h]) ----
__global__ __launch_bounds__(256) void k_edge_csr(
    const int* __restrict__ rp, const int* __restrict__ col,
    const float* __restrict__ A, const float* __restrict__ B,
    float* __restrict__ m, int N)
{
    const int wid = (blockIdx.x * 256 + threadIdx.x) >> 6;  // one wave per node
    const int h = threadIdx.x & 63;
    if (wid >= N) return;
    const float a = A[(size_t)wid * H + h];
    const int beg = rp[wid], end = rp[wid + 1];
    float acc = 0.f;
    for (int j = beg; j < end; ++j) {
        int d = col[j];
        acc += silu_f(a + B[(size_t)d * H + h]);
    }
    m[(size_t)wid * H + h] = acc;
}

// ---------------- Update: x += silu((x + 0.25*m) @ uW + ub) ----------------
__global__ __launch_bounds__(256) void k_update(
    float* __restrict__ x, const float* __restrict__ m,
    const float* __restrict__ Wg, const float* __restrict__ ub, int N)
{
    __shared__ float Wl[64 * 64];
    __shared__ float xl[NODES_PER_BLK * 64];
    __shared__ float ml[NODES_PER_BLK * 64];
    const int t = threadIdx.x;
    for (int i = t; i < 64 * 64; i += 256) Wl[i] = Wg[i];
    const int n0 = blockIdx.x * NODES_PER_BLK;
    for (int i = t; i < NODES_PER_BLK * 64; i += 256) {
        int g = n0 * 64 + i;
        xl[i] = (g < N * 64) ? x[g] : 0.f;
        ml[i] = (g < N * 64) ? m[g] : 0.f;
    }
    __syncthreads();
    const int h = t & 63, ni = t >> 6;
    const float bias = ub[h];
    #pragma unroll
    for (int j = 0; j < 4; ++j) {
        int node = ni + 4 * j;
        int gnode = n0 + node;
        if (gnode >= N) continue;
        float acc = bias;
        #pragma unroll 8
        for (int k = 0; k < 64; ++k) {
            float tv = fmaf(0.25f, ml[node * 64 + k], xl[node * 64 + k]);  // 1/sqrt(16)
            acc = fmaf(tv, Wl[k * 64 + h], acc);
        }
        x[(size_t)gnode * H + h] = xl[node * 64 + h] + silu_f(acc);
    }
}

// ---------------- Output: out = (x + x0) @ outW + outB ----------------
__global__ __launch_bounds__(256) void k_out(
    const float* __restrict__ x, const float* __restrict__ x0,
    const float* __restrict__ W, const float* __restrict__ ob,
    float* __restrict__ out, int N)
{
    const int t = threadIdx.x;
    const int h = t & 63, ni = t >> 6;
    const int node = blockIdx.x * 4 + ni;
    if (node >= N) return;
    float v = x[(size_t)node * H + h] + x0[(size_t)node * H + h];
    float p0 = v * W[h * 3 + 0];
    float p1 = v * W[h * 3 + 1];
    float p2 = v * W[h * 3 + 2];
    #pragma unroll
    for (int off = 32; off; off >>= 1) {
        p0 += __shfl_down(p0, off);
        p1 += __shfl_down(p1, off);
        p2 += __shfl_down(p2, off);
    }
    if (h == 0) {
        out[node * 3 + 0] = p0 + ob[0];
        out[node * 3 + 1] = p1 + ob[1];
        out[node * 3 + 2] = p2 + ob[2];
    }
}

extern "C" void kernel_launch(void* const* d_in, const int* in_sizes, int n_in,
                              void* d_out, int out_size, void* d_ws, size_t ws_size,
                              hipStream_t stream)
{
    const float* oneh = (const float*)d_in[0];
    const float* pos  = (const float*)d_in[1];
    const int*   ei   = (const int*)d_in[2];
    const float* embW = (const float*)d_in[3];
    const float* embB = (const float*)d_in[4];
    const float* iW   = (const float*)d_in[5];   // [4][128][64]
    const float* iB   = (const float*)d_in[6];   // [4][64]
    const float* uW   = (const float*)d_in[7];   // [4][64][64]
    const float* uB   = (const float*)d_in[8];   // [4][64]
    const float* oW   = (const float*)d_in[9];   // [64][3]
    const float* oB   = (const float*)d_in[10];  // [3]

    const int N = in_sizes[0] / 118;
    const int E = in_sizes[2] / 2;
    const int* src = ei;
    const int* dst = ei + E;

    float* ws = (float*)d_ws;
    const size_t NH = (size_t)N * H;
    float* x  = ws;
    float* x0 = ws + NH;
    float* A  = ws + 2 * NH;
    float* B  = ws + 3 * NH;
    float* m  = ws + 4 * NH;
    int* ibase = (int*)(ws + 5 * NH);
    int* cnt   = ibase;               // N
    int* cur   = ibase + N;           // N
    int* rp    = ibase + 2 * N;       // N+1
    int* col   = ibase + 3 * N + 1;   // E

    const int nb = (N + NODES_PER_BLK - 1) / NODES_PER_BLK;

    // CSR build (once per call; amortized over 4 layers)
    hipMemsetAsync(cnt, 0, (size_t)N * sizeof(int), stream);
    k_hist<<<1024, 256, 0, stream>>>(src, cnt, E);
    k_scan<<<1, 1024, 0, stream>>>(cnt, rp, cur, N);
    k_scatter<<<1024, 256, 0, stream>>>(src, dst, cur, col, E);

    k_embed<<<nb, 256, 0, stream>>>(oneh, pos, embW, embB, x, x0, N);

    for (int l = 0; l < 4; ++l) {
        k_interact<<<nb, 256, 0, stream>>>(x, iW + (size_t)l * 128 * 64, iB + l * 64, A, B, N);
        k_edge_csr<<<(N * 64 + 255) / 256, 256, 0, stream>>>(rp, col, A, B, m, N);
        k_update<<<nb, 256, 0, stream>>>(x, m, uW + (size_t)l * 64 * 64, uB + l * 64, N);
    }

    k_out<<<(N + 3) / 4, 256, 0, stream>>>(x, x0, oW, oB, (float*)d_out, N);
}

// Round 3
// 684.308 us; speedup vs baseline: 4.5604x; 1.2889x over previous
//
#include <hip/hip_runtime.h>

#define H 64
#define NODES_PER_BLK 16
#define MM_NODES 32   // nodes per block in interact/update (8 per wave)

__device__ __forceinline__ float silu_f(float v) { return v / (1.0f + __expf(-v)); }

// ---------------- CSR build ----------------
__global__ __launch_bounds__(256) void k_hist(const int* __restrict__ src, int* __restrict__ cnt, int E)
{
    int stride = gridDim.x * blockDim.x;
    for (int e = blockIdx.x * blockDim.x + threadIdx.x; e < E; e += stride)
        atomicAdd(&cnt[src[e]], 1);
}

// Hierarchical scan, pass 1: per-block (256 elems) exclusive scan + block sums.
__global__ __launch_bounds__(256) void k_scan1(const int* __restrict__ cnt,
                                               int* __restrict__ texc, int* __restrict__ bsum, int n)
{
    __shared__ int s[256];
    const int t = threadIdx.x;
    const int i = blockIdx.x * 256 + t;
    int v = (i < n) ? cnt[i] : 0;
    s[t] = v;
    __syncthreads();
    for (int off = 1; off < 256; off <<= 1) {
        int u = (t >= off) ? s[t - off] : 0;
        __syncthreads();
        s[t] += u;
        __syncthreads();
    }
    if (i < n) texc[i] = s[t] - v;          // exclusive within block
    if (t == 255) bsum[blockIdx.x] = s[255];
}

// pass 2: single block scans the (<=256) block sums in place -> exclusive.
__global__ __launch_bounds__(256) void k_scan2(int* __restrict__ bsum, int nb)
{
    __shared__ int s[256];
    const int t = threadIdx.x;
    int v = (t < nb) ? bsum[t] : 0;
    s[t] = v;
    __syncthreads();
    for (int off = 1; off < 256; off <<= 1) {
        int u = (t >= off) ? s[t - off] : 0;
        __syncthreads();
        s[t] += u;
        __syncthreads();
    }
    if (t < nb) bsum[t] = s[t] - v;         // exclusive
}

// pass 3: rp = texc + bsum[block]; cur = rp; rp[n] = E.
__global__ __launch_bounds__(256) void k_scan3(const int* __restrict__ texc, const int* __restrict__ bsum,
                                               int* __restrict__ rp, int* __restrict__ cur, int n, int E)
{
    const int i = blockIdx.x * 256 + threadIdx.x;
    if (i < n) {
        int v = texc[i] + bsum[blockIdx.x];
        rp[i] = v;
        cur[i] = v;
    }
    if (i == 0) rp[n] = E;
}

__global__ __launch_bounds__(256) void k_scatter(const int* __restrict__ src, const int* __restrict__ dst,
                                                 int* __restrict__ cur, int* __restrict__ col, int E)
{
    int stride = gridDim.x * blockDim.x;
    for (int e = blockIdx.x * blockDim.x + threadIdx.x; e < E; e += stride) {
        int s = src[e];
        int pos = atomicAdd(&cur[s], 1);
        col[pos] = dst[e];
    }
}

// ---------------- Embedding: x = silu(concat(onehot, pos) @ embW + embB) ----------------
__global__ __launch_bounds__(256) void k_embed(
    const float* __restrict__ oneh, const float* __restrict__ pos,
    const float* __restrict__ W, const float* __restrict__ bvec,
    float* __restrict__ x, float* __restrict__ x0, int N)
{
    __shared__ float Wl[121 * 64];
    __shared__ float xin[NODES_PER_BLK * 121];
    const int t = threadIdx.x;
    for (int i = t; i < 121 * 64; i += 256) Wl[i] = W[i];
    const int n0 = blockIdx.x * NODES_PER_BLK;
    for (int i = t; i < NODES_PER_BLK * 121; i += 256) {
        int node = n0 + i / 121;
        int k = i % 121;
        float v = 0.f;
        if (node < N) v = (k < 118) ? oneh[(size_t)node * 118 + k] : pos[(size_t)node * 3 + (k - 118)];
        xin[i] = v;
    }
    __syncthreads();
    const int h = t & 63, ni = t >> 6;
    const float bb = bvec[h];
    #pragma unroll
    for (int j = 0; j < 4; ++j) {
        int node = ni + 4 * j;
        int gnode = n0 + node;
        if (gnode >= N) continue;
        float acc = bb;
        #pragma unroll 11
        for (int k = 0; k < 121; ++k)
            acc = fmaf(xin[node * 121 + k], Wl[k * 64 + h], acc);
        float v = silu_f(acc);
        x[(size_t)gnode * H + h] = v;
        x0[(size_t)gnode * H + h] = v;
    }
}

// ---------------- Per-layer node transform: A = x@Wt + ib ; B = x@Wb ----------------
// W columns live in VGPRs (compile-time indexed). x rows staged in LDS, read as
// float4 broadcasts (all 64 lanes same address -> no conflict). fma-bound.
__global__ __launch_bounds__(256) void k_interact(
    const float* __restrict__ x, const float* __restrict__ Wg, const float* __restrict__ ib,
    float* __restrict__ A, float* __restrict__ B, int N)
{
    const int t = threadIdx.x;
    const int h = t & 63, w = t >> 6;
    float wA[64], wB[64];
    #pragma unroll
    for (int k = 0; k < 64; ++k) {
        wA[k] = Wg[k * 64 + h];
        wB[k] = Wg[(64 + k) * 64 + h];
    }
    __shared__ float xl[MM_NODES * 64];
    const int n0 = blockIdx.x * MM_NODES;
    for (int i = t; i < MM_NODES * 64; i += 256) {
        int g = n0 * 64 + i;
        xl[i] = (g < N * 64) ? x[g] : 0.f;
    }
    __syncthreads();
    const float bias = ib[h];
    #pragma unroll
    for (int j = 0; j < 8; ++j) {
        int node = w * 8 + j;            // wave-uniform
        int gnode = n0 + node;
        if (gnode >= N) continue;
        float acca = bias, accb = 0.f;
        const float4* xr = reinterpret_cast<const float4*>(&xl[node * 64]);
        #pragma unroll
        for (int kk = 0; kk < 16; ++kk) {
            float4 xq = xr[kk];
            acca = fmaf(xq.x, wA[4 * kk + 0], acca); accb = fmaf(xq.x, wB[4 * kk + 0], accb);
            acca = fmaf(xq.y, wA[4 * kk + 1], acca); accb = fmaf(xq.y, wB[4 * kk + 1], accb);
            acca = fmaf(xq.z, wA[4 * kk + 2], acca); accb = fmaf(xq.z, wB[4 * kk + 2], accb);
            acca = fmaf(xq.w, wA[4 * kk + 3], acca); accb = fmaf(xq.w, wB[4 * kk + 3], accb);
        }
        A[(size_t)gnode * H + h] = acca;
        B[(size_t)gnode * H + h] = accb;
    }
}

// ---------------- Edge pass (CSR, no atomics): m[i][h] = sum_j silu(A[i][h] + B[col[j]][h]) ----
__global__ __launch_bounds__(256) void k_edge_csr(
    const int* __restrict__ rp, const int* __restrict__ col,
    const float* __restrict__ A, const float* __restrict__ B,
    float* __restrict__ m, int N)
{
    const int wid = (blockIdx.x * 256 + threadIdx.x) >> 6;  // one wave per node
    const int h = threadIdx.x & 63;
    if (wid >= N) return;
    const float a = A[(size_t)wid * H + h];
    const int beg = rp[wid], end = rp[wid + 1];
    float acc = 0.f;
    for (int j = beg; j < end; ++j) {
        int d = col[j];
        acc += silu_f(a + B[(size_t)d * H + h]);
    }
    m[(size_t)wid * H + h] = acc;
}

// ---------------- Update: x += silu((x + 0.25*m) @ uW + ub) ----------------
__global__ __launch_bounds__(256) void k_update(
    float* __restrict__ x, const float* __restrict__ m,
    const float* __restrict__ Wg, const float* __restrict__ ub, int N)
{
    const int t = threadIdx.x;
    const int h = t & 63, w = t >> 6;
    float wU[64];
    #pragma unroll
    for (int k = 0; k < 64; ++k) wU[k] = Wg[k * 64 + h];
    __shared__ float xl[MM_NODES * 64];
    __shared__ float ml[MM_NODES * 64];
    const int n0 = blockIdx.x * MM_NODES;
    for (int i = t; i < MM_NODES * 64; i += 256) {
        int g = n0 * 64 + i;
        xl[i] = (g < N * 64) ? x[g] : 0.f;
        ml[i] = (g < N * 64) ? m[g] : 0.f;
    }
    __syncthreads();
    const float bias = ub[h];
    #pragma unroll
    for (int j = 0; j < 8; ++j) {
        int node = w * 8 + j;
        int gnode = n0 + node;
        if (gnode >= N) continue;
        float acc = bias;
        const float4* xr = reinterpret_cast<const float4*>(&xl[node * 64]);
        const float4* mr = reinterpret_cast<const float4*>(&ml[node * 64]);
        #pragma unroll
        for (int kk = 0; kk < 16; ++kk) {
            float4 xq = xr[kk];
            float4 mq = mr[kk];
            acc = fmaf(fmaf(0.25f, mq.x, xq.x), wU[4 * kk + 0], acc);
            acc = fmaf(fmaf(0.25f, mq.y, xq.y), wU[4 * kk + 1], acc);
            acc = fmaf(fmaf(0.25f, mq.z, xq.z), wU[4 * kk + 2], acc);
            acc = fmaf(fmaf(0.25f, mq.w, xq.w), wU[4 * kk + 3], acc);
        }
        x[(size_t)gnode * H + h] = xl[node * 64 + h] + silu_f(acc);
    }
}

// ---------------- Output: out = (x + x0) @ outW + outB ----------------
__global__ __launch_bounds__(256) void k_out(
    const float* __restrict__ x, const float* __restrict__ x0,
    const float* __restrict__ W, const float* __restrict__ ob,
    float* __restrict__ out, int N)
{
    const int t = threadIdx.x;
    const int h = t & 63, ni = t >> 6;
    const int node = blockIdx.x * 4 + ni;
    if (node >= N) return;
    float v = x[(size_t)node * H + h] + x0[(size_t)node * H + h];
    float p0 = v * W[h * 3 + 0];
    float p1 = v * W[h * 3 + 1];
    float p2 = v * W[h * 3 + 2];
    #pragma unroll
    for (int off = 32; off; off >>= 1) {
        p0 += __shfl_down(p0, off);
        p1 += __shfl_down(p1, off);
        p2 += __shfl_down(p2, off);
    }
    if (h == 0) {
        out[node * 3 + 0] = p0 + ob[0];
        out[node * 3 + 1] = p1 + ob[1];
        out[node * 3 + 2] = p2 + ob[2];
    }
}

extern "C" void kernel_launch(void* const* d_in, const int* in_sizes, int n_in,
                              void* d_out, int out_size, void* d_ws, size_t ws_size,
                              hipStream_t stream)
{
    const float* oneh = (const float*)d_in[0];
    const float* pos  = (const float*)d_in[1];
    const int*   ei   = (const int*)d_in[2];
    const float* embW = (const float*)d_in[3];
    const float* embB = (const float*)d_in[4];
    const float* iW   = (const float*)d_in[5];   // [4][128][64]
    const float* iB   = (const float*)d_in[6];   // [4][64]
    const float* uW   = (const float*)d_in[7];   // [4][64][64]
    const float* uB   = (const float*)d_in[8];   // [4][64]
    const float* oW   = (const float*)d_in[9];   // [64][3]
    const float* oB   = (const float*)d_in[10];  // [3]

    const int N = in_sizes[0] / 118;
    const int E = in_sizes[2] / 2;
    const int* src = ei;
    const int* dst = ei + E;

    float* ws = (float*)d_ws;
    const size_t NH = (size_t)N * H;
    float* x  = ws;
    float* x0 = ws + NH;
    float* A  = ws + 2 * NH;
    float* B  = ws + 3 * NH;
    float* m  = ws + 4 * NH;
    int* ibase = (int*)(ws + 5 * NH);
    int* cnt   = ibase;               // N
    int* cur   = ibase + N;           // N
    int* rp    = ibase + 2 * N;       // N+1
    int* col   = ibase + 3 * N + 1;   // E
    int* texc  = col + E;             // N
    int* bsum  = texc + N;            // <=256

    const int nbe = (N + NODES_PER_BLK - 1) / NODES_PER_BLK;
    const int nbm = (N + MM_NODES - 1) / MM_NODES;
    const int nbs = (N + 255) / 256;  // scan blocks (196 <= 256)

    // CSR build (once per call; amortized over 4 layers)
    hipMemsetAsync(cnt, 0, (size_t)N * sizeof(int), stream);
    k_hist<<<1024, 256, 0, stream>>>(src, cnt, E);
    k_scan1<<<nbs, 256, 0, stream>>>(cnt, texc, bsum, N);
    k_scan2<<<1, 256, 0, stream>>>(bsum, nbs);
    k_scan3<<<nbs, 256, 0, stream>>>(texc, bsum, rp, cur, N, E);
    k_scatter<<<1024, 256, 0, stream>>>(src, dst, cur, col, E);

    k_embed<<<nbe, 256, 0, stream>>>(oneh, pos, embW, embB, x, x0, N);

    for (int l = 0; l < 4; ++l) {
        k_interact<<<nbm, 256, 0, stream>>>(x, iW + (size_t)l * 128 * 64, iB + l * 64, A, B, N);
        k_edge_csr<<<(N * 64 + 255) / 256, 256, 0, stream>>>(rp, col, A, B, m, N);
        k_update<<<nbm, 256, 0, stream>>>(x, m, uW + (size_t)l * 64 * 64, uB + l * 64, N);
    }

    k_out<<<(N + 3) / 4, 256, 0, stream>>>(x, x0, oW, oB, (float*)d_out, N);
}

// Round 4
// 514.033 us; speedup vs baseline: 6.0710x; 1.3313x over previous
//
#include <hip/hip_runtime.h>

#define H 64
#define NODES_PER_BLK 16
#define MM_NODES 32   // nodes per block in interact/update (8 per wave)

__device__ __forceinline__ float silu_f(float v) { return v / (1.0f + __expf(-v)); }

__device__ __forceinline__ float4 silu4(float4 v) {
    float4 r;
    r.x = silu_f(v.x); r.y = silu_f(v.y); r.z = silu_f(v.z); r.w = silu_f(v.w);
    return r;
}

// ---------------- CSR build ----------------
__global__ __launch_bounds__(256) void k_hist(const int* __restrict__ src, int* __restrict__ cnt, int E)
{
    int stride = gridDim.x * blockDim.x;
    for (int e = blockIdx.x * blockDim.x + threadIdx.x; e < E; e += stride)
        atomicAdd(&cnt[src[e]], 1);
}

__global__ __launch_bounds__(256) void k_scan1(const int* __restrict__ cnt,
                                               int* __restrict__ texc, int* __restrict__ bsum, int n)
{
    __shared__ int s[256];
    const int t = threadIdx.x;
    const int i = blockIdx.x * 256 + t;
    int v = (i < n) ? cnt[i] : 0;
    s[t] = v;
    __syncthreads();
    for (int off = 1; off < 256; off <<= 1) {
        int u = (t >= off) ? s[t - off] : 0;
        __syncthreads();
        s[t] += u;
        __syncthreads();
    }
    if (i < n) texc[i] = s[t] - v;
    if (t == 255) bsum[blockIdx.x] = s[255];
}

__global__ __launch_bounds__(256) void k_scan2(int* __restrict__ bsum, int nb)
{
    __shared__ int s[256];
    const int t = threadIdx.x;
    int v = (t < nb) ? bsum[t] : 0;
    s[t] = v;
    __syncthreads();
    for (int off = 1; off < 256; off <<= 1) {
        int u = (t >= off) ? s[t - off] : 0;
        __syncthreads();
        s[t] += u;
        __syncthreads();
    }
    if (t < nb) bsum[t] = s[t] - v;
}

__global__ __launch_bounds__(256) void k_scan3(const int* __restrict__ texc, const int* __restrict__ bsum,
                                               int* __restrict__ rp, int* __restrict__ cur, int n, int E)
{
    const int i = blockIdx.x * 256 + threadIdx.x;
    if (i < n) {
        int v = texc[i] + bsum[blockIdx.x];
        rp[i] = v;
        cur[i] = v;
    }
    if (i == 0) rp[n] = E;
}

__global__ __launch_bounds__(256) void k_scatter(const int* __restrict__ src, const int* __restrict__ dst,
                                                 int* __restrict__ cur, int* __restrict__ col, int E)
{
    int stride = gridDim.x * blockDim.x;
    for (int e = blockIdx.x * blockDim.x + threadIdx.x; e < E; e += stride) {
        int s = src[e];
        int pos = atomicAdd(&cur[s], 1);
        col[pos] = dst[e];
    }
}

// ---------------- Embedding: x = silu(concat(onehot, pos) @ embW + embB) ----------------
__global__ __launch_bounds__(256) void k_embed(
    const float* __restrict__ oneh, const float* __restrict__ pos,
    const float* __restrict__ W, const float* __restrict__ bvec,
    float* __restrict__ x, float* __restrict__ x0, int N)
{
    __shared__ float Wl[121 * 64];
    __shared__ float xin[NODES_PER_BLK * 121];
    const int t = threadIdx.x;
    for (int i = t; i < 121 * 64; i += 256) Wl[i] = W[i];
    const int n0 = blockIdx.x * NODES_PER_BLK;
    for (int i = t; i < NODES_PER_BLK * 121; i += 256) {
        int node = n0 + i / 121;
        int k = i % 121;
        float v = 0.f;
        if (node < N) v = (k < 118) ? oneh[(size_t)node * 118 + k] : pos[(size_t)node * 3 + (k - 118)];
        xin[i] = v;
    }
    __syncthreads();
    const int h = t & 63, ni = t >> 6;
    const float bb = bvec[h];
    #pragma unroll
    for (int j = 0; j < 4; ++j) {
        int node = ni + 4 * j;
        int gnode = n0 + node;
        if (gnode >= N) continue;
        float acc = bb;
        #pragma unroll 11
        for (int k = 0; k < 121; ++k)
            acc = fmaf(xin[node * 121 + k], Wl[k * 64 + h], acc);
        float v = silu_f(acc);
        x[(size_t)gnode * H + h] = v;
        x0[(size_t)gnode * H + h] = v;
    }
}

// ---------------- Per-layer node transform: A = x@Wt + ib ; B = x@Wb ----------------
__global__ __launch_bounds__(256) void k_interact(
    const float* __restrict__ x, const float* __restrict__ Wg, const float* __restrict__ ib,
    float* __restrict__ A, float* __restrict__ B, int N)
{
    const int t = threadIdx.x;
    const int h = t & 63, w = t >> 6;
    float wA[64], wB[64];
    #pragma unroll
    for (int k = 0; k < 64; ++k) {
        wA[k] = Wg[k * 64 + h];
        wB[k] = Wg[(64 + k) * 64 + h];
    }
    __shared__ float xl[MM_NODES * 64];
    const int n0 = blockIdx.x * MM_NODES;
    for (int i = t; i < MM_NODES * 64; i += 256) {
        int g = n0 * 64 + i;
        xl[i] = (g < N * 64) ? x[g] : 0.f;
    }
    __syncthreads();
    const float bias = ib[h];
    #pragma unroll
    for (int j = 0; j < 8; ++j) {
        int node = w * 8 + j;
        int gnode = n0 + node;
        if (gnode >= N) continue;
        float acca = bias, accb = 0.f;
        const float4* xr = reinterpret_cast<const float4*>(&xl[node * 64]);
        #pragma unroll
        for (int kk = 0; kk < 16; ++kk) {
            float4 xq = xr[kk];
            acca = fmaf(xq.x, wA[4 * kk + 0], acca); accb = fmaf(xq.x, wB[4 * kk + 0], accb);
            acca = fmaf(xq.y, wA[4 * kk + 1], acca); accb = fmaf(xq.y, wB[4 * kk + 1], accb);
            acca = fmaf(xq.z, wA[4 * kk + 2], acca); accb = fmaf(xq.z, wB[4 * kk + 2], accb);
            acca = fmaf(xq.w, wA[4 * kk + 3], acca); accb = fmaf(xq.w, wB[4 * kk + 3], accb);
        }
        A[(size_t)gnode * H + h] = acca;
        B[(size_t)gnode * H + h] = accb;
    }
}

// ---------------- Edge pass (CSR, no atomics) ----------------
// 16-lane subgroup per node, float4 per lane. 4 nodes per wave -> 4 independent
// gather chains; unroll x2 -> 8 outstanding B-row loads per wave.
__global__ __launch_bounds__(256) void k_edge_csr(
    const int* __restrict__ rp, const int* __restrict__ col,
    const float* __restrict__ A, const float* __restrict__ B,
    float* __restrict__ m, int N)
{
    const int tid = blockIdx.x * 256 + threadIdx.x;
    const int node = tid >> 4;         // 16 lanes per node
    const int q = threadIdx.x & 15;    // float4 slot within the 64-float row
    if (node >= N) return;
    const float4* __restrict__ Av = reinterpret_cast<const float4*>(A);
    const float4* __restrict__ Bv = reinterpret_cast<const float4*>(B);
    const float4 a = Av[(size_t)node * 16 + q];
    const int beg = rp[node], end = rp[node + 1];
    float4 acc = make_float4(0.f, 0.f, 0.f, 0.f);
    int j = beg;
    for (; j + 2 <= end; j += 2) {
        int d0 = col[j];
        int d1 = col[j + 1];
        float4 b0 = Bv[(size_t)d0 * 16 + q];
        float4 b1 = Bv[(size_t)d1 * 16 + q];
        float4 s0, s1;
        s0.x = a.x + b0.x; s0.y = a.y + b0.y; s0.z = a.z + b0.z; s0.w = a.w + b0.w;
        s1.x = a.x + b1.x; s1.y = a.y + b1.y; s1.z = a.z + b1.z; s1.w = a.w + b1.w;
        s0 = silu4(s0); s1 = silu4(s1);
        acc.x += s0.x + s1.x; acc.y += s0.y + s1.y;
        acc.z += s0.z + s1.z; acc.w += s0.w + s1.w;
    }
    if (j < end) {
        int d = col[j];
        float4 b = Bv[(size_t)d * 16 + q];
        float4 s;
        s.x = silu_f(a.x + b.x); s.y = silu_f(a.y + b.y);
        s.z = silu_f(a.z + b.z); s.w = silu_f(a.w + b.w);
        acc.x += s.x; acc.y += s.y; acc.z += s.z; acc.w += s.w;
    }
    reinterpret_cast<float4*>(m)[(size_t)node * 16 + q] = acc;
}

// ---------------- Update: x += silu((x + 0.25*m) @ uW + ub) ----------------
__global__ __launch_bounds__(256) void k_update(
    float* __restrict__ x, const float* __restrict__ m,
    const float* __restrict__ Wg, const float* __restrict__ ub, int N)
{
    const int t = threadIdx.x;
    const int h = t & 63, w = t >> 6;
    float wU[64];
    #pragma unroll
    for (int k = 0; k < 64; ++k) wU[k] = Wg[k * 64 + h];
    __shared__ float xl[MM_NODES * 64];
    __shared__ float ml[MM_NODES * 64];
    const int n0 = blockIdx.x * MM_NODES;
    for (int i = t; i < MM_NODES * 64; i += 256) {
        int g = n0 * 64 + i;
        xl[i] = (g < N * 64) ? x[g] : 0.f;
        ml[i] = (g < N * 64) ? m[g] : 0.f;
    }
    __syncthreads();
    const float bias = ub[h];
    #pragma unroll
    for (int j = 0; j < 8; ++j) {
        int node = w * 8 + j;
        int gnode = n0 + node;
        if (gnode >= N) continue;
        float acc = bias;
        const float4* xr = reinterpret_cast<const float4*>(&xl[node * 64]);
        const float4* mr = reinterpret_cast<const float4*>(&ml[node * 64]);
        #pragma unroll
        for (int kk = 0; kk < 16; ++kk) {
            float4 xq = xr[kk];
            float4 mq = mr[kk];
            acc = fmaf(fmaf(0.25f, mq.x, xq.x), wU[4 * kk + 0], acc);
            acc = fmaf(fmaf(0.25f, mq.y, xq.y), wU[4 * kk + 1], acc);
            acc = fmaf(fmaf(0.25f, mq.z, xq.z), wU[4 * kk + 2], acc);
            acc = fmaf(fmaf(0.25f, mq.w, xq.w), wU[4 * kk + 3], acc);
        }
        x[(size_t)gnode * H + h] = xl[node * 64 + h] + silu_f(acc);
    }
}

// ---------------- Output: out = (x + x0) @ outW + outB ----------------
__global__ __launch_bounds__(256) void k_out(
    const float* __restrict__ x, const float* __restrict__ x0,
    const float* __restrict__ W, const float* __restrict__ ob,
    float* __restrict__ out, int N)
{
    const int t = threadIdx.x;
    const int h = t & 63, ni = t >> 6;
    const int node = blockIdx.x * 4 + ni;
    if (node >= N) return;
    float v = x[(size_t)node * H + h] + x0[(size_t)node * H + h];
    float p0 = v * W[h * 3 + 0];
    float p1 = v * W[h * 3 + 1];
    float p2 = v * W[h * 3 + 2];
    #pragma unroll
    for (int off = 32; off; off >>= 1) {
        p0 += __shfl_down(p0, off);
        p1 += __shfl_down(p1, off);
        p2 += __shfl_down(p2, off);
    }
    if (h == 0) {
        out[node * 3 + 0] = p0 + ob[0];
        out[node * 3 + 1] = p1 + ob[1];
        out[node * 3 + 2] = p2 + ob[2];
    }
}

extern "C" void kernel_launch(void* const* d_in, const int* in_sizes, int n_in,
                              void* d_out, int out_size, void* d_ws, size_t ws_size,
                              hipStream_t stream)
{
    const float* oneh = (const float*)d_in[0];
    const float* pos  = (const float*)d_in[1];
    const int*   ei   = (const int*)d_in[2];
    const float* embW = (const float*)d_in[3];
    const float* embB = (const float*)d_in[4];
    const float* iW   = (const float*)d_in[5];   // [4][128][64]
    const float* iB   = (const float*)d_in[6];   // [4][64]
    const float* uW   = (const float*)d_in[7];   // [4][64][64]
    const float* uB   = (const float*)d_in[8];   // [4][64]
    const float* oW   = (const float*)d_in[9];   // [64][3]
    const float* oB   = (const float*)d_in[10];  // [3]

    const int N = in_sizes[0] / 118;
    const int E = in_sizes[2] / 2;
    const int* src = ei;
    const int* dst = ei + E;

    float* ws = (float*)d_ws;
    const size_t NH = (size_t)N * H;
    float* x  = ws;
    float* x0 = ws + NH;
    float* A  = ws + 2 * NH;
    float* B  = ws + 3 * NH;
    float* m  = ws + 4 * NH;
    int* ibase = (int*)(ws + 5 * NH);
    int* cnt   = ibase;               // N
    int* cur   = ibase + N;           // N
    int* rp    = ibase + 2 * N;       // N+1
    int* col   = ibase + 3 * N + 1;   // E
    int* texc  = col + E;             // N
    int* bsum  = texc + N;            // <=256

    const int nbe = (N + NODES_PER_BLK - 1) / NODES_PER_BLK;
    const int nbm = (N + MM_NODES - 1) / MM_NODES;
    const int nbs = (N + 255) / 256;

    hipMemsetAsync(cnt, 0, (size_t)N * sizeof(int), stream);
    k_hist<<<1024, 256, 0, stream>>>(src, cnt, E);
    k_scan1<<<nbs, 256, 0, stream>>>(cnt, texc, bsum, N);
    k_scan2<<<1, 256, 0, stream>>>(bsum, nbs);
    k_scan3<<<nbs, 256, 0, stream>>>(texc, bsum, rp, cur, N, E);
    k_scatter<<<1024, 256, 0, stream>>>(src, dst, cur, col, E);

    k_embed<<<nbe, 256, 0, stream>>>(oneh, pos, embW, embB, x, x0, N);

    for (int l = 0; l < 4; ++l) {
        k_interact<<<nbm, 256, 0, stream>>>(x, iW + (size_t)l * 128 * 64, iB + l * 64, A, B, N);
        k_edge_csr<<<((size_t)N * 16 + 255) / 256, 256, 0, stream>>>(rp, col, A, B, m, N);
        k_update<<<nbm, 256, 0, stream>>>(x, m, uW + (size_t)l * 64 * 64, uB + l * 64, N);
    }

    k_out<<<(N + 3) / 4, 256, 0, stream>>>(x, x0, oW, oB, (float*)d_out, N);
}

// Round 5
// 450.662 us; speedup vs baseline: 6.9247x; 1.1406x over previous
//
#include <hip/hip_runtime.h>

#define H 64
#define EMB_NODES 32  // nodes per block in embed
#define MM_NODES 32   // nodes per block in interact (8 per wave)

__device__ __forceinline__ float silu_f(float v) { return v / (1.0f + __expf(-v)); }

__device__ __forceinline__ float4 silu4(float4 v) {
    float4 r;
    r.x = silu_f(v.x); r.y = silu_f(v.y); r.z = silu_f(v.z); r.w = silu_f(v.w);
    return r;
}

// ---------------- CSR build ----------------
__global__ __launch_bounds__(256) void k_hist(const int* __restrict__ src, int* __restrict__ cnt, int E)
{
    int stride = gridDim.x * blockDim.x;
    for (int e = blockIdx.x * blockDim.x + threadIdx.x; e < E; e += stride)
        atomicAdd(&cnt[src[e]], 1);
}

__global__ __launch_bounds__(256) void k_scan1(const int* __restrict__ cnt,
                                               int* __restrict__ texc, int* __restrict__ bsum, int n)
{
    __shared__ int s[256];
    const int t = threadIdx.x;
    const int i = blockIdx.x * 256 + t;
    int v = (i < n) ? cnt[i] : 0;
    s[t] = v;
    __syncthreads();
    for (int off = 1; off < 256; off <<= 1) {
        int u = (t >= off) ? s[t - off] : 0;
        __syncthreads();
        s[t] += u;
        __syncthreads();
    }
    if (i < n) texc[i] = s[t] - v;
    if (t == 255) bsum[blockIdx.x] = s[255];
}

__global__ __launch_bounds__(256) void k_scan2(int* __restrict__ bsum, int nb)
{
    __shared__ int s[256];
    const int t = threadIdx.x;
    int v = (t < nb) ? bsum[t] : 0;
    s[t] = v;
    __syncthreads();
    for (int off = 1; off < 256; off <<= 1) {
        int u = (t >= off) ? s[t - off] : 0;
        __syncthreads();
        s[t] += u;
        __syncthreads();
    }
    if (t < nb) bsum[t] = s[t] - v;
}

__global__ __launch_bounds__(256) void k_scan3(const int* __restrict__ texc, const int* __restrict__ bsum,
                                               int* __restrict__ rp, int* __restrict__ cur, int n, int E)
{
    const int i = blockIdx.x * 256 + threadIdx.x;
    if (i < n) {
        int v = texc[i] + bsum[blockIdx.x];
        rp[i] = v;
        cur[i] = v;
    }
    if (i == 0) rp[n] = E;
}

__global__ __launch_bounds__(256) void k_scatter(const int* __restrict__ src, const int* __restrict__ dst,
                                                 int* __restrict__ cur, int* __restrict__ col, int E)
{
    int stride = gridDim.x * blockDim.x;
    for (int e = blockIdx.x * blockDim.x + threadIdx.x; e < E; e += stride) {
        int s = src[e];
        int pos = atomicAdd(&cur[s], 1);
        col[pos] = dst[e];
    }
}

// ---------------- Embedding: x = silu(concat(onehot, pos) @ embW + embB) ----------------
// W column h lives in lane h's VGPRs (padded to 124); xin staged in LDS at stride 124.
__global__ __launch_bounds__(256) void k_embed(
    const float* __restrict__ oneh, const float* __restrict__ pos,
    const float* __restrict__ W, const float* __restrict__ bvec,
    float* __restrict__ x, float* __restrict__ x0, int N)
{
    const int t = threadIdx.x;
    const int h = t & 63, w = t >> 6;
    float wE[124];
    #pragma unroll
    for (int k = 0; k < 124; ++k) wE[k] = (k < 121) ? W[k * 64 + h] : 0.f;
    __shared__ float xin[EMB_NODES * 124];
    const int n0 = blockIdx.x * EMB_NODES;
    for (int i = t; i < EMB_NODES * 124; i += 256) {
        int node = n0 + i / 124;
        int k = i % 124;
        float v = 0.f;
        if (node < N) {
            if (k < 118) v = oneh[(size_t)node * 118 + k];
            else if (k < 121) v = pos[(size_t)node * 3 + (k - 118)];
        }
        xin[i] = v;
    }
    __syncthreads();
    const float bb = bvec[h];
    #pragma unroll
    for (int j = 0; j < 8; ++j) {
        int node = w * 8 + j;
        int gnode = n0 + node;
        if (gnode >= N) continue;
        float acc = bb;
        const float4* xr = reinterpret_cast<const float4*>(&xin[node * 124]);
        #pragma unroll
        for (int kk = 0; kk < 31; ++kk) {
            float4 xq = xr[kk];
            acc = fmaf(xq.x, wE[4 * kk + 0], acc);
            acc = fmaf(xq.y, wE[4 * kk + 1], acc);
            acc = fmaf(xq.z, wE[4 * kk + 2], acc);
            acc = fmaf(xq.w, wE[4 * kk + 3], acc);
        }
        float v = silu_f(acc);
        x[(size_t)gnode * H + h] = v;
        x0[(size_t)gnode * H + h] = v;
    }
}

// ---------------- Per-layer node transform: A = x@Wt + ib ; B = x@Wb ----------------
__global__ __launch_bounds__(256) void k_interact(
    const float* __restrict__ x, const float* __restrict__ Wg, const float* __restrict__ ib,
    float* __restrict__ A, float* __restrict__ B, int N)
{
    const int t = threadIdx.x;
    const int h = t & 63, w = t >> 6;
    float wA[64], wB[64];
    #pragma unroll
    for (int k = 0; k < 64; ++k) {
        wA[k] = Wg[k * 64 + h];
        wB[k] = Wg[(64 + k) * 64 + h];
    }
    __shared__ float xl[MM_NODES * 64];
    const int n0 = blockIdx.x * MM_NODES;
    for (int i = t; i < MM_NODES * 64; i += 256) {
        int g = n0 * 64 + i;
        xl[i] = (g < N * 64) ? x[g] : 0.f;
    }
    __syncthreads();
    const float bias = ib[h];
    #pragma unroll
    for (int j = 0; j < 8; ++j) {
        int node = w * 8 + j;
        int gnode = n0 + node;
        if (gnode >= N) continue;
        float acca = bias, accb = 0.f;
        const float4* xr = reinterpret_cast<const float4*>(&xl[node * 64]);
        #pragma unroll
        for (int kk = 0; kk < 16; ++kk) {
            float4 xq = xr[kk];
            acca = fmaf(xq.x, wA[4 * kk + 0], acca); accb = fmaf(xq.x, wB[4 * kk + 0], accb);
            acca = fmaf(xq.y, wA[4 * kk + 1], acca); accb = fmaf(xq.y, wB[4 * kk + 1], accb);
            acca = fmaf(xq.z, wA[4 * kk + 2], acca); accb = fmaf(xq.z, wB[4 * kk + 2], accb);
            acca = fmaf(xq.w, wA[4 * kk + 3], acca); accb = fmaf(xq.w, wB[4 * kk + 3], accb);
        }
        A[(size_t)gnode * H + h] = acca;
        B[(size_t)gnode * H + h] = accb;
    }
}

// ---------------- Fused edge + update (+ final output projection) ----------------
// 16-lane group per node: gather/accumulate m, then v = x + 0.25*m, stage v in LDS,
// matmul against LDS-staged uW, x_new = x + silu(...). LAST also emits the out row.
template <bool LAST>
__global__ __launch_bounds__(256) void k_edge_upd(
    const int* __restrict__ rp, const int* __restrict__ col,
    const float* __restrict__ A, const float* __restrict__ B,
    float* __restrict__ x, const float* __restrict__ uWl, const float* __restrict__ ub,
    const float* __restrict__ x0, const float* __restrict__ oW, const float* __restrict__ ob,
    float* __restrict__ out, int N)
{
    __shared__ float Wl[64 * 64];          // update weights, [k][h]
    __shared__ float sv[16 * 68];          // per-group v rows, stride 68 (bank-spread)
    const int t = threadIdx.x;
    const int g = t >> 4;                  // group (node slot) 0..15
    const int q = t & 15;                  // float4 slot
    {
        const float4* src4 = reinterpret_cast<const float4*>(uWl);
        float4* dst4 = reinterpret_cast<float4*>(Wl);
        #pragma unroll
        for (int i = 0; i < 4; ++i) dst4[t + 256 * i] = src4[t + 256 * i];
    }
    const int node = blockIdx.x * 16 + g;
    const bool valid = node < N;
    const size_t nidx = (size_t)(valid ? node : 0) * 16 + q;
    const float4* __restrict__ Av = reinterpret_cast<const float4*>(A);
    const float4* __restrict__ Bv = reinterpret_cast<const float4*>(B);
    float4* __restrict__ Xv = reinterpret_cast<float4*>(x);

    const float4 a = Av[nidx];
    const float4 xq = Xv[nidx];
    const int beg = valid ? rp[node] : 0;
    const int end = valid ? rp[node + 1] : 0;

    float4 acc = make_float4(0.f, 0.f, 0.f, 0.f);
    int j = beg;
    for (; j + 2 <= end; j += 2) {
        int d0 = col[j];
        int d1 = col[j + 1];
        float4 b0 = Bv[(size_t)d0 * 16 + q];
        float4 b1 = Bv[(size_t)d1 * 16 + q];
        float4 s0, s1;
        s0.x = a.x + b0.x; s0.y = a.y + b0.y; s0.z = a.z + b0.z; s0.w = a.w + b0.w;
        s1.x = a.x + b1.x; s1.y = a.y + b1.y; s1.z = a.z + b1.z; s1.w = a.w + b1.w;
        s0 = silu4(s0); s1 = silu4(s1);
        acc.x += s0.x + s1.x; acc.y += s0.y + s1.y;
        acc.z += s0.z + s1.z; acc.w += s0.w + s1.w;
    }
    if (j < end) {
        int d = col[j];
        float4 b = Bv[(size_t)d * 16 + q];
        acc.x += silu_f(a.x + b.x); acc.y += silu_f(a.y + b.y);
        acc.z += silu_f(a.z + b.z); acc.w += silu_f(a.w + b.w);
    }
    // v = x + 0.25 * m
    float4 v;
    v.x = fmaf(0.25f, acc.x, xq.x); v.y = fmaf(0.25f, acc.y, xq.y);
    v.z = fmaf(0.25f, acc.z, xq.z); v.w = fmaf(0.25f, acc.w, xq.w);
    float* svg = &sv[g * 68];
    svg[q * 4 + 0] = v.x; svg[q * 4 + 1] = v.y;
    svg[q * 4 + 2] = v.z; svg[q * 4 + 3] = v.w;
    __syncthreads();
    // u[h] = sum_k v[k] * uW[k][h], lane handles h = 4q..4q+3
    float4 acc2 = reinterpret_cast<const float4*>(ub)[q];
    const float4* Wl4 = reinterpret_cast<const float4*>(Wl);
    #pragma unroll 8
    for (int k = 0; k < 64; ++k) {
        float vk = svg[k];
        float4 wq = Wl4[k * 16 + q];
        acc2.x = fmaf(vk, wq.x, acc2.x);
        acc2.y = fmaf(vk, wq.y, acc2.y);
        acc2.z = fmaf(vk, wq.z, acc2.z);
        acc2.w = fmaf(vk, wq.w, acc2.w);
    }
    float4 xn;
    xn.x = xq.x + silu_f(acc2.x); xn.y = xq.y + silu_f(acc2.y);
    xn.z = xq.z + silu_f(acc2.z); xn.w = xq.w + silu_f(acc2.w);
    if (valid) Xv[nidx] = xn;
    if (LAST) {
        const float4 x0q = reinterpret_cast<const float4*>(x0)[nidx];
        float f0 = xn.x + x0q.x, f1 = xn.y + x0q.y, f2 = xn.z + x0q.z, f3 = xn.w + x0q.w;
        float p0 = 0.f, p1 = 0.f, p2 = 0.f;
        const int k0 = 4 * q;
        p0 = fmaf(f0, oW[(k0 + 0) * 3 + 0], p0); p1 = fmaf(f0, oW[(k0 + 0) * 3 + 1], p1); p2 = fmaf(f0, oW[(k0 + 0) * 3 + 2], p2);
        p0 = fmaf(f1, oW[(k0 + 1) * 3 + 0], p0); p1 = fmaf(f1, oW[(k0 + 1) * 3 + 1], p1); p2 = fmaf(f1, oW[(k0 + 1) * 3 + 2], p2);
        p0 = fmaf(f2, oW[(k0 + 2) * 3 + 0], p0); p1 = fmaf(f2, oW[(k0 + 2) * 3 + 1], p1); p2 = fmaf(f2, oW[(k0 + 2) * 3 + 2], p2);
        p0 = fmaf(f3, oW[(k0 + 3) * 3 + 0], p0); p1 = fmaf(f3, oW[(k0 + 3) * 3 + 1], p1); p2 = fmaf(f3, oW[(k0 + 3) * 3 + 2], p2);
        #pragma unroll
        for (int off = 8; off; off >>= 1) {
            p0 += __shfl_xor(p0, off, 16);
            p1 += __shfl_xor(p1, off, 16);
            p2 += __shfl_xor(p2, off, 16);
        }
        if (valid && q == 0) {
            out[node * 3 + 0] = p0 + ob[0];
            out[node * 3 + 1] = p1 + ob[1];
            out[node * 3 + 2] = p2 + ob[2];
        }
    }
}

extern "C" void kernel_launch(void* const* d_in, const int* in_sizes, int n_in,
                              void* d_out, int out_size, void* d_ws, size_t ws_size,
                              hipStream_t stream)
{
    const float* oneh = (const float*)d_in[0];
    const float* pos  = (const float*)d_in[1];
    const int*   ei   = (const int*)d_in[2];
    const float* embW = (const float*)d_in[3];
    const float* embB = (const float*)d_in[4];
    const float* iW   = (const float*)d_in[5];   // [4][128][64]
    const float* iB   = (const float*)d_in[6];   // [4][64]
    const float* uW   = (const float*)d_in[7];   // [4][64][64]
    const float* uB   = (const float*)d_in[8];   // [4][64]
    const float* oW   = (const float*)d_in[9];   // [64][3]
    const float* oB   = (const float*)d_in[10];  // [3]

    const int N = in_sizes[0] / 118;
    const int E = in_sizes[2] / 2;
    const int* src = ei;
    const int* dst = ei + E;

    float* ws = (float*)d_ws;
    const size_t NH = (size_t)N * H;
    float* x  = ws;
    float* x0 = ws + NH;
    float* A  = ws + 2 * NH;
    float* B  = ws + 3 * NH;
    int* ibase = (int*)(ws + 4 * NH);
    int* cnt   = ibase;               // N
    int* cur   = ibase + N;           // N
    int* rp    = ibase + 2 * N;       // N+1
    int* col   = ibase + 3 * N + 1;   // E
    int* texc  = col + E;             // N
    int* bsum  = texc + N;            // <=256

    const int nbe = (N + EMB_NODES - 1) / EMB_NODES;
    const int nbm = (N + MM_NODES - 1) / MM_NODES;
    const int nbf = (N + 15) / 16;
    const int nbs = (N + 255) / 256;

    hipMemsetAsync(cnt, 0, (size_t)N * sizeof(int), stream);
    k_hist<<<1024, 256, 0, stream>>>(src, cnt, E);
    k_scan1<<<nbs, 256, 0, stream>>>(cnt, texc, bsum, N);
    k_scan2<<<1, 256, 0, stream>>>(bsum, nbs);
    k_scan3<<<nbs, 256, 0, stream>>>(texc, bsum, rp, cur, N, E);
    k_scatter<<<1024, 256, 0, stream>>>(src, dst, cur, col, E);

    k_embed<<<nbe, 256, 0, stream>>>(oneh, pos, embW, embB, x, x0, N);

    for (int l = 0; l < 4; ++l) {
        k_interact<<<nbm, 256, 0, stream>>>(x, iW + (size_t)l * 128 * 64, iB + l * 64, A, B, N);
        if (l < 3)
            k_edge_upd<false><<<nbf, 256, 0, stream>>>(rp, col, A, B, x,
                uW + (size_t)l * 64 * 64, uB + l * 64, x0, oW, oB, (float*)d_out, N);
        else
            k_edge_upd<true><<<nbf, 256, 0, stream>>>(rp, col, A, B, x,
                uW + (size_t)l * 64 * 64, uB + l * 64, x0, oW, oB, (float*)d_out, N);
    }
}

// Round 6
// 440.394 us; speedup vs baseline: 7.0862x; 1.0233x over previous
//
#include <hip/hip_runtime.h>

#define H 64
#define EMB_NODES 32  // nodes per block in embed
#define MM_NODES 32   // nodes per block in interact (8 per wave)

__device__ __forceinline__ float silu_f(float v) { return v / (1.0f + __expf(-v)); }

__device__ __forceinline__ unsigned bf16r(float f) {
    unsigned b = __float_as_uint(f);
    return (b + 0x7fffu + ((b >> 16) & 1u)) >> 16;   // RTNE, NaN-unsafe (inputs finite)
}
__device__ __forceinline__ unsigned pack2(float lo, float hi) {
    return bf16r(lo) | (bf16r(hi) << 16);
}
__device__ __forceinline__ float4 unpack4(uint2 u) {
    float4 r;
    r.x = __uint_as_float(u.x << 16);
    r.y = __uint_as_float(u.x & 0xffff0000u);
    r.z = __uint_as_float(u.y << 16);
    r.w = __uint_as_float(u.y & 0xffff0000u);
    return r;
}

// ---------------- CSR build ----------------
__global__ __launch_bounds__(256) void k_hist(const int* __restrict__ src, int* __restrict__ cnt, int E)
{
    int stride = gridDim.x * blockDim.x;
    for (int e = blockIdx.x * blockDim.x + threadIdx.x; e < E; e += stride)
        atomicAdd(&cnt[src[e]], 1);
}

__global__ __launch_bounds__(256) void k_scan1(const int* __restrict__ cnt,
                                               int* __restrict__ texc, int* __restrict__ bsum, int n)
{
    __shared__ int s[256];
    const int t = threadIdx.x;
    const int i = blockIdx.x * 256 + t;
    int v = (i < n) ? cnt[i] : 0;
    s[t] = v;
    __syncthreads();
    for (int off = 1; off < 256; off <<= 1) {
        int u = (t >= off) ? s[t - off] : 0;
        __syncthreads();
        s[t] += u;
        __syncthreads();
    }
    if (i < n) texc[i] = s[t] - v;
    if (t == 255) bsum[blockIdx.x] = s[255];
}

__global__ __launch_bounds__(256) void k_scan2(int* __restrict__ bsum, int nb)
{
    __shared__ int s[256];
    const int t = threadIdx.x;
    int v = (t < nb) ? bsum[t] : 0;
    s[t] = v;
    __syncthreads();
    for (int off = 1; off < 256; off <<= 1) {
        int u = (t >= off) ? s[t - off] : 0;
        __syncthreads();
        s[t] += u;
        __syncthreads();
    }
    if (t < nb) bsum[t] = s[t] - v;
}

__global__ __launch_bounds__(256) void k_scan3(const int* __restrict__ texc, const int* __restrict__ bsum,
                                               int* __restrict__ rp, int* __restrict__ cur, int n, int E)
{
    const int i = blockIdx.x * 256 + threadIdx.x;
    if (i < n) {
        int v = texc[i] + bsum[blockIdx.x];
        rp[i] = v;
        cur[i] = v;
    }
    if (i == 0) rp[n] = E;
}

__global__ __launch_bounds__(256) void k_scatter(const int* __restrict__ src, const int* __restrict__ dst,
                                                 int* __restrict__ cur, int* __restrict__ col, int E)
{
    int stride = gridDim.x * blockDim.x;
    for (int e = blockIdx.x * blockDim.x + threadIdx.x; e < E; e += stride) {
        int s = src[e];
        int pos = atomicAdd(&cur[s], 1);
        col[pos] = dst[e];
    }
}

// ---------------- Embedding: x = silu(concat(onehot, pos) @ embW + embB) ----------------
// k-chunked register-W: 32 W-values live at a time (no spill), chunk loop not unrolled.
__global__ __launch_bounds__(256) void k_embed(
    const float* __restrict__ oneh, const float* __restrict__ pos,
    const float* __restrict__ W, const float* __restrict__ bvec,
    float* __restrict__ x, float* __restrict__ x0, int N)
{
    const int t = threadIdx.x;
    const int h = t & 63, w = t >> 6;
    __shared__ float xin[EMB_NODES * 128];   // rows padded to 128 (zero-filled)
    const int n0 = blockIdx.x * EMB_NODES;
    for (int i = t; i < EMB_NODES * 128; i += 256) {
        int node = n0 + (i >> 7);
        int k = i & 127;
        float v = 0.f;
        if (node < N) {
            if (k < 118) v = oneh[(size_t)node * 118 + k];
            else if (k < 121) v = pos[(size_t)node * 3 + (k - 118)];
        }
        xin[i] = v;
    }
    __syncthreads();
    float acc[8];
    const float bb = bvec[h];
    #pragma unroll
    for (int j = 0; j < 8; ++j) acc[j] = bb;
    #pragma unroll 1
    for (int c = 0; c < 4; ++c) {
        float wE[32];
        #pragma unroll
        for (int k = 0; k < 32; ++k) {
            int kk = c * 32 + k;
            wE[k] = (kk < 121) ? W[kk * 64 + h] : 0.f;
        }
        #pragma unroll
        for (int j = 0; j < 8; ++j) {
            const float4* xr = reinterpret_cast<const float4*>(&xin[(w * 8 + j) * 128 + c * 32]);
            #pragma unroll
            for (int kk = 0; kk < 8; ++kk) {
                float4 xq = xr[kk];
                acc[j] = fmaf(xq.x, wE[4 * kk + 0], acc[j]);
                acc[j] = fmaf(xq.y, wE[4 * kk + 1], acc[j]);
                acc[j] = fmaf(xq.z, wE[4 * kk + 2], acc[j]);
                acc[j] = fmaf(xq.w, wE[4 * kk + 3], acc[j]);
            }
        }
    }
    #pragma unroll
    for (int j = 0; j < 8; ++j) {
        int gnode = n0 + w * 8 + j;
        if (gnode >= N) continue;
        float v = silu_f(acc[j]);
        x[(size_t)gnode * H + h] = v;
        x0[(size_t)gnode * H + h] = v;
    }
}

// ---------------- Per-layer node transform: A = x@Wt + ib (fp32) ; Bb = bf16(x@Wb) ----------------
// k-chunked register-W (16 per side live); B packed to bf16 via LDS repack, coalesced uint4 stores.
__global__ __launch_bounds__(256) void k_interact(
    const float* __restrict__ x, const float* __restrict__ Wg, const float* __restrict__ ib,
    float* __restrict__ A, unsigned* __restrict__ Bb, int N)
{
    const int t = threadIdx.x;
    const int h = t & 63, w = t >> 6;
    __shared__ float xl[MM_NODES * 64];
    __shared__ float bl[MM_NODES * 64];
    const int n0 = blockIdx.x * MM_NODES;
    for (int i = t; i < MM_NODES * 64; i += 256) {
        int g = n0 * 64 + i;
        xl[i] = (g < N * 64) ? x[g] : 0.f;
    }
    __syncthreads();
    float acca[8], accb[8];
    const float bias = ib[h];
    #pragma unroll
    for (int j = 0; j < 8; ++j) { acca[j] = bias; accb[j] = 0.f; }
    #pragma unroll 1
    for (int c = 0; c < 4; ++c) {
        float wAc[16], wBc[16];
        #pragma unroll
        for (int k = 0; k < 16; ++k) {
            wAc[k] = Wg[(c * 16 + k) * 64 + h];
            wBc[k] = Wg[(64 + c * 16 + k) * 64 + h];
        }
        #pragma unroll
        for (int j = 0; j < 8; ++j) {
            const float4* xr = reinterpret_cast<const float4*>(&xl[(w * 8 + j) * 64 + c * 16]);
            #pragma unroll
            for (int kk = 0; kk < 4; ++kk) {
                float4 xq = xr[kk];
                acca[j] = fmaf(xq.x, wAc[4 * kk + 0], acca[j]); accb[j] = fmaf(xq.x, wBc[4 * kk + 0], accb[j]);
                acca[j] = fmaf(xq.y, wAc[4 * kk + 1], acca[j]); accb[j] = fmaf(xq.y, wBc[4 * kk + 1], accb[j]);
                acca[j] = fmaf(xq.z, wAc[4 * kk + 2], acca[j]); accb[j] = fmaf(xq.z, wBc[4 * kk + 2], accb[j]);
                acca[j] = fmaf(xq.w, wAc[4 * kk + 3], acca[j]); accb[j] = fmaf(xq.w, wBc[4 * kk + 3], accb[j]);
            }
        }
    }
    #pragma unroll
    for (int j = 0; j < 8; ++j) {
        int node = w * 8 + j;
        int gnode = n0 + node;
        if (gnode < N) A[(size_t)gnode * H + h] = acca[j];
        bl[node * 64 + h] = accb[j];
    }
    __syncthreads();
    // pack 8 consecutive floats -> uint4 (8 bf16), coalesced global store
    {
        const float* bp = &bl[t * 8];
        uint4 o;
        o.x = pack2(bp[0], bp[1]);
        o.y = pack2(bp[2], bp[3]);
        o.z = pack2(bp[4], bp[5]);
        o.w = pack2(bp[6], bp[7]);
        int node = n0 + (t >> 3);
        if (node < N)
            reinterpret_cast<uint4*>(Bb)[(size_t)n0 * 8 + t] = o;
    }
}

// ---------------- Fused edge + update (+ final output projection) ----------------
// 16-lane group per node: gather bf16 B rows, accumulate m, v = x + 0.25*m staged in LDS,
// matmul vs LDS-staged uW, x_new = x + silu(...). LAST also emits the out row.
template <bool LAST>
__global__ __launch_bounds__(256) void k_edge_upd(
    const int* __restrict__ rp, const int* __restrict__ col,
    const float* __restrict__ A, const unsigned* __restrict__ Bb,
    float* __restrict__ x, const float* __restrict__ uWl, const float* __restrict__ ub,
    const float* __restrict__ x0, const float* __restrict__ oW, const float* __restrict__ ob,
    float* __restrict__ out, int N)
{
    __shared__ float Wl[64 * 64];          // update weights, [k][h]
    __shared__ float sv[16 * 68];          // per-group v rows, stride 68
    const int t = threadIdx.x;
    const int g = t >> 4;
    const int q = t & 15;
    {
        const float4* src4 = reinterpret_cast<const float4*>(uWl);
        float4* dst4 = reinterpret_cast<float4*>(Wl);
        #pragma unroll
        for (int i = 0; i < 4; ++i) dst4[t + 256 * i] = src4[t + 256 * i];
    }
    const int node = blockIdx.x * 16 + g;
    const bool valid = node < N;
    const size_t nidx = (size_t)(valid ? node : 0) * 16 + q;
    const float4* __restrict__ Av = reinterpret_cast<const float4*>(A);
    const uint2* __restrict__ Bv = reinterpret_cast<const uint2*>(Bb);
    float4* __restrict__ Xv = reinterpret_cast<float4*>(x);

    const float4 a = Av[nidx];
    const float4 xq = Xv[nidx];
    const int beg = valid ? rp[node] : 0;
    const int end = valid ? rp[node + 1] : 0;

    float4 acc = make_float4(0.f, 0.f, 0.f, 0.f);
    int j = beg;
    for (; j + 2 <= end; j += 2) {
        int d0 = col[j];
        int d1 = col[j + 1];
        uint2 u0 = Bv[(size_t)d0 * 16 + q];
        uint2 u1 = Bv[(size_t)d1 * 16 + q];
        float4 b0 = unpack4(u0);
        float4 b1 = unpack4(u1);
        acc.x += silu_f(a.x + b0.x) + silu_f(a.x + b1.x);
        acc.y += silu_f(a.y + b0.y) + silu_f(a.y + b1.y);
        acc.z += silu_f(a.z + b0.z) + silu_f(a.z + b1.z);
        acc.w += silu_f(a.w + b0.w) + silu_f(a.w + b1.w);
    }
    if (j < end) {
        int d = col[j];
        float4 b = unpack4(Bv[(size_t)d * 16 + q]);
        acc.x += silu_f(a.x + b.x); acc.y += silu_f(a.y + b.y);
        acc.z += silu_f(a.z + b.z); acc.w += silu_f(a.w + b.w);
    }
    // v = x + 0.25 * m
    float4 v;
    v.x = fmaf(0.25f, acc.x, xq.x); v.y = fmaf(0.25f, acc.y, xq.y);
    v.z = fmaf(0.25f, acc.z, xq.z); v.w = fmaf(0.25f, acc.w, xq.w);
    float* svg = &sv[g * 68];
    svg[q * 4 + 0] = v.x; svg[q * 4 + 1] = v.y;
    svg[q * 4 + 2] = v.z; svg[q * 4 + 3] = v.w;
    __syncthreads();
    float4 acc2 = reinterpret_cast<const float4*>(ub)[q];
    const float4* Wl4 = reinterpret_cast<const float4*>(Wl);
    #pragma unroll 8
    for (int k = 0; k < 64; ++k) {
        float vk = svg[k];
        float4 wq = Wl4[k * 16 + q];
        acc2.x = fmaf(vk, wq.x, acc2.x);
        acc2.y = fmaf(vk, wq.y, acc2.y);
        acc2.z = fmaf(vk, wq.z, acc2.z);
        acc2.w = fmaf(vk, wq.w, acc2.w);
    }
    float4 xn;
    xn.x = xq.x + silu_f(acc2.x); xn.y = xq.y + silu_f(acc2.y);
    xn.z = xq.z + silu_f(acc2.z); xn.w = xq.w + silu_f(acc2.w);
    if (valid) Xv[nidx] = xn;
    if (LAST) {
        const float4 x0q = reinterpret_cast<const float4*>(x0)[nidx];
        float f0 = xn.x + x0q.x, f1 = xn.y + x0q.y, f2 = xn.z + x0q.z, f3 = xn.w + x0q.w;
        float p0 = 0.f, p1 = 0.f, p2 = 0.f;
        const int k0 = 4 * q;
        p0 = fmaf(f0, oW[(k0 + 0) * 3 + 0], p0); p1 = fmaf(f0, oW[(k0 + 0) * 3 + 1], p1); p2 = fmaf(f0, oW[(k0 + 0) * 3 + 2], p2);
        p0 = fmaf(f1, oW[(k0 + 1) * 3 + 0], p0); p1 = fmaf(f1, oW[(k0 + 1) * 3 + 1], p1); p2 = fmaf(f1, oW[(k0 + 1) * 3 + 2], p2);
        p0 = fmaf(f2, oW[(k0 + 2) * 3 + 0], p0); p1 = fmaf(f2, oW[(k0 + 2) * 3 + 1], p1); p2 = fmaf(f2, oW[(k0 + 2) * 3 + 2], p2);
        p0 = fmaf(f3, oW[(k0 + 3) * 3 + 0], p0); p1 = fmaf(f3, oW[(k0 + 3) * 3 + 1], p1); p2 = fmaf(f3, oW[(k0 + 3) * 3 + 2], p2);
        #pragma unroll
        for (int off = 8; off; off >>= 1) {
            p0 += __shfl_xor(p0, off, 16);
            p1 += __shfl_xor(p1, off, 16);
            p2 += __shfl_xor(p2, off, 16);
        }
        if (valid && q == 0) {
            out[node * 3 + 0] = p0 + ob[0];
            out[node * 3 + 1] = p1 + ob[1];
            out[node * 3 + 2] = p2 + ob[2];
        }
    }
}

extern "C" void kernel_launch(void* const* d_in, const int* in_sizes, int n_in,
                              void* d_out, int out_size, void* d_ws, size_t ws_size,
                              hipStream_t stream)
{
    const float* oneh = (const float*)d_in[0];
    const float* pos  = (const float*)d_in[1];
    const int*   ei   = (const int*)d_in[2];
    const float* embW = (const float*)d_in[3];
    const float* embB = (const float*)d_in[4];
    const float* iW   = (const float*)d_in[5];   // [4][128][64]
    const float* iB   = (const float*)d_in[6];   // [4][64]
    const float* uW   = (const float*)d_in[7];   // [4][64][64]
    const float* uB   = (const float*)d_in[8];   // [4][64]
    const float* oW   = (const float*)d_in[9];   // [64][3]
    const float* oB   = (const float*)d_in[10];  // [3]

    const int N = in_sizes[0] / 118;
    const int E = in_sizes[2] / 2;
    const int* src = ei;
    const int* dst = ei + E;

    float* ws = (float*)d_ws;
    const size_t NH = (size_t)N * H;
    float* x  = ws;
    float* x0 = ws + NH;
    float* A  = ws + 2 * NH;
    unsigned* Bb = (unsigned*)(ws + 3 * NH);   // NH bf16 = NH/2 uints
    int* ibase = (int*)(ws + 3 * NH + NH / 2);
    int* cnt   = ibase;               // N
    int* cur   = ibase + N;           // N
    int* rp    = ibase + 2 * N;       // N+1
    int* col   = ibase + 3 * N + 1;   // E
    int* texc  = col + E;             // N
    int* bsum  = texc + N;            // <=256

    const int nbe = (N + EMB_NODES - 1) / EMB_NODES;
    const int nbm = (N + MM_NODES - 1) / MM_NODES;
    const int nbf = (N + 15) / 16;
    const int nbs = (N + 255) / 256;

    hipMemsetAsync(cnt, 0, (size_t)N * sizeof(int), stream);
    k_hist<<<1024, 256, 0, stream>>>(src, cnt, E);
    k_scan1<<<nbs, 256, 0, stream>>>(cnt, texc, bsum, N);
    k_scan2<<<1, 256, 0, stream>>>(bsum, nbs);
    k_scan3<<<nbs, 256, 0, stream>>>(texc, bsum, rp, cur, N, E);
    k_scatter<<<1024, 256, 0, stream>>>(src, dst, cur, col, E);

    k_embed<<<nbe, 256, 0, stream>>>(oneh, pos, embW, embB, x, x0, N);

    for (int l = 0; l < 4; ++l) {
        k_interact<<<nbm, 256, 0, stream>>>(x, iW + (size_t)l * 128 * 64, iB + l * 64, A, Bb, N);
        if (l < 3)
            k_edge_upd<false><<<nbf, 256, 0, stream>>>(rp, col, A, Bb, x,
                uW + (size_t)l * 64 * 64, uB + l * 64, x0, oW, oB, (float*)d_out, N);
        else
            k_edge_upd<true><<<nbf, 256, 0, stream>>>(rp, col, A, Bb, x,
                uW + (size_t)l * 64 * 64, uB + l * 64, x0, oW, oB, (float*)d_out, N);
    }
}

// Round 7
// 355.537 us; speedup vs baseline: 8.7775x; 1.2387x over previous
//
#include <hip/hip_runtime.h>

#define H 64

typedef __attribute__((ext_vector_type(8))) __bf16 bf16x8;
typedef __attribute__((ext_vector_type(4))) float f32x4;
union U16 { uint4 u; bf16x8 b; };

__device__ __forceinline__ float silu_f(float v) { return v / (1.0f + __expf(-v)); }

__device__ __forceinline__ unsigned bf16r(float f) {
    unsigned b = __float_as_uint(f);
    return (b + 0x7fffu + ((b >> 16) & 1u)) >> 16;   // RTNE (inputs finite)
}
__device__ __forceinline__ unsigned pack2(float lo, float hi) {
    return bf16r(lo) | (bf16r(hi) << 16);
}
__device__ __forceinline__ float4 unpack4(uint2 u) {
    float4 r;
    r.x = __uint_as_float(u.x << 16);
    r.y = __uint_as_float(u.x & 0xffff0000u);
    r.z = __uint_as_float(u.y << 16);
    r.w = __uint_as_float(u.y & 0xffff0000u);
    return r;
}

// ---------------- Weight pre-pack into MFMA fragment order (bf16) ----------------
// Fragment layout per 16x16x32 tile: lane l supplies 8 contiguous-k bf16;
// A: row=l&15, k=(l>>4)*8+e.  B: col=l&15, k=(l>>4)*8+e (stored lane-major, 16B/lane).
__global__ __launch_bounds__(256) void k_wpack(
    const float* __restrict__ embW, const float* __restrict__ iW,
    unsigned short* __restrict__ embF, unsigned short* __restrict__ iF)
{
    int t = blockIdx.x * 256 + threadIdx.x;
    if (t < 8192) {   // embF: ct(4) x kt(4) x lane(64) x e(8); K=128 pad of 121, N=64
        int e = t & 7, l = (t >> 3) & 63, kt = (t >> 9) & 3, ct = (t >> 11) & 3;
        int k = kt * 32 + (l >> 4) * 8 + e;
        int n = ct * 16 + (l & 15);
        float v = (k < 121) ? embW[k * 64 + n] : 0.f;
        embF[t] = (unsigned short)bf16r(v);
    }
    if (t < 32768) {  // iF: layer(4) x ct(8) x kt(2) x lane(64) x e(8); K=64, N=128 (=[Wt|Wb])
        int e = t & 7, l = (t >> 3) & 63, kt = (t >> 9) & 1, ct = (t >> 10) & 7, ly = (t >> 13) & 3;
        int k = kt * 32 + (l >> 4) * 8 + e;
        int n = ct * 16 + (l & 15);
        const float* W = iW + (size_t)ly * 128 * 64;
        float v = (n < 64) ? W[k * 64 + n] : W[(64 + k) * 64 + (n - 64)];
        iF[t] = (unsigned short)bf16r(v);
    }
}

// ---------------- CSR build ----------------
__global__ __launch_bounds__(256) void k_hist(const int* __restrict__ src, int* __restrict__ cnt, int E)
{
    int stride = gridDim.x * blockDim.x;
    for (int e = blockIdx.x * blockDim.x + threadIdx.x; e < E; e += stride)
        atomicAdd(&cnt[src[e]], 1);
}

__global__ __launch_bounds__(256) void k_scan1(const int* __restrict__ cnt,
                                               int* __restrict__ texc, int* __restrict__ bsum, int n)
{
    __shared__ int s[256];
    const int t = threadIdx.x;
    const int i = blockIdx.x * 256 + t;
    int v = (i < n) ? cnt[i] : 0;
    s[t] = v;
    __syncthreads();
    for (int off = 1; off < 256; off <<= 1) {
        int u = (t >= off) ? s[t - off] : 0;
        __syncthreads();
        s[t] += u;
        __syncthreads();
    }
    if (i < n) texc[i] = s[t] - v;
    if (t == 255) bsum[blockIdx.x] = s[255];
}

__global__ __launch_bounds__(256) void k_scan2(int* __restrict__ bsum, int nb)
{
    __shared__ int s[256];
    const int t = threadIdx.x;
    int v = (t < nb) ? bsum[t] : 0;
    s[t] = v;
    __syncthreads();
    for (int off = 1; off < 256; off <<= 1) {
        int u = (t >= off) ? s[t - off] : 0;
        __syncthreads();
        s[t] += u;
        __syncthreads();
    }
    if (t < nb) bsum[t] = s[t] - v;
}

__global__ __launch_bounds__(256) void k_scan3(const int* __restrict__ texc, const int* __restrict__ bsum,
                                               int* __restrict__ rp, int* __restrict__ cur, int n, int E)
{
    const int i = blockIdx.x * 256 + threadIdx.x;
    if (i < n) {
        int v = texc[i] + bsum[blockIdx.x];
        rp[i] = v;
        cur[i] = v;
    }
    if (i == 0) rp[n] = E;
}

__global__ __launch_bounds__(256) void k_scatter(const int* __restrict__ src, const int* __restrict__ dst,
                                                 int* __restrict__ cur, int* __restrict__ col, int E)
{
    int stride = gridDim.x * blockDim.x;
    for (int e = blockIdx.x * blockDim.x + threadIdx.x; e < E; e += stride) {
        int s = src[e];
        int pos = atomicAdd(&cur[s], 1);
        col[pos] = dst[e];
    }
}

// ---------------- Embedding (MFMA): x = silu(concat(onehot,pos) @ embW + embB) ----------------
// 32 nodes/block, K=128(pad), N=64. Input staged bf16 in LDS (stride 136: 2-way = free).
// LDS buffer aliased: xin (8704B) then ot[32][68] fp32 (8704B).
__global__ __launch_bounds__(256) void k_embed_mfma(
    const float* __restrict__ oneh, const float* __restrict__ pos,
    const uint4* __restrict__ Wf, const float* __restrict__ eb,
    float* __restrict__ x, float* __restrict__ x0, uint4* __restrict__ xb4, int N)
{
    __shared__ float ot[32 * 68];
    unsigned short* xin = (unsigned short*)ot;   // 32*136 ushorts == 8704 B
    const int t = threadIdx.x;
    const int w = t >> 6, l = t & 63;
    const int n0 = blockIdx.x * 32;
    for (int i = t; i < 32 * 128; i += 256) {
        int node = i >> 7, k = i & 127;
        int g = n0 + node;
        float v = 0.f;
        if (g < N) {
            if (k < 118) v = oneh[(size_t)g * 118 + k];
            else if (k < 121) v = pos[(size_t)g * 3 + (k - 118)];
        }
        xin[node * 136 + k] = (unsigned short)bf16r(v);
    }
    __syncthreads();
    const int rt = w & 1, ctb = (w >> 1) * 2;
    U16 af[4];
    #pragma unroll
    for (int kt = 0; kt < 4; ++kt)
        af[kt].u = *reinterpret_cast<const uint4*>(
            &xin[(rt * 16 + (l & 15)) * 136 + kt * 32 + (l >> 4) * 8]);
    f32x4 acc0 = {0.f, 0.f, 0.f, 0.f}, acc1 = {0.f, 0.f, 0.f, 0.f};
    #pragma unroll
    for (int kt = 0; kt < 4; ++kt) {
        U16 b0, b1;
        b0.u = Wf[((ctb + 0) * 4 + kt) * 64 + l];
        b1.u = Wf[((ctb + 1) * 4 + kt) * 64 + l];
        acc0 = __builtin_amdgcn_mfma_f32_16x16x32_bf16(af[kt].b, b0.b, acc0, 0, 0, 0);
        acc1 = __builtin_amdgcn_mfma_f32_16x16x32_bf16(af[kt].b, b1.b, acc1, 0, 0, 0);
    }
    __syncthreads();   // done with xin; reuse as ot
    #pragma unroll
    for (int r = 0; r < 4; ++r) {
        ot[(rt * 16 + (l >> 4) * 4 + r) * 68 + (ctb + 0) * 16 + (l & 15)] = acc0[r];
        ot[(rt * 16 + (l >> 4) * 4 + r) * 68 + (ctb + 1) * 16 + (l & 15)] = acc1[r];
    }
    __syncthreads();
    for (int v = t; v < 512; v += 256) {
        int node = v >> 4, q = v & 15;
        float4 bq = reinterpret_cast<const float4*>(eb)[q];
        float* p = &ot[node * 68 + q * 4];
        float4 o;
        o.x = silu_f(p[0] + bq.x); o.y = silu_f(p[1] + bq.y);
        o.z = silu_f(p[2] + bq.z); o.w = silu_f(p[3] + bq.w);
        int g = n0 + node;
        if (g < N) {
            reinterpret_cast<float4*>(x)[(size_t)g * 16 + q] = o;
            reinterpret_cast<float4*>(x0)[(size_t)g * 16 + q] = o;
        }
        p[0] = o.x; p[1] = o.y; p[2] = o.z; p[3] = o.w;
    }
    __syncthreads();
    {
        int node = t >> 3, j = t & 7;
        int g = n0 + node;
        if (g < N) {
            const float* p = &ot[node * 68 + j * 8];
            uint4 o;
            o.x = pack2(p[0], p[1]); o.y = pack2(p[2], p[3]);
            o.z = pack2(p[4], p[5]); o.w = pack2(p[6], p[7]);
            xb4[(size_t)g * 8 + j] = o;
        }
    }
}

// ---------------- Interact (MFMA): [A|B] = x_bf16 @ [Wt|Wb] ; A+=bias fp32, B->bf16 ----------------
// 32 nodes/block, M-tiles=2, N-tiles=8, K=64. A-frags straight from global xb (16B/lane).
__global__ __launch_bounds__(256) void k_interact_mfma(
    const uint4* __restrict__ xb4, const uint4* __restrict__ Wf, const float* __restrict__ ib,
    float* __restrict__ A, uint4* __restrict__ Bb4, int N)
{
    __shared__ float ot[32 * 132];
    const int t = threadIdx.x;
    const int w = t >> 6, l = t & 63;
    const int n0 = blockIdx.x * 32;
    const int rt = w & 1, ctb = (w >> 1) * 4;
    int row = n0 + rt * 16 + (l & 15);
    if (row >= N) row = N - 1;
    U16 a0, a1;
    a0.u = xb4[(size_t)row * 8 + (l >> 4)];
    a1.u = xb4[(size_t)row * 8 + 4 + (l >> 4)];
    f32x4 acc[4];
    #pragma unroll
    for (int c = 0; c < 4; ++c) acc[c] = (f32x4){0.f, 0.f, 0.f, 0.f};
    #pragma unroll
    for (int c = 0; c < 4; ++c) {
        int ct = ctb + c;
        U16 b0, b1;
        b0.u = Wf[(ct * 2 + 0) * 64 + l];
        b1.u = Wf[(ct * 2 + 1) * 64 + l];
        acc[c] = __builtin_amdgcn_mfma_f32_16x16x32_bf16(a0.b, b0.b, acc[c], 0, 0, 0);
        acc[c] = __builtin_amdgcn_mfma_f32_16x16x32_bf16(a1.b, b1.b, acc[c], 0, 0, 0);
    }
    #pragma unroll
    for (int c = 0; c < 4; ++c)
        #pragma unroll
        for (int r = 0; r < 4; ++r)
            ot[(rt * 16 + (l >> 4) * 4 + r) * 132 + (ctb + c) * 16 + (l & 15)] = acc[c][r];
    __syncthreads();
    for (int v = t; v < 512; v += 256) {   // A half + bias, fp32
        int node = v >> 4, q = v & 15;
        int g = n0 + node;
        if (g >= N) continue;
        float4 bq = reinterpret_cast<const float4*>(ib)[q];
        const float* p = &ot[node * 132 + q * 4];
        float4 o;
        o.x = p[0] + bq.x; o.y = p[1] + bq.y; o.z = p[2] + bq.z; o.w = p[3] + bq.w;
        reinterpret_cast<float4*>(A)[(size_t)g * 16 + q] = o;
    }
    {   // B half -> bf16
        int node = t >> 3, j = t & 7;
        int g = n0 + node;
        if (g < N) {
            const float* p = &ot[node * 132 + 64 + j * 8];
            uint4 o;
            o.x = pack2(p[0], p[1]); o.y = pack2(p[2], p[3]);
            o.z = pack2(p[4], p[5]); o.w = pack2(p[6], p[7]);
            Bb4[(size_t)g * 8 + j] = o;
        }
    }
}

// ---------------- Fused edge + update (+ final output projection) ----------------
template <bool LAST>
__global__ __launch_bounds__(256) void k_edge_upd(
    const int* __restrict__ rp, const int* __restrict__ col,
    const float* __restrict__ A, const unsigned* __restrict__ Bb,
    float* __restrict__ x, unsigned* __restrict__ xb,
    const float* __restrict__ uWl, const float* __restrict__ ub,
    const float* __restrict__ x0, const float* __restrict__ oW, const float* __restrict__ ob,
    float* __restrict__ out, int N)
{
    __shared__ float Wl[64 * 64];          // update weights, [k][h]
    __shared__ float sv[16 * 68];          // per-group v rows, stride 68
    const int t = threadIdx.x;
    const int g = t >> 4;
    const int q = t & 15;
    {
        const float4* src4 = reinterpret_cast<const float4*>(uWl);
        float4* dst4 = reinterpret_cast<float4*>(Wl);
        #pragma unroll
        for (int i = 0; i < 4; ++i) dst4[t + 256 * i] = src4[t + 256 * i];
    }
    const int node = blockIdx.x * 16 + g;
    const bool valid = node < N;
    const size_t nidx = (size_t)(valid ? node : 0) * 16 + q;
    const float4* __restrict__ Av = reinterpret_cast<const float4*>(A);
    const uint2* __restrict__ Bv = reinterpret_cast<const uint2*>(Bb);
    float4* __restrict__ Xv = reinterpret_cast<float4*>(x);

    const float4 a = Av[nidx];
    const float4 xq = Xv[nidx];
    const int beg = valid ? rp[node] : 0;
    const int end = valid ? rp[node + 1] : 0;

    float4 acc = make_float4(0.f, 0.f, 0.f, 0.f);
    int j = beg;
    for (; j + 2 <= end; j += 2) {
        int d0 = col[j];
        int d1 = col[j + 1];
        uint2 u0 = Bv[(size_t)d0 * 16 + q];
        uint2 u1 = Bv[(size_t)d1 * 16 + q];
        float4 b0 = unpack4(u0);
        float4 b1 = unpack4(u1);
        acc.x += silu_f(a.x + b0.x) + silu_f(a.x + b1.x);
        acc.y += silu_f(a.y + b0.y) + silu_f(a.y + b1.y);
        acc.z += silu_f(a.z + b0.z) + silu_f(a.z + b1.z);
        acc.w += silu_f(a.w + b0.w) + silu_f(a.w + b1.w);
    }
    if (j < end) {
        int d = col[j];
        float4 b = unpack4(Bv[(size_t)d * 16 + q]);
        acc.x += silu_f(a.x + b.x); acc.y += silu_f(a.y + b.y);
        acc.z += silu_f(a.z + b.z); acc.w += silu_f(a.w + b.w);
    }
    float4 v;
    v.x = fmaf(0.25f, acc.x, xq.x); v.y = fmaf(0.25f, acc.y, xq.y);
    v.z = fmaf(0.25f, acc.z, xq.z); v.w = fmaf(0.25f, acc.w, xq.w);
    float* svg = &sv[g * 68];
    svg[q * 4 + 0] = v.x; svg[q * 4 + 1] = v.y;
    svg[q * 4 + 2] = v.z; svg[q * 4 + 3] = v.w;
    __syncthreads();
    float4 acc2 = reinterpret_cast<const float4*>(ub)[q];
    const float4* Wl4 = reinterpret_cast<const float4*>(Wl);
    #pragma unroll 8
    for (int k = 0; k < 64; ++k) {
        float vk = svg[k];
        float4 wq = Wl4[k * 16 + q];
        acc2.x = fmaf(vk, wq.x, acc2.x);
        acc2.y = fmaf(vk, wq.y, acc2.y);
        acc2.z = fmaf(vk, wq.z, acc2.z);
        acc2.w = fmaf(vk, wq.w, acc2.w);
    }
    float4 xn;
    xn.x = xq.x + silu_f(acc2.x); xn.y = xq.y + silu_f(acc2.y);
    xn.z = xq.z + silu_f(acc2.z); xn.w = xq.w + silu_f(acc2.w);
    if (valid) {
        Xv[nidx] = xn;
        uint2 xo;
        xo.x = pack2(xn.x, xn.y);
        xo.y = pack2(xn.z, xn.w);
        reinterpret_cast<uint2*>(xb)[nidx] = xo;   // bf16 copy for next interact
    }
    if (LAST) {
        const float4 x0q = reinterpret_cast<const float4*>(x0)[nidx];
        float f0 = xn.x + x0q.x, f1 = xn.y + x0q.y, f2 = xn.z + x0q.z, f3 = xn.w + x0q.w;
        float p0 = 0.f, p1 = 0.f, p2 = 0.f;
        const int k0 = 4 * q;
        p0 = fmaf(f0, oW[(k0 + 0) * 3 + 0], p0); p1 = fmaf(f0, oW[(k0 + 0) * 3 + 1], p1); p2 = fmaf(f0, oW[(k0 + 0) * 3 + 2], p2);
        p0 = fmaf(f1, oW[(k0 + 1) * 3 + 0], p0); p1 = fmaf(f1, oW[(k0 + 1) * 3 + 1], p1); p2 = fmaf(f1, oW[(k0 + 1) * 3 + 2], p2);
        p0 = fmaf(f2, oW[(k0 + 2) * 3 + 0], p0); p1 = fmaf(f2, oW[(k0 + 2) * 3 + 1], p1); p2 = fmaf(f2, oW[(k0 + 2) * 3 + 2], p2);
        p0 = fmaf(f3, oW[(k0 + 3) * 3 + 0], p0); p1 = fmaf(f3, oW[(k0 + 3) * 3 + 1], p1); p2 = fmaf(f3, oW[(k0 + 3) * 3 + 2], p2);
        #pragma unroll
        for (int off = 8; off; off >>= 1) {
            p0 += __shfl_xor(p0, off, 16);
            p1 += __shfl_xor(p1, off, 16);
            p2 += __shfl_xor(p2, off, 16);
        }
        if (valid && q == 0) {
            out[node * 3 + 0] = p0 + ob[0];
            out[node * 3 + 1] = p1 + ob[1];
            out[node * 3 + 2] = p2 + ob[2];
        }
    }
}

extern "C" void kernel_launch(void* const* d_in, const int* in_sizes, int n_in,
                              void* d_out, int out_size, void* d_ws, size_t ws_size,
                              hipStream_t stream)
{
    const float* oneh = (const float*)d_in[0];
    const float* pos  = (const float*)d_in[1];
    const int*   ei   = (const int*)d_in[2];
    const float* embW = (const float*)d_in[3];
    const float* embB = (const float*)d_in[4];
    const float* iW   = (const float*)d_in[5];   // [4][128][64]
    const float* iB   = (const float*)d_in[6];   // [4][64]
    const float* uW   = (const float*)d_in[7];   // [4][64][64]
    const float* uB   = (const float*)d_in[8];   // [4][64]
    const float* oW   = (const float*)d_in[9];   // [64][3]
    const float* oB   = (const float*)d_in[10];  // [3]

    const int N = in_sizes[0] / 118;
    const int E = in_sizes[2] / 2;
    const int* src = ei;
    const int* dst = ei + E;

    float* ws = (float*)d_ws;
    const size_t NH = (size_t)N * H;
    float* x  = ws;
    float* x0 = ws + NH;
    float* A  = ws + 2 * NH;
    unsigned short* Bb   = (unsigned short*)(ws + 3 * NH);  // NH bf16
    unsigned short* xb   = Bb + NH;                          // NH bf16
    unsigned short* embF = xb + NH;                          // 8192
    unsigned short* iF   = embF + 8192;                      // 32768
    int* ibase = (int*)(iF + 32768);
    int* cnt   = ibase;               // N
    int* cur   = ibase + N;           // N
    int* rp    = ibase + 2 * N;       // N+1
    int* col   = ibase + 3 * N + 1;   // E
    int* texc  = col + E;             // N
    int* bsum  = texc + N;            // <=256

    const int nbm = (N + 31) / 32;
    const int nbf = (N + 15) / 16;
    const int nbs = (N + 255) / 256;

    k_wpack<<<128, 256, 0, stream>>>(embW, iW, embF, iF);

    hipMemsetAsync(cnt, 0, (size_t)N * sizeof(int), stream);
    k_hist<<<1024, 256, 0, stream>>>(src, cnt, E);
    k_scan1<<<nbs, 256, 0, stream>>>(cnt, texc, bsum, N);
    k_scan2<<<1, 256, 0, stream>>>(bsum, nbs);
    k_scan3<<<nbs, 256, 0, stream>>>(texc, bsum, rp, cur, N, E);
    k_scatter<<<1024, 256, 0, stream>>>(src, dst, cur, col, E);

    k_embed_mfma<<<nbm, 256, 0, stream>>>(oneh, pos, (const uint4*)embF, embB,
                                          x, x0, (uint4*)xb, N);

    for (int l = 0; l < 4; ++l) {
        k_interact_mfma<<<nbm, 256, 0, stream>>>((const uint4*)xb,
            (const uint4*)(iF + (size_t)l * 8192), iB + l * 64, A, (uint4*)Bb, N);
        if (l < 3)
            k_edge_upd<false><<<nbf, 256, 0, stream>>>(rp, col, A, (const unsigned*)Bb, x,
                (unsigned*)xb, uW + (size_t)l * 64 * 64, uB + l * 64, x0, oW, oB, (float*)d_out, N);
        else
            k_edge_upd<true><<<nbf, 256, 0, stream>>>(rp, col, A, (const unsigned*)Bb, x,
                (unsigned*)xb, uW + (size_t)l * 64 * 64, uB + l * 64, x0, oW, oB, (float*)d_out, N);
    }
}

// Round 8
// 292.542 us; speedup vs baseline: 10.6676x; 1.2153x over previous
//
#include <hip/hip_runtime.h>

#define H 64

typedef __attribute__((ext_vector_type(8))) __bf16 bf16x8;
typedef __attribute__((ext_vector_type(4))) float f32x4;
union U16 { uint4 u; bf16x8 b; };

__device__ __forceinline__ float silu_f(float v) {
    return v * __builtin_amdgcn_rcpf(1.0f + __expf(-v));   // rcp: ~1ulp, fine vs bf16 threshold
}

__device__ __forceinline__ unsigned bf16r(float f) {
    unsigned b = __float_as_uint(f);
    return (b + 0x7fffu + ((b >> 16) & 1u)) >> 16;   // RTNE (inputs finite)
}
__device__ __forceinline__ unsigned pack2(float lo, float hi) {
    return bf16r(lo) | (bf16r(hi) << 16);
}
__device__ __forceinline__ float4 unpack4(uint2 u) {
    float4 r;
    r.x = __uint_as_float(u.x << 16);
    r.y = __uint_as_float(u.x & 0xffff0000u);
    r.z = __uint_as_float(u.y << 16);
    r.w = __uint_as_float(u.y & 0xffff0000u);
    return r;
}

// ---------------- Weight pre-pack into MFMA fragment order (bf16) ----------------
// A: row=l&15, k=(l>>4)*8+e.  B: col=l&15, k=(l>>4)*8+e (lane-major, 16B/lane).
__global__ __launch_bounds__(256) void k_wpack(
    const float* __restrict__ embW, const float* __restrict__ iW, const float* __restrict__ uW,
    unsigned short* __restrict__ embF, unsigned short* __restrict__ iF, unsigned short* __restrict__ uF)
{
    int t = blockIdx.x * 256 + threadIdx.x;
    if (t < 8192) {   // embF: ct(4) x kt(4) x lane(64) x e(8); K=128 pad of 121, N=64
        int e = t & 7, l = (t >> 3) & 63, kt = (t >> 9) & 3, ct = (t >> 11) & 3;
        int k = kt * 32 + (l >> 4) * 8 + e;
        int n = ct * 16 + (l & 15);
        float v = (k < 121) ? embW[k * 64 + n] : 0.f;
        embF[t] = (unsigned short)bf16r(v);
    }
    if (t < 16384) {  // uF: layer(4) x ct(4) x kt(2) x lane(64) x e(8); K=64, N=64
        int e = t & 7, l = (t >> 3) & 63, kt = (t >> 9) & 1, ct = (t >> 10) & 3, ly = (t >> 12) & 3;
        int k = kt * 32 + (l >> 4) * 8 + e;
        int n = ct * 16 + (l & 15);
        uF[t] = (unsigned short)bf16r(uW[(size_t)ly * 4096 + k * 64 + n]);
    }
    if (t < 32768) {  // iF: layer(4) x ct(8) x kt(2) x lane(64) x e(8); K=64, N=128 (=[Wt|Wb])
        int e = t & 7, l = (t >> 3) & 63, kt = (t >> 9) & 1, ct = (t >> 10) & 7, ly = (t >> 13) & 3;
        int k = kt * 32 + (l >> 4) * 8 + e;
        int n = ct * 16 + (l & 15);
        const float* W = iW + (size_t)ly * 128 * 64;
        float v = (n < 64) ? W[k * 64 + n] : W[(64 + k) * 64 + (n - 64)];
        iF[t] = (unsigned short)bf16r(v);
    }
}

// ---------------- CSR build ----------------
__global__ __launch_bounds__(256) void k_hist(const int* __restrict__ src, int* __restrict__ cnt, int E)
{
    int stride = gridDim.x * blockDim.x;
    for (int e = blockIdx.x * blockDim.x + threadIdx.x; e < E; e += stride)
        atomicAdd(&cnt[src[e]], 1);
}

__global__ __launch_bounds__(256) void k_scan1(const int* __restrict__ cnt,
                                               int* __restrict__ texc, int* __restrict__ bsum, int n)
{
    __shared__ int s[256];
    const int t = threadIdx.x;
    const int i = blockIdx.x * 256 + t;
    int v = (i < n) ? cnt[i] : 0;
    s[t] = v;
    __syncthreads();
    for (int off = 1; off < 256; off <<= 1) {
        int u = (t >= off) ? s[t - off] : 0;
        __syncthreads();
        s[t] += u;
        __syncthreads();
    }
    if (i < n) texc[i] = s[t] - v;
    if (t == 255) bsum[blockIdx.x] = s[255];
}

__global__ __launch_bounds__(256) void k_scan2(int* __restrict__ bsum, int nb)
{
    __shared__ int s[256];
    const int t = threadIdx.x;
    int v = (t < nb) ? bsum[t] : 0;
    s[t] = v;
    __syncthreads();
    for (int off = 1; off < 256; off <<= 1) {
        int u = (t >= off) ? s[t - off] : 0;
        __syncthreads();
        s[t] += u;
        __syncthreads();
    }
    if (t < nb) bsum[t] = s[t] - v;
}

__global__ __launch_bounds__(256) void k_scan3(const int* __restrict__ texc, const int* __restrict__ bsum,
                                               int* __restrict__ rp, int* __restrict__ cur, int n, int E)
{
    const int i = blockIdx.x * 256 + threadIdx.x;
    if (i < n) {
        int v = texc[i] + bsum[blockIdx.x];
        rp[i] = v;
        cur[i] = v;
    }
    if (i == 0) rp[n] = E;
}

__global__ __launch_bounds__(256) void k_scatter(const int* __restrict__ src, const int* __restrict__ dst,
                                                 int* __restrict__ cur, int* __restrict__ col, int E)
{
    int stride = gridDim.x * blockDim.x;
    for (int e = blockIdx.x * blockDim.x + threadIdx.x; e < E; e += stride) {
        int s = src[e];
        int pos = atomicAdd(&cur[s], 1);
        col[pos] = dst[e];
    }
}

// ---------------- Embedding (MFMA): x = silu(concat(onehot,pos) @ embW + embB) ----------------
__global__ __launch_bounds__(256) void k_embed_mfma(
    const float* __restrict__ oneh, const float* __restrict__ pos,
    const uint4* __restrict__ Wf, const float* __restrict__ eb,
    float* __restrict__ x, float* __restrict__ x0, uint4* __restrict__ xb4, int N)
{
    __shared__ float ot[32 * 68];
    unsigned short* xin = (unsigned short*)ot;   // 32*136 ushorts == 8704 B
    const int t = threadIdx.x;
    const int w = t >> 6, l = t & 63;
    const int n0 = blockIdx.x * 32;
    for (int i = t; i < 32 * 128; i += 256) {
        int node = i >> 7, k = i & 127;
        int g = n0 + node;
        float v = 0.f;
        if (g < N) {
            if (k < 118) v = oneh[(size_t)g * 118 + k];
            else if (k < 121) v = pos[(size_t)g * 3 + (k - 118)];
        }
        xin[node * 136 + k] = (unsigned short)bf16r(v);
    }
    __syncthreads();
    const int rt = w & 1, ctb = (w >> 1) * 2;
    U16 af[4];
    #pragma unroll
    for (int kt = 0; kt < 4; ++kt)
        af[kt].u = *reinterpret_cast<const uint4*>(
            &xin[(rt * 16 + (l & 15)) * 136 + kt * 32 + (l >> 4) * 8]);
    f32x4 acc0 = {0.f, 0.f, 0.f, 0.f}, acc1 = {0.f, 0.f, 0.f, 0.f};
    #pragma unroll
    for (int kt = 0; kt < 4; ++kt) {
        U16 b0, b1;
        b0.u = Wf[((ctb + 0) * 4 + kt) * 64 + l];
        b1.u = Wf[((ctb + 1) * 4 + kt) * 64 + l];
        acc0 = __builtin_amdgcn_mfma_f32_16x16x32_bf16(af[kt].b, b0.b, acc0, 0, 0, 0);
        acc1 = __builtin_amdgcn_mfma_f32_16x16x32_bf16(af[kt].b, b1.b, acc1, 0, 0, 0);
    }
    __syncthreads();   // done with xin; reuse as ot
    #pragma unroll
    for (int r = 0; r < 4; ++r) {
        ot[(rt * 16 + (l >> 4) * 4 + r) * 68 + (ctb + 0) * 16 + (l & 15)] = acc0[r];
        ot[(rt * 16 + (l >> 4) * 4 + r) * 68 + (ctb + 1) * 16 + (l & 15)] = acc1[r];
    }
    __syncthreads();
    for (int v = t; v < 512; v += 256) {
        int node = v >> 4, q = v & 15;
        float4 bq = reinterpret_cast<const float4*>(eb)[q];
        float* p = &ot[node * 68 + q * 4];
        float4 o;
        o.x = silu_f(p[0] + bq.x); o.y = silu_f(p[1] + bq.y);
        o.z = silu_f(p[2] + bq.z); o.w = silu_f(p[3] + bq.w);
        int g = n0 + node;
        if (g < N) {
            reinterpret_cast<float4*>(x)[(size_t)g * 16 + q] = o;
            reinterpret_cast<float4*>(x0)[(size_t)g * 16 + q] = o;
        }
        p[0] = o.x; p[1] = o.y; p[2] = o.z; p[3] = o.w;
    }
    __syncthreads();
    {
        int node = t >> 3, j = t & 7;
        int g = n0 + node;
        if (g < N) {
            const float* p = &ot[node * 68 + j * 8];
            uint4 o;
            o.x = pack2(p[0], p[1]); o.y = pack2(p[2], p[3]);
            o.z = pack2(p[4], p[5]); o.w = pack2(p[6], p[7]);
            xb4[(size_t)g * 8 + j] = o;
        }
    }
}

// ---------------- Interact (MFMA): [A|B] = x_bf16 @ [Wt|Wb] ; A+=bias fp32, B->bf16 ----------------
__global__ __launch_bounds__(256) void k_interact_mfma(
    const uint4* __restrict__ xb4, const uint4* __restrict__ Wf, const float* __restrict__ ib,
    float* __restrict__ A, uint4* __restrict__ Bb4, int N)
{
    __shared__ float ot[32 * 132];
    const int t = threadIdx.x;
    const int w = t >> 6, l = t & 63;
    const int n0 = blockIdx.x * 32;
    const int rt = w & 1, ctb = (w >> 1) * 4;
    int row = n0 + rt * 16 + (l & 15);
    if (row >= N) row = N - 1;
    U16 a0, a1;
    a0.u = xb4[(size_t)row * 8 + (l >> 4)];
    a1.u = xb4[(size_t)row * 8 + 4 + (l >> 4)];
    f32x4 acc[4];
    #pragma unroll
    for (int c = 0; c < 4; ++c) acc[c] = (f32x4){0.f, 0.f, 0.f, 0.f};
    #pragma unroll
    for (int c = 0; c < 4; ++c) {
        int ct = ctb + c;
        U16 b0, b1;
        b0.u = Wf[(ct * 2 + 0) * 64 + l];
        b1.u = Wf[(ct * 2 + 1) * 64 + l];
        acc[c] = __builtin_amdgcn_mfma_f32_16x16x32_bf16(a0.b, b0.b, acc[c], 0, 0, 0);
        acc[c] = __builtin_amdgcn_mfma_f32_16x16x32_bf16(a1.b, b1.b, acc[c], 0, 0, 0);
    }
    #pragma unroll
    for (int c = 0; c < 4; ++c)
        #pragma unroll
        for (int r = 0; r < 4; ++r)
            ot[(rt * 16 + (l >> 4) * 4 + r) * 132 + (ctb + c) * 16 + (l & 15)] = acc[c][r];
    __syncthreads();
    for (int v = t; v < 512; v += 256) {   // A half + bias, fp32
        int node = v >> 4, q = v & 15;
        int g = n0 + node;
        if (g >= N) continue;
        float4 bq = reinterpret_cast<const float4*>(ib)[q];
        const float* p = &ot[node * 132 + q * 4];
        float4 o;
        o.x = p[0] + bq.x; o.y = p[1] + bq.y; o.z = p[2] + bq.z; o.w = p[3] + bq.w;
        reinterpret_cast<float4*>(A)[(size_t)g * 16 + q] = o;
    }
    {   // B half -> bf16
        int node = t >> 3, j = t & 7;
        int g = n0 + node;
        if (g < N) {
            const float* p = &ot[node * 132 + 64 + j * 8];
            uint4 o;
            o.x = pack2(p[0], p[1]); o.y = pack2(p[2], p[3]);
            o.z = pack2(p[4], p[5]); o.w = pack2(p[6], p[7]);
            Bb4[(size_t)g * 8 + j] = o;
        }
    }
}

// ---------------- Fused edge + MFMA update (+ final output projection) ----------------
// 16-lane group per node gathers m; v=x+0.25m -> bf16 LDS [16][64]; 4 waves each do
// one 16-col tile of v @ uW via 2 MFMA; silu result bounced via LDS back to gather layout.
template <bool LAST>
__global__ __launch_bounds__(256) void k_edge_upd(
    const int* __restrict__ rp, const int* __restrict__ col,
    const float* __restrict__ A, const unsigned* __restrict__ Bb,
    float* __restrict__ x, unsigned* __restrict__ xb,
    const uint4* __restrict__ uFf, const float* __restrict__ ub,
    const float* __restrict__ x0, const float* __restrict__ oW, const float* __restrict__ ob,
    float* __restrict__ out, int N)
{
    __shared__ unsigned short vb[16 * 64];   // bf16 v rows (node-major)
    __shared__ float sv[16 * 68];            // silu(update) rows, stride 68
    const int t = threadIdx.x;
    const int g = t >> 4, q = t & 15;
    const int w = t >> 6, l = t & 63;
    const int node = blockIdx.x * 16 + g;
    const bool valid = node < N;
    const size_t nidx = (size_t)(valid ? node : 0) * 16 + q;
    const float4* __restrict__ Av = reinterpret_cast<const float4*>(A);
    const uint2* __restrict__ Bv = reinterpret_cast<const uint2*>(Bb);
    float4* __restrict__ Xv = reinterpret_cast<float4*>(x);

    const float4 a = Av[nidx];
    const float4 xq = Xv[nidx];
    const int beg = valid ? rp[node] : 0;
    const int end = valid ? rp[node + 1] : 0;

    float4 acc = make_float4(0.f, 0.f, 0.f, 0.f);
    int j = beg;
    for (; j + 2 <= end; j += 2) {
        int d0 = col[j];
        int d1 = col[j + 1];
        uint2 u0 = Bv[(size_t)d0 * 16 + q];
        uint2 u1 = Bv[(size_t)d1 * 16 + q];
        float4 b0 = unpack4(u0);
        float4 b1 = unpack4(u1);
        acc.x += silu_f(a.x + b0.x) + silu_f(a.x + b1.x);
        acc.y += silu_f(a.y + b0.y) + silu_f(a.y + b1.y);
        acc.z += silu_f(a.z + b0.z) + silu_f(a.z + b1.z);
        acc.w += silu_f(a.w + b0.w) + silu_f(a.w + b1.w);
    }
    if (j < end) {
        int d = col[j];
        float4 b = unpack4(Bv[(size_t)d * 16 + q]);
        acc.x += silu_f(a.x + b.x); acc.y += silu_f(a.y + b.y);
        acc.z += silu_f(a.z + b.z); acc.w += silu_f(a.w + b.w);
    }
    float4 v;
    v.x = fmaf(0.25f, acc.x, xq.x); v.y = fmaf(0.25f, acc.y, xq.y);
    v.z = fmaf(0.25f, acc.z, xq.z); v.w = fmaf(0.25f, acc.w, xq.w);
    {
        uint2 vo;
        vo.x = pack2(v.x, v.y);
        vo.y = pack2(v.z, v.w);
        *reinterpret_cast<uint2*>(&vb[g * 64 + q * 4]) = vo;
    }
    __syncthreads();
    // MFMA: A-frag = vb rows (same for all waves), B-frag = uW tile ct=w
    {
        U16 a0, a1, b0, b1;
        a0.u = *reinterpret_cast<const uint4*>(&vb[(l & 15) * 64 + (l >> 4) * 8]);
        a1.u = *reinterpret_cast<const uint4*>(&vb[(l & 15) * 64 + 32 + (l >> 4) * 8]);
        b0.u = uFf[(w * 2 + 0) * 64 + l];
        b1.u = uFf[(w * 2 + 1) * 64 + l];
        f32x4 uacc = {0.f, 0.f, 0.f, 0.f};
        uacc = __builtin_amdgcn_mfma_f32_16x16x32_bf16(a0.b, b0.b, uacc, 0, 0, 0);
        uacc = __builtin_amdgcn_mfma_f32_16x16x32_bf16(a1.b, b1.b, uacc, 0, 0, 0);
        const int h = w * 16 + (l & 15);
        const float ubh = ub[h];
        #pragma unroll
        for (int r = 0; r < 4; ++r)
            sv[((l >> 4) * 4 + r) * 68 + h] = silu_f(uacc[r] + ubh);
    }
    __syncthreads();
    const float4 s = *reinterpret_cast<const float4*>(&sv[g * 68 + q * 4]);
    float4 xn;
    xn.x = xq.x + s.x; xn.y = xq.y + s.y;
    xn.z = xq.z + s.z; xn.w = xq.w + s.w;
    if (valid) {
        Xv[nidx] = xn;
        uint2 xo;
        xo.x = pack2(xn.x, xn.y);
        xo.y = pack2(xn.z, xn.w);
        reinterpret_cast<uint2*>(xb)[nidx] = xo;   // bf16 copy for next interact
    }
    if (LAST) {
        const float4 x0q = reinterpret_cast<const float4*>(x0)[nidx];
        float f0 = xn.x + x0q.x, f1 = xn.y + x0q.y, f2 = xn.z + x0q.z, f3 = xn.w + x0q.w;
        float p0 = 0.f, p1 = 0.f, p2 = 0.f;
        const int k0 = 4 * q;
        p0 = fmaf(f0, oW[(k0 + 0) * 3 + 0], p0); p1 = fmaf(f0, oW[(k0 + 0) * 3 + 1], p1); p2 = fmaf(f0, oW[(k0 + 0) * 3 + 2], p2);
        p0 = fmaf(f1, oW[(k0 + 1) * 3 + 0], p0); p1 = fmaf(f1, oW[(k0 + 1) * 3 + 1], p1); p2 = fmaf(f1, oW[(k0 + 1) * 3 + 2], p2);
        p0 = fmaf(f2, oW[(k0 + 2) * 3 + 0], p0); p1 = fmaf(f2, oW[(k0 + 2) * 3 + 1], p1); p2 = fmaf(f2, oW[(k0 + 2) * 3 + 2], p2);
        p0 = fmaf(f3, oW[(k0 + 3) * 3 + 0], p0); p1 = fmaf(f3, oW[(k0 + 3) * 3 + 1], p1); p2 = fmaf(f3, oW[(k0 + 3) * 3 + 2], p2);
        #pragma unroll
        for (int off = 8; off; off >>= 1) {
            p0 += __shfl_xor(p0, off, 16);
            p1 += __shfl_xor(p1, off, 16);
            p2 += __shfl_xor(p2, off, 16);
        }
        if (valid && q == 0) {
            out[node * 3 + 0] = p0 + ob[0];
            out[node * 3 + 1] = p1 + ob[1];
            out[node * 3 + 2] = p2 + ob[2];
        }
    }
}

extern "C" void kernel_launch(void* const* d_in, const int* in_sizes, int n_in,
                              void* d_out, int out_size, void* d_ws, size_t ws_size,
                              hipStream_t stream)
{
    const float* oneh = (const float*)d_in[0];
    const float* pos  = (const float*)d_in[1];
    const int*   ei   = (const int*)d_in[2];
    const float* embW = (const float*)d_in[3];
    const float* embB = (const float*)d_in[4];
    const float* iW   = (const float*)d_in[5];   // [4][128][64]
    const float* iB   = (const float*)d_in[6];   // [4][64]
    const float* uW   = (const float*)d_in[7];   // [4][64][64]
    const float* uB   = (const float*)d_in[8];   // [4][64]
    const float* oW   = (const float*)d_in[9];   // [64][3]
    const float* oB   = (const float*)d_in[10];  // [3]

    const int N = in_sizes[0] / 118;
    const int E = in_sizes[2] / 2;
    const int* src = ei;
    const int* dst = ei + E;

    float* ws = (float*)d_ws;
    const size_t NH = (size_t)N * H;
    float* x  = ws;
    float* x0 = ws + NH;
    float* A  = ws + 2 * NH;
    unsigned short* Bb   = (unsigned short*)(ws + 3 * NH);  // NH bf16
    unsigned short* xb   = Bb + NH;                          // NH bf16
    unsigned short* embF = xb + NH;                          // 8192
    unsigned short* iF   = embF + 8192;                      // 32768
    unsigned short* uFf  = iF + 32768;                       // 16384
    int* ibase = (int*)(uFf + 16384);
    int* cnt   = ibase;               // N
    int* cur   = ibase + N;           // N
    int* rp    = ibase + 2 * N;       // N+1
    int* col   = ibase + 3 * N + 1;   // E
    int* texc  = col + E;             // N
    int* bsum  = texc + N;            // <=256

    const int nbm = (N + 31) / 32;
    const int nbf = (N + 15) / 16;
    const int nbs = (N + 255) / 256;

    k_wpack<<<128, 256, 0, stream>>>(embW, iW, uW, embF, iF, uFf);

    hipMemsetAsync(cnt, 0, (size_t)N * sizeof(int), stream);
    k_hist<<<1024, 256, 0, stream>>>(src, cnt, E);
    k_scan1<<<nbs, 256, 0, stream>>>(cnt, texc, bsum, N);
    k_scan2<<<1, 256, 0, stream>>>(bsum, nbs);
    k_scan3<<<nbs, 256, 0, stream>>>(texc, bsum, rp, cur, N, E);
    k_scatter<<<1024, 256, 0, stream>>>(src, dst, cur, col, E);

    k_embed_mfma<<<nbm, 256, 0, stream>>>(oneh, pos, (const uint4*)embF, embB,
                                          x, x0, (uint4*)xb, N);

    for (int l = 0; l < 4; ++l) {
        k_interact_mfma<<<nbm, 256, 0, stream>>>((const uint4*)xb,
            (const uint4*)(iF + (size_t)l * 8192), iB + l * 64, A, (uint4*)Bb, N);
        if (l < 3)
            k_edge_upd<false><<<nbf, 256, 0, stream>>>(rp, col, A, (const unsigned*)Bb, x,
                (unsigned*)xb, (const uint4*)(uFf + (size_t)l * 4096), uB + l * 64,
                x0, oW, oB, (float*)d_out, N);
        else
            k_edge_upd<true><<<nbf, 256, 0, stream>>>(rp, col, A, (const unsigned*)Bb, x,
                (unsigned*)xb, (const uint4*)(uFf + (size_t)l * 4096), uB + l * 64,
                x0, oW, oB, (float*)d_out, N);
    }
}

// Round 9
// 258.743 us; speedup vs baseline: 12.0611x; 1.1306x over previous
//
#include <hip/hip_runtime.h>

#define H 64

typedef __attribute__((ext_vector_type(8))) __bf16 bf16x8;
typedef __attribute__((ext_vector_type(4))) float f32x4;
union U16 { uint4 u; bf16x8 b; };

__device__ __forceinline__ float silu_f(float v) {
    return v * __builtin_amdgcn_rcpf(1.0f + __expf(-v));
}

__device__ __forceinline__ unsigned bf16r(float f) {
    unsigned b = __float_as_uint(f);
    return (b + 0x7fffu + ((b >> 16) & 1u)) >> 16;   // RTNE (inputs finite)
}
__device__ __forceinline__ unsigned pack2(float lo, float hi) {
    return bf16r(lo) | (bf16r(hi) << 16);
}
__device__ __forceinline__ float4 unpack4(uint2 u) {
    float4 r;
    r.x = __uint_as_float(u.x << 16);
    r.y = __uint_as_float(u.x & 0xffff0000u);
    r.z = __uint_as_float(u.y << 16);
    r.w = __uint_as_float(u.y & 0xffff0000u);
    return r;
}

// ---------------- Weight pre-pack into MFMA fragment order (bf16) ----------------
// A: row=l&15, k=(l>>4)*8+e.  B: col=l&15, k=(l>>4)*8+e (lane-major, 16B/lane).
__global__ __launch_bounds__(256) void k_wpack(
    const float* __restrict__ embW, const float* __restrict__ iW, const float* __restrict__ uW,
    unsigned short* __restrict__ embF, unsigned short* __restrict__ iF, unsigned short* __restrict__ uF)
{
    int t = blockIdx.x * 256 + threadIdx.x;
    if (t < 8192) {   // embF: ct(4) x kt(4) x lane(64) x e(8); K=128 pad of 121, N=64
        int e = t & 7, l = (t >> 3) & 63, kt = (t >> 9) & 3, ct = (t >> 11) & 3;
        int k = kt * 32 + (l >> 4) * 8 + e;
        int n = ct * 16 + (l & 15);
        float v = (k < 121) ? embW[k * 64 + n] : 0.f;
        embF[t] = (unsigned short)bf16r(v);
    }
    if (t < 16384) {  // uF: layer(4) x ct(4) x kt(2) x lane(64) x e(8); K=64, N=64
        int e = t & 7, l = (t >> 3) & 63, kt = (t >> 9) & 1, ct = (t >> 10) & 3, ly = (t >> 12) & 3;
        int k = kt * 32 + (l >> 4) * 8 + e;
        int n = ct * 16 + (l & 15);
        uF[t] = (unsigned short)bf16r(uW[(size_t)ly * 4096 + k * 64 + n]);
    }
    if (t < 32768) {  // iF: layer(4) x ct(8) x kt(2) x lane(64) x e(8); K=64, N=128 (=[Wt|Wb])
        int e = t & 7, l = (t >> 3) & 63, kt = (t >> 9) & 1, ct = (t >> 10) & 7, ly = (t >> 13) & 3;
        int k = kt * 32 + (l >> 4) * 8 + e;
        int n = ct * 16 + (l & 15);
        const float* W = iW + (size_t)ly * 128 * 64;
        float v = (n < 64) ? W[k * 64 + n] : W[(64 + k) * 64 + (n - 64)];
        iF[t] = (unsigned short)bf16r(v);
    }
}

// ---------------- CSR build ----------------
__global__ __launch_bounds__(256) void k_hist(const int* __restrict__ src, int* __restrict__ cnt, int E)
{
    int stride = gridDim.x * blockDim.x;
    for (int e = blockIdx.x * blockDim.x + threadIdx.x; e < E; e += stride)
        atomicAdd(&cnt[src[e]], 1);
}

__global__ __launch_bounds__(256) void k_scan1(const int* __restrict__ cnt,
                                               int* __restrict__ texc, int* __restrict__ bsum, int n)
{
    __shared__ int s[256];
    const int t = threadIdx.x;
    const int i = blockIdx.x * 256 + t;
    int v = (i < n) ? cnt[i] : 0;
    s[t] = v;
    __syncthreads();
    for (int off = 1; off < 256; off <<= 1) {
        int u = (t >= off) ? s[t - off] : 0;
        __syncthreads();
        s[t] += u;
        __syncthreads();
    }
    if (i < n) texc[i] = s[t] - v;
    if (t == 255) bsum[blockIdx.x] = s[255];
}

__global__ __launch_bounds__(256) void k_scan2(int* __restrict__ bsum, int nb)
{
    __shared__ int s[256];
    const int t = threadIdx.x;
    int v = (t < nb) ? bsum[t] : 0;
    s[t] = v;
    __syncthreads();
    for (int off = 1; off < 256; off <<= 1) {
        int u = (t >= off) ? s[t - off] : 0;
        __syncthreads();
        s[t] += u;
        __syncthreads();
    }
    if (t < nb) bsum[t] = s[t] - v;
}

__global__ __launch_bounds__(256) void k_scan3(const int* __restrict__ texc, const int* __restrict__ bsum,
                                               int* __restrict__ rp, int* __restrict__ cur, int n, int E)
{
    const int i = blockIdx.x * 256 + threadIdx.x;
    if (i < n) {
        int v = texc[i] + bsum[blockIdx.x];
        rp[i] = v;
        cur[i] = v;
    }
    if (i == 0) rp[n] = E;
}

__global__ __launch_bounds__(256) void k_scatter(const int* __restrict__ src, const int* __restrict__ dst,
                                                 int* __restrict__ cur, int* __restrict__ col, int E)
{
    int stride = gridDim.x * blockDim.x;
    for (int e = blockIdx.x * blockDim.x + threadIdx.x; e < E; e += stride) {
        int s = src[e];
        int pos = atomicAdd(&cur[s], 1);
        col[pos] = dst[e];
    }
}

// ---------------- Embedding + layer-0 interact (MFMA) ----------------
// x = silu(concat(onehot,pos) @ embW + embB); then A0/Bb0 = x @ [Wt|Wb] of layer 0.
__global__ __launch_bounds__(256) void k_embed_mfma(
    const float* __restrict__ oneh, const float* __restrict__ pos,
    const uint4* __restrict__ Wf, const float* __restrict__ eb,
    const uint4* __restrict__ iFn, const float* __restrict__ ibn,
    float* __restrict__ x, float* __restrict__ x0,
    float* __restrict__ Aout, unsigned short* __restrict__ Bout, int N)
{
    __shared__ float ot[32 * 68];
    __shared__ unsigned short xbuf[32 * 72];
    unsigned short* xin = (unsigned short*)ot;   // 32*136 ushorts == 8704 B (aliased)
    const int t = threadIdx.x;
    const int w = t >> 6, l = t & 63;
    const int n0 = blockIdx.x * 32;
    for (int i = t; i < 32 * 128; i += 256) {
        int node = i >> 7, k = i & 127;
        int g = n0 + node;
        float v = 0.f;
        if (g < N) {
            if (k < 118) v = oneh[(size_t)g * 118 + k];
            else if (k < 121) v = pos[(size_t)g * 3 + (k - 118)];
        }
        xin[node * 136 + k] = (unsigned short)bf16r(v);
    }
    __syncthreads();
    const int rt = w & 1, ctb = (w >> 1) * 2;
    U16 af[4];
    #pragma unroll
    for (int kt = 0; kt < 4; ++kt)
        af[kt].u = *reinterpret_cast<const uint4*>(
            &xin[(rt * 16 + (l & 15)) * 136 + kt * 32 + (l >> 4) * 8]);
    f32x4 acc0 = {0.f, 0.f, 0.f, 0.f}, acc1 = {0.f, 0.f, 0.f, 0.f};
    #pragma unroll
    for (int kt = 0; kt < 4; ++kt) {
        U16 b0, b1;
        b0.u = Wf[((ctb + 0) * 4 + kt) * 64 + l];
        b1.u = Wf[((ctb + 1) * 4 + kt) * 64 + l];
        acc0 = __builtin_amdgcn_mfma_f32_16x16x32_bf16(af[kt].b, b0.b, acc0, 0, 0, 0);
        acc1 = __builtin_amdgcn_mfma_f32_16x16x32_bf16(af[kt].b, b1.b, acc1, 0, 0, 0);
    }
    __syncthreads();   // done with xin; reuse as ot
    #pragma unroll
    for (int r = 0; r < 4; ++r) {
        ot[(rt * 16 + (l >> 4) * 4 + r) * 68 + (ctb + 0) * 16 + (l & 15)] = acc0[r];
        ot[(rt * 16 + (l >> 4) * 4 + r) * 68 + (ctb + 1) * 16 + (l & 15)] = acc1[r];
    }
    __syncthreads();
    for (int v = t; v < 512; v += 256) {
        int node = v >> 4, q = v & 15;
        float4 bq = reinterpret_cast<const float4*>(eb)[q];
        float* p = &ot[node * 68 + q * 4];
        float4 o;
        o.x = silu_f(p[0] + bq.x); o.y = silu_f(p[1] + bq.y);
        o.z = silu_f(p[2] + bq.z); o.w = silu_f(p[3] + bq.w);
        int g = n0 + node;
        if (g < N) {
            reinterpret_cast<float4*>(x)[(size_t)g * 16 + q] = o;
            reinterpret_cast<float4*>(x0)[(size_t)g * 16 + q] = o;
        }
        p[0] = o.x; p[1] = o.y; p[2] = o.z; p[3] = o.w;
    }
    __syncthreads();
    {   // pack x rows bf16 into xbuf (stride 72)
        int node = t >> 3, j = t & 7;
        const float* p = &ot[node * 68 + j * 8];
        uint4 o;
        o.x = pack2(p[0], p[1]); o.y = pack2(p[2], p[3]);
        o.z = pack2(p[4], p[5]); o.w = pack2(p[6], p[7]);
        *reinterpret_cast<uint4*>(&xbuf[node * 72 + j * 8]) = o;
    }
    __syncthreads();
    // layer-0 interact: 2 M-tiles, wave w handles ct_A=w (A cols) and ct_B=w+4 (B cols)
    #pragma unroll
    for (int mt = 0; mt < 2; ++mt) {
        U16 a0, a1, bA0, bA1, bB0, bB1;
        a0.u = *reinterpret_cast<const uint4*>(&xbuf[(mt * 16 + (l & 15)) * 72 + (l >> 4) * 8]);
        a1.u = *reinterpret_cast<const uint4*>(&xbuf[(mt * 16 + (l & 15)) * 72 + 32 + (l >> 4) * 8]);
        bA0.u = iFn[(w * 2 + 0) * 64 + l];
        bA1.u = iFn[(w * 2 + 1) * 64 + l];
        bB0.u = iFn[((w + 4) * 2 + 0) * 64 + l];
        bB1.u = iFn[((w + 4) * 2 + 1) * 64 + l];
        f32x4 accA = {0.f, 0.f, 0.f, 0.f}, accB = {0.f, 0.f, 0.f, 0.f};
        accA = __builtin_amdgcn_mfma_f32_16x16x32_bf16(a0.b, bA0.b, accA, 0, 0, 0);
        accA = __builtin_amdgcn_mfma_f32_16x16x32_bf16(a1.b, bA1.b, accA, 0, 0, 0);
        accB = __builtin_amdgcn_mfma_f32_16x16x32_bf16(a0.b, bB0.b, accB, 0, 0, 0);
        accB = __builtin_amdgcn_mfma_f32_16x16x32_bf16(a1.b, bB1.b, accB, 0, 0, 0);
        const int colA = w * 16 + (l & 15);
        const float biasA = ibn[colA];
        #pragma unroll
        for (int r = 0; r < 4; ++r) {
            int gn = n0 + mt * 16 + (l >> 4) * 4 + r;
            if (gn < N) {
                Aout[(size_t)gn * 64 + colA] = accA[r] + biasA;
                Bout[(size_t)gn * 64 + colA] = (unsigned short)bf16r(accB[r]);
            }
        }
    }
}

// ---------------- Fused edge + MFMA update + next-layer interact (+ final out) ----------------
template <bool LAST>
__global__ __launch_bounds__(256) void k_edge_upd(
    const int* __restrict__ rp, const int* __restrict__ col,
    const float* __restrict__ A, const unsigned* __restrict__ Bb,
    float* __restrict__ x,
    const uint4* __restrict__ uFf, const float* __restrict__ ub,
    const uint4* __restrict__ iFn, const float* __restrict__ ibn,
    float* __restrict__ Aout, unsigned short* __restrict__ Bout,
    const float* __restrict__ x0, const float* __restrict__ oW, const float* __restrict__ ob,
    float* __restrict__ out, int N)
{
    __shared__ unsigned short vb[16 * 72];   // bf16 rows, stride 72 (bank spread)
    __shared__ float sv[16 * 68];            // silu(update) rows, stride 68
    const int t = threadIdx.x;
    const int g = t >> 4, q = t & 15;
    const int w = t >> 6, l = t & 63;
    const int node = blockIdx.x * 16 + g;
    const bool valid = node < N;
    const size_t nidx = (size_t)(valid ? node : 0) * 16 + q;
    const float4* __restrict__ Av = reinterpret_cast<const float4*>(A);
    const uint2* __restrict__ Bv = reinterpret_cast<const uint2*>(Bb);
    float4* __restrict__ Xv = reinterpret_cast<float4*>(x);

    const float4 a = Av[nidx];
    const float4 xq = Xv[nidx];
    const int beg = valid ? rp[node] : 0;
    const int end = valid ? rp[node + 1] : 0;

    float4 acc = make_float4(0.f, 0.f, 0.f, 0.f);
    int j = beg;
    for (; j + 4 <= end; j += 4) {
        int d0 = col[j], d1 = col[j + 1], d2 = col[j + 2], d3 = col[j + 3];
        float4 b0 = unpack4(Bv[(size_t)d0 * 16 + q]);
        float4 b1 = unpack4(Bv[(size_t)d1 * 16 + q]);
        float4 b2 = unpack4(Bv[(size_t)d2 * 16 + q]);
        float4 b3 = unpack4(Bv[(size_t)d3 * 16 + q]);
        acc.x += silu_f(a.x + b0.x) + silu_f(a.x + b1.x) + silu_f(a.x + b2.x) + silu_f(a.x + b3.x);
        acc.y += silu_f(a.y + b0.y) + silu_f(a.y + b1.y) + silu_f(a.y + b2.y) + silu_f(a.y + b3.y);
        acc.z += silu_f(a.z + b0.z) + silu_f(a.z + b1.z) + silu_f(a.z + b2.z) + silu_f(a.z + b3.z);
        acc.w += silu_f(a.w + b0.w) + silu_f(a.w + b1.w) + silu_f(a.w + b2.w) + silu_f(a.w + b3.w);
    }
    for (; j < end; ++j) {
        int d = col[j];
        float4 b = unpack4(Bv[(size_t)d * 16 + q]);
        acc.x += silu_f(a.x + b.x); acc.y += silu_f(a.y + b.y);
        acc.z += silu_f(a.z + b.z); acc.w += silu_f(a.w + b.w);
    }
    float4 v;
    v.x = fmaf(0.25f, acc.x, xq.x); v.y = fmaf(0.25f, acc.y, xq.y);
    v.z = fmaf(0.25f, acc.z, xq.z); v.w = fmaf(0.25f, acc.w, xq.w);
    {
        uint2 vo;
        vo.x = pack2(v.x, v.y);
        vo.y = pack2(v.z, v.w);
        *reinterpret_cast<uint2*>(&vb[g * 72 + q * 4]) = vo;
    }
    __syncthreads();
    // update MFMA: A-frag = vb rows, B-frag = uW tile ct=w
    {
        U16 a0, a1, b0, b1;
        a0.u = *reinterpret_cast<const uint4*>(&vb[(l & 15) * 72 + (l >> 4) * 8]);
        a1.u = *reinterpret_cast<const uint4*>(&vb[(l & 15) * 72 + 32 + (l >> 4) * 8]);
        b0.u = uFf[(w * 2 + 0) * 64 + l];
        b1.u = uFf[(w * 2 + 1) * 64 + l];
        f32x4 uacc = {0.f, 0.f, 0.f, 0.f};
        uacc = __builtin_amdgcn_mfma_f32_16x16x32_bf16(a0.b, b0.b, uacc, 0, 0, 0);
        uacc = __builtin_amdgcn_mfma_f32_16x16x32_bf16(a1.b, b1.b, uacc, 0, 0, 0);
        const int h = w * 16 + (l & 15);
        const float ubh = ub[h];
        #pragma unroll
        for (int r = 0; r < 4; ++r)
            sv[((l >> 4) * 4 + r) * 68 + h] = silu_f(uacc[r] + ubh);
    }
    __syncthreads();
    const float4 s = *reinterpret_cast<const float4*>(&sv[g * 68 + q * 4]);
    float4 xn;
    xn.x = xq.x + s.x; xn.y = xq.y + s.y;
    xn.z = xq.z + s.z; xn.w = xq.w + s.w;
    if (valid && !LAST) Xv[nidx] = xn;
    if (!LAST) {
        // next-layer interact: stage xn bf16, one M-tile, ct_A=w / ct_B=w+4 per wave
        uint2 xo;
        xo.x = pack2(xn.x, xn.y);
        xo.y = pack2(xn.z, xn.w);
        *reinterpret_cast<uint2*>(&vb[g * 72 + q * 4]) = xo;
        __syncthreads();
        U16 a0, a1, bA0, bA1, bB0, bB1;
        a0.u = *reinterpret_cast<const uint4*>(&vb[(l & 15) * 72 + (l >> 4) * 8]);
        a1.u = *reinterpret_cast<const uint4*>(&vb[(l & 15) * 72 + 32 + (l >> 4) * 8]);
        bA0.u = iFn[(w * 2 + 0) * 64 + l];
        bA1.u = iFn[(w * 2 + 1) * 64 + l];
        bB0.u = iFn[((w + 4) * 2 + 0) * 64 + l];
        bB1.u = iFn[((w + 4) * 2 + 1) * 64 + l];
        f32x4 accA = {0.f, 0.f, 0.f, 0.f}, accB = {0.f, 0.f, 0.f, 0.f};
        accA = __builtin_amdgcn_mfma_f32_16x16x32_bf16(a0.b, bA0.b, accA, 0, 0, 0);
        accA = __builtin_amdgcn_mfma_f32_16x16x32_bf16(a1.b, bA1.b, accA, 0, 0, 0);
        accB = __builtin_amdgcn_mfma_f32_16x16x32_bf16(a0.b, bB0.b, accB, 0, 0, 0);
        accB = __builtin_amdgcn_mfma_f32_16x16x32_bf16(a1.b, bB1.b, accB, 0, 0, 0);
        const int colA = w * 16 + (l & 15);
        const float biasA = ibn[colA];
        #pragma unroll
        for (int r = 0; r < 4; ++r) {
            int gn = blockIdx.x * 16 + (l >> 4) * 4 + r;
            if (gn < N) {
                Aout[(size_t)gn * 64 + colA] = accA[r] + biasA;
                Bout[(size_t)gn * 64 + colA] = (unsigned short)bf16r(accB[r]);
            }
        }
    } else {
        const float4 x0q = reinterpret_cast<const float4*>(x0)[nidx];
        float f0 = xn.x + x0q.x, f1 = xn.y + x0q.y, f2 = xn.z + x0q.z, f3 = xn.w + x0q.w;
        float p0 = 0.f, p1 = 0.f, p2 = 0.f;
        const int k0 = 4 * q;
        p0 = fmaf(f0, oW[(k0 + 0) * 3 + 0], p0); p1 = fmaf(f0, oW[(k0 + 0) * 3 + 1], p1); p2 = fmaf(f0, oW[(k0 + 0) * 3 + 2], p2);
        p0 = fmaf(f1, oW[(k0 + 1) * 3 + 0], p0); p1 = fmaf(f1, oW[(k0 + 1) * 3 + 1], p1); p2 = fmaf(f1, oW[(k0 + 1) * 3 + 2], p2);
        p0 = fmaf(f2, oW[(k0 + 2) * 3 + 0], p0); p1 = fmaf(f2, oW[(k0 + 2) * 3 + 1], p1); p2 = fmaf(f2, oW[(k0 + 2) * 3 + 2], p2);
        p0 = fmaf(f3, oW[(k0 + 3) * 3 + 0], p0); p1 = fmaf(f3, oW[(k0 + 3) * 3 + 1], p1); p2 = fmaf(f3, oW[(k0 + 3) * 3 + 2], p2);
        #pragma unroll
        for (int off = 8; off; off >>= 1) {
            p0 += __shfl_xor(p0, off, 16);
            p1 += __shfl_xor(p1, off, 16);
            p2 += __shfl_xor(p2, off, 16);
        }
        if (valid && q == 0) {
            out[node * 3 + 0] = p0 + ob[0];
            out[node * 3 + 1] = p1 + ob[1];
            out[node * 3 + 2] = p2 + ob[2];
        }
    }
}

extern "C" void kernel_launch(void* const* d_in, const int* in_sizes, int n_in,
                              void* d_out, int out_size, void* d_ws, size_t ws_size,
                              hipStream_t stream)
{
    const float* oneh = (const float*)d_in[0];
    const float* pos  = (const float*)d_in[1];
    const int*   ei   = (const int*)d_in[2];
    const float* embW = (const float*)d_in[3];
    const float* embB = (const float*)d_in[4];
    const float* iW   = (const float*)d_in[5];   // [4][128][64]
    const float* iB   = (const float*)d_in[6];   // [4][64]
    const float* uW   = (const float*)d_in[7];   // [4][64][64]
    const float* uB   = (const float*)d_in[8];   // [4][64]
    const float* oW   = (const float*)d_in[9];   // [64][3]
    const float* oB   = (const float*)d_in[10];  // [3]

    const int N = in_sizes[0] / 118;
    const int E = in_sizes[2] / 2;
    const int* src = ei;
    const int* dst = ei + E;

    float* ws = (float*)d_ws;
    const size_t NH = (size_t)N * H;
    float* x  = ws;
    float* x0 = ws + NH;
    float* A0 = ws + 2 * NH;
    float* A1 = ws + 3 * NH;
    unsigned short* Bb0  = (unsigned short*)(ws + 4 * NH);   // NH bf16
    unsigned short* Bb1  = Bb0 + NH;                          // NH bf16
    unsigned short* embF = Bb1 + NH;                          // 8192
    unsigned short* iF   = embF + 8192;                       // 32768
    unsigned short* uFf  = iF + 32768;                        // 16384
    int* ibase = (int*)(uFf + 16384);
    int* cnt   = ibase;               // N
    int* cur   = ibase + N;           // N
    int* rp    = ibase + 2 * N;       // N+1
    int* col   = ibase + 3 * N + 1;   // E
    int* texc  = col + E;             // N
    int* bsum  = texc + N;            // <=256

    const int nbm = (N + 31) / 32;
    const int nbf = (N + 15) / 16;
    const int nbs = (N + 255) / 256;

    k_wpack<<<128, 256, 0, stream>>>(embW, iW, uW, embF, iF, uFf);

    hipMemsetAsync(cnt, 0, (size_t)N * sizeof(int), stream);
    k_hist<<<1024, 256, 0, stream>>>(src, cnt, E);
    k_scan1<<<nbs, 256, 0, stream>>>(cnt, texc, bsum, N);
    k_scan2<<<1, 256, 0, stream>>>(bsum, nbs);
    k_scan3<<<nbs, 256, 0, stream>>>(texc, bsum, rp, cur, N, E);
    k_scatter<<<1024, 256, 0, stream>>>(src, dst, cur, col, E);

    // embed + layer-0 interact -> A0/Bb0
    k_embed_mfma<<<nbm, 256, 0, stream>>>(oneh, pos, (const uint4*)embF, embB,
                                          (const uint4*)iF, iB, x, x0, A0, Bb0, N);

    float* Ain[4]  = {A0, A1, A0, A1};
    float* Aout[4] = {A1, A0, A1, A0};
    unsigned short* Bin[4]  = {Bb0, Bb1, Bb0, Bb1};
    unsigned short* Bout[4] = {Bb1, Bb0, Bb1, Bb0};

    for (int l = 0; l < 4; ++l) {
        const uint4* uFl = (const uint4*)(uFf + (size_t)l * 4096);
        const uint4* iFn = (l < 3) ? (const uint4*)(iF + (size_t)(l + 1) * 8192) : (const uint4*)iF;
        const float* ibn = (l < 3) ? iB + (l + 1) * 64 : iB;
        if (l < 3)
            k_edge_upd<false><<<nbf, 256, 0, stream>>>(rp, col, Ain[l], (const unsigned*)Bin[l], x,
                uFl, uB + l * 64, iFn, ibn, Aout[l], Bout[l], x0, oW, oB, (float*)d_out, N);
        else
            k_edge_upd<true><<<nbf, 256, 0, stream>>>(rp, col, Ain[l], (const unsigned*)Bin[l], x,
                uFl, uB + l * 64, iFn, ibn, Aout[l], Bout[l], x0, oW, oB, (float*)d_out, N);
    }
}

// Round 10
// 208.579 us; speedup vs baseline: 14.9618x; 1.2405x over previous
//
#include <hip/hip_runtime.h>

#define H 64
#define ACHUNK 4096

typedef __attribute__((ext_vector_type(8))) __bf16 bf16x8;
typedef __attribute__((ext_vector_type(4))) float f32x4;
union U16 { uint4 u; bf16x8 b; };

__device__ __forceinline__ float silu_f(float v) {
    return v * __builtin_amdgcn_rcpf(1.0f + __expf(-v));
}

__device__ __forceinline__ unsigned bf16r(float f) {
    unsigned b = __float_as_uint(f);
    return (b + 0x7fffu + ((b >> 16) & 1u)) >> 16;   // RTNE (inputs finite)
}
__device__ __forceinline__ unsigned pack2(float lo, float hi) {
    return bf16r(lo) | (bf16r(hi) << 16);
}
__device__ __forceinline__ float4 unpack4(uint2 u) {
    float4 r;
    r.x = __uint_as_float(u.x << 16);
    r.y = __uint_as_float(u.x & 0xffff0000u);
    r.z = __uint_as_float(u.y << 16);
    r.w = __uint_as_float(u.y & 0xffff0000u);
    return r;
}

// ---------------- Weight pre-pack into MFMA fragment order (bf16) ----------------
__global__ __launch_bounds__(256) void k_wpack(
    const float* __restrict__ embW, const float* __restrict__ iW, const float* __restrict__ uW,
    unsigned short* __restrict__ embF, unsigned short* __restrict__ iF, unsigned short* __restrict__ uF)
{
    int t = blockIdx.x * 256 + threadIdx.x;
    if (t < 8192) {   // embF: ct(4) x kt(4) x lane(64) x e(8); K=128 pad of 121, N=64
        int e = t & 7, l = (t >> 3) & 63, kt = (t >> 9) & 3, ct = (t >> 11) & 3;
        int k = kt * 32 + (l >> 4) * 8 + e;
        int n = ct * 16 + (l & 15);
        float v = (k < 121) ? embW[k * 64 + n] : 0.f;
        embF[t] = (unsigned short)bf16r(v);
    }
    if (t < 16384) {  // uF: layer(4) x ct(4) x kt(2) x lane(64) x e(8); K=64, N=64
        int e = t & 7, l = (t >> 3) & 63, kt = (t >> 9) & 1, ct = (t >> 10) & 3, ly = (t >> 12) & 3;
        int k = kt * 32 + (l >> 4) * 8 + e;
        int n = ct * 16 + (l & 15);
        uF[t] = (unsigned short)bf16r(uW[(size_t)ly * 4096 + k * 64 + n]);
    }
    if (t < 32768) {  // iF: layer(4) x ct(8) x kt(2) x lane(64) x e(8); K=64, N=128 (=[Wt|Wb])
        int e = t & 7, l = (t >> 3) & 63, kt = (t >> 9) & 1, ct = (t >> 10) & 7, ly = (t >> 13) & 3;
        int k = kt * 32 + (l >> 4) * 8 + e;
        int n = ct * 16 + (l & 15);
        const float* W = iW + (size_t)ly * 128 * 64;
        float v = (n < 64) ? W[k * 64 + n] : W[(64 + k) * 64 + (n - 64)];
        iF[t] = (unsigned short)bf16r(v);
    }
}

// ---------------- CSR build (bucket-grouped, write-coalesced) ----------------
// bucket b = src >> 8; NB = ceil(N/256) <= 256.
__global__ __launch_bounds__(256) void k_bcount(const int* __restrict__ src,
                                                int* __restrict__ bcnt, int E, int NB)
{
    __shared__ int lc[256];
    const int t = threadIdx.x;
    lc[t] = 0;
    __syncthreads();
    const int stride = gridDim.x * 256;
    for (int e = blockIdx.x * 256 + t; e < E; e += stride)
        atomicAdd(&lc[src[e] >> 8], 1);
    __syncthreads();
    if (t < NB && lc[t]) atomicAdd(&bcnt[t], lc[t]);
}

__global__ __launch_bounds__(256) void k_bscan(const int* __restrict__ bcnt,
                                               int* __restrict__ bbase, int* __restrict__ bcur,
                                               int NB, int E)
{
    __shared__ int s[256];
    const int t = threadIdx.x;
    int v = (t < NB) ? bcnt[t] : 0;
    s[t] = v;
    __syncthreads();
    for (int off = 1; off < 256; off <<= 1) {
        int u = (t >= off) ? s[t - off] : 0;
        __syncthreads();
        s[t] += u;
        __syncthreads();
    }
    if (t < NB) {
        int ex = s[t] - v;
        bbase[t] = ex;
        bcur[t] = ex;
    }
    if (t == 0) bbase[NB] = E;
}

// Stage ACHUNK edges in LDS grouped by bucket; write each group contiguously.
__global__ __launch_bounds__(256) void k_bucketA(const int* __restrict__ src, const int* __restrict__ dst,
                                                 int* __restrict__ bcur, uint2* __restrict__ tmp, int E)
{
    __shared__ int lscan[256], lrun[256], gbase[256];
    __shared__ uint2 stage[ACHUNK];
    const int t = threadIdx.x;
    const int c0 = blockIdx.x * ACHUNK;
    const int cend = min(c0 + ACHUNK, E);
    const int n = cend - c0;
    lscan[t] = 0;
    __syncthreads();
    for (int i = c0 + t; i < cend; i += 256)
        atomicAdd(&lscan[src[i] >> 8], 1);
    __syncthreads();
    int v = lscan[t];
    __syncthreads();
    lscan[t] = v;   // re-init for ladder
    __syncthreads();
    for (int off = 1; off < 256; off <<= 1) {
        int u = (t >= off) ? lscan[t - off] : 0;
        __syncthreads();
        lscan[t] += u;
        __syncthreads();
    }
    int ex = lscan[t] - v;       // exclusive
    lscan[t] = ex;               // own-cell rewrite, no race
    lrun[t] = ex;
    if (v > 0) gbase[t] = atomicAdd(&bcur[t], v);
    __syncthreads();
    for (int i = c0 + t; i < cend; i += 256) {
        int s_ = src[i];
        int b = s_ >> 8;
        int p = atomicAdd(&lrun[b], 1);
        stage[p] = make_uint2((unsigned)s_, (unsigned)dst[i]);
    }
    __syncthreads();
    for (int i = t; i < n; i += 256) {
        uint2 e = stage[i];
        int b = (int)(e.x >> 8);
        tmp[gbase[b] + i - lscan[b]] = e;
    }
}

// Per-node counts from bucketed tmp; coalesced cnt write.
__global__ __launch_bounds__(256) void k_hist2(const uint2* __restrict__ tmp, const int* __restrict__ bbase,
                                               int* __restrict__ cnt, int N)
{
    __shared__ int lc[256];
    const int b = blockIdx.x, t = threadIdx.x;
    lc[t] = 0;
    __syncthreads();
    const int beg = bbase[b], end = bbase[b + 1];
    for (int i = beg + t; i < end; i += 256)
        atomicAdd(&lc[tmp[i].x & 255], 1);
    __syncthreads();
    const int node = b * 256 + t;
    if (node < N) cnt[node] = lc[t];
}

__global__ __launch_bounds__(256) void k_scan1(const int* __restrict__ cnt,
                                               int* __restrict__ texc, int* __restrict__ bsum, int n)
{
    __shared__ int s[256];
    const int t = threadIdx.x;
    const int i = blockIdx.x * 256 + t;
    int v = (i < n) ? cnt[i] : 0;
    s[t] = v;
    __syncthreads();
    for (int off = 1; off < 256; off <<= 1) {
        int u = (t >= off) ? s[t - off] : 0;
        __syncthreads();
        s[t] += u;
        __syncthreads();
    }
    if (i < n) texc[i] = s[t] - v;
    if (t == 255) bsum[blockIdx.x] = s[255];
}

__global__ __launch_bounds__(256) void k_scan2(int* __restrict__ bsum, int nb)
{
    __shared__ int s[256];
    const int t = threadIdx.x;
    int v = (t < nb) ? bsum[t] : 0;
    s[t] = v;
    __syncthreads();
    for (int off = 1; off < 256; off <<= 1) {
        int u = (t >= off) ? s[t - off] : 0;
        __syncthreads();
        s[t] += u;
        __syncthreads();
    }
    if (t < nb) bsum[t] = s[t] - v;
}

__global__ __launch_bounds__(256) void k_scan3(const int* __restrict__ texc, const int* __restrict__ bsum,
                                               int* __restrict__ rp, int n, int E)
{
    const int i = blockIdx.x * 256 + threadIdx.x;
    if (i < n) rp[i] = texc[i] + bsum[blockIdx.x];
    if (i == 0) rp[n] = E;
}

// Scatter within bucket: per-node LDS cursors; col writes land in one ~16KB window.
__global__ __launch_bounds__(256) void k_bucketB(const uint2* __restrict__ tmp, const int* __restrict__ bbase,
                                                 const int* __restrict__ rp, int* __restrict__ col, int N)
{
    __shared__ int curL[256];
    const int b = blockIdx.x, t = threadIdx.x;
    const int node = b * 256 + t;
    curL[t] = (node < N) ? rp[node] : 0;
    __syncthreads();
    const int beg = bbase[b], end = bbase[b + 1];
    for (int i = beg + t; i < end; i += 256) {
        uint2 e = tmp[i];
        int p = atomicAdd(&curL[e.x & 255], 1);
        col[p] = (int)e.y;
    }
}

// ---------------- Embedding + layer-0 interact (MFMA) ----------------
__global__ __launch_bounds__(256) void k_embed_mfma(
    const float* __restrict__ oneh, const float* __restrict__ pos,
    const uint4* __restrict__ Wf, const float* __restrict__ eb,
    const uint4* __restrict__ iFn, const float* __restrict__ ibn,
    float* __restrict__ x, float* __restrict__ x0,
    float* __restrict__ Aout, unsigned short* __restrict__ Bout, int N)
{
    __shared__ float ot[32 * 68];
    __shared__ unsigned short xbuf[32 * 72];
    unsigned short* xin = (unsigned short*)ot;   // 32*136 ushorts == 8704 B (aliased)
    const int t = threadIdx.x;
    const int w = t >> 6, l = t & 63;
    const int n0 = blockIdx.x * 32;
    for (int i = t; i < 32 * 128; i += 256) {
        int node = i >> 7, k = i & 127;
        int g = n0 + node;
        float v = 0.f;
        if (g < N) {
            if (k < 118) v = oneh[(size_t)g * 118 + k];
            else if (k < 121) v = pos[(size_t)g * 3 + (k - 118)];
        }
        xin[node * 136 + k] = (unsigned short)bf16r(v);
    }
    __syncthreads();
    const int rt = w & 1, ctb = (w >> 1) * 2;
    U16 af[4];
    #pragma unroll
    for (int kt = 0; kt < 4; ++kt)
        af[kt].u = *reinterpret_cast<const uint4*>(
            &xin[(rt * 16 + (l & 15)) * 136 + kt * 32 + (l >> 4) * 8]);
    f32x4 acc0 = {0.f, 0.f, 0.f, 0.f}, acc1 = {0.f, 0.f, 0.f, 0.f};
    #pragma unroll
    for (int kt = 0; kt < 4; ++kt) {
        U16 b0, b1;
        b0.u = Wf[((ctb + 0) * 4 + kt) * 64 + l];
        b1.u = Wf[((ctb + 1) * 4 + kt) * 64 + l];
        acc0 = __builtin_amdgcn_mfma_f32_16x16x32_bf16(af[kt].b, b0.b, acc0, 0, 0, 0);
        acc1 = __builtin_amdgcn_mfma_f32_16x16x32_bf16(af[kt].b, b1.b, acc1, 0, 0, 0);
    }
    __syncthreads();   // done with xin; reuse as ot
    #pragma unroll
    for (int r = 0; r < 4; ++r) {
        ot[(rt * 16 + (l >> 4) * 4 + r) * 68 + (ctb + 0) * 16 + (l & 15)] = acc0[r];
        ot[(rt * 16 + (l >> 4) * 4 + r) * 68 + (ctb + 1) * 16 + (l & 15)] = acc1[r];
    }
    __syncthreads();
    for (int v = t; v < 512; v += 256) {
        int node = v >> 4, q = v & 15;
        float4 bq = reinterpret_cast<const float4*>(eb)[q];
        float* p = &ot[node * 68 + q * 4];
        float4 o;
        o.x = silu_f(p[0] + bq.x); o.y = silu_f(p[1] + bq.y);
        o.z = silu_f(p[2] + bq.z); o.w = silu_f(p[3] + bq.w);
        int g = n0 + node;
        if (g < N) {
            reinterpret_cast<float4*>(x)[(size_t)g * 16 + q] = o;
            reinterpret_cast<float4*>(x0)[(size_t)g * 16 + q] = o;
        }
        p[0] = o.x; p[1] = o.y; p[2] = o.z; p[3] = o.w;
    }
    __syncthreads();
    {   // pack x rows bf16 into xbuf (stride 72)
        int node = t >> 3, j = t & 7;
        const float* p = &ot[node * 68 + j * 8];
        uint4 o;
        o.x = pack2(p[0], p[1]); o.y = pack2(p[2], p[3]);
        o.z = pack2(p[4], p[5]); o.w = pack2(p[6], p[7]);
        *reinterpret_cast<uint4*>(&xbuf[node * 72 + j * 8]) = o;
    }
    __syncthreads();
    // layer-0 interact: 2 M-tiles, wave w handles ct_A=w and ct_B=w+4
    #pragma unroll
    for (int mt = 0; mt < 2; ++mt) {
        U16 a0, a1, bA0, bA1, bB0, bB1;
        a0.u = *reinterpret_cast<const uint4*>(&xbuf[(mt * 16 + (l & 15)) * 72 + (l >> 4) * 8]);
        a1.u = *reinterpret_cast<const uint4*>(&xbuf[(mt * 16 + (l & 15)) * 72 + 32 + (l >> 4) * 8]);
        bA0.u = iFn[(w * 2 + 0) * 64 + l];
        bA1.u = iFn[(w * 2 + 1) * 64 + l];
        bB0.u = iFn[((w + 4) * 2 + 0) * 64 + l];
        bB1.u = iFn[((w + 4) * 2 + 1) * 64 + l];
        f32x4 accA = {0.f, 0.f, 0.f, 0.f}, accB = {0.f, 0.f, 0.f, 0.f};
        accA = __builtin_amdgcn_mfma_f32_16x16x32_bf16(a0.b, bA0.b, accA, 0, 0, 0);
        accA = __builtin_amdgcn_mfma_f32_16x16x32_bf16(a1.b, bA1.b, accA, 0, 0, 0);
        accB = __builtin_amdgcn_mfma_f32_16x16x32_bf16(a0.b, bB0.b, accB, 0, 0, 0);
        accB = __builtin_amdgcn_mfma_f32_16x16x32_bf16(a1.b, bB1.b, accB, 0, 0, 0);
        const int colA = w * 16 + (l & 15);
        const float biasA = ibn[colA];
        #pragma unroll
        for (int r = 0; r < 4; ++r) {
            int gn = n0 + mt * 16 + (l >> 4) * 4 + r;
            if (gn < N) {
                Aout[(size_t)gn * 64 + colA] = accA[r] + biasA;
                Bout[(size_t)gn * 64 + colA] = (unsigned short)bf16r(accB[r]);
            }
        }
    }
}

// ---------------- Fused edge + MFMA update + next-layer interact (+ final out) ----------------
template <bool LAST>
__global__ __launch_bounds__(256) void k_edge_upd(
    const int* __restrict__ rp, const int* __restrict__ col,
    const float* __restrict__ A, const unsigned* __restrict__ Bb,
    float* __restrict__ x,
    const uint4* __restrict__ uFf, const float* __restrict__ ub,
    const uint4* __restrict__ iFn, const float* __restrict__ ibn,
    float* __restrict__ Aout, unsigned short* __restrict__ Bout,
    const float* __restrict__ x0, const float* __restrict__ oW, const float* __restrict__ ob,
    float* __restrict__ out, int N)
{
    __shared__ unsigned short vb[16 * 72];   // bf16 rows, stride 72
    __shared__ float sv[16 * 68];            // silu(update) rows, stride 68
    const int t = threadIdx.x;
    const int g = t >> 4, q = t & 15;
    const int w = t >> 6, l = t & 63;
    const int node = blockIdx.x * 16 + g;
    const bool valid = node < N;
    const size_t nidx = (size_t)(valid ? node : 0) * 16 + q;
    const float4* __restrict__ Av = reinterpret_cast<const float4*>(A);
    const uint2* __restrict__ Bv = reinterpret_cast<const uint2*>(Bb);
    float4* __restrict__ Xv = reinterpret_cast<float4*>(x);

    const float4 a = Av[nidx];
    const float4 xq = Xv[nidx];
    const int beg = valid ? rp[node] : 0;
    const int end = valid ? rp[node + 1] : 0;

    float4 acc = make_float4(0.f, 0.f, 0.f, 0.f);
    int j = beg;
    for (; j + 4 <= end; j += 4) {
        int d0 = col[j], d1 = col[j + 1], d2 = col[j + 2], d3 = col[j + 3];
        float4 b0 = unpack4(Bv[(size_t)d0 * 16 + q]);
        float4 b1 = unpack4(Bv[(size_t)d1 * 16 + q]);
        float4 b2 = unpack4(Bv[(size_t)d2 * 16 + q]);
        float4 b3 = unpack4(Bv[(size_t)d3 * 16 + q]);
        acc.x += silu_f(a.x + b0.x) + silu_f(a.x + b1.x) + silu_f(a.x + b2.x) + silu_f(a.x + b3.x);
        acc.y += silu_f(a.y + b0.y) + silu_f(a.y + b1.y) + silu_f(a.y + b2.y) + silu_f(a.y + b3.y);
        acc.z += silu_f(a.z + b0.z) + silu_f(a.z + b1.z) + silu_f(a.z + b2.z) + silu_f(a.z + b3.z);
        acc.w += silu_f(a.w + b0.w) + silu_f(a.w + b1.w) + silu_f(a.w + b2.w) + silu_f(a.w + b3.w);
    }
    for (; j < end; ++j) {
        int d = col[j];
        float4 b = unpack4(Bv[(size_t)d * 16 + q]);
        acc.x += silu_f(a.x + b.x); acc.y += silu_f(a.y + b.y);
        acc.z += silu_f(a.z + b.z); acc.w += silu_f(a.w + b.w);
    }
    float4 v;
    v.x = fmaf(0.25f, acc.x, xq.x); v.y = fmaf(0.25f, acc.y, xq.y);
    v.z = fmaf(0.25f, acc.z, xq.z); v.w = fmaf(0.25f, acc.w, xq.w);
    {
        uint2 vo;
        vo.x = pack2(v.x, v.y);
        vo.y = pack2(v.z, v.w);
        *reinterpret_cast<uint2*>(&vb[g * 72 + q * 4]) = vo;
    }
    __syncthreads();
    // update MFMA: A-frag = vb rows, B-frag = uW tile ct=w
    {
        U16 a0, a1, b0, b1;
        a0.u = *reinterpret_cast<const uint4*>(&vb[(l & 15) * 72 + (l >> 4) * 8]);
        a1.u = *reinterpret_cast<const uint4*>(&vb[(l & 15) * 72 + 32 + (l >> 4) * 8]);
        b0.u = uFf[(w * 2 + 0) * 64 + l];
        b1.u = uFf[(w * 2 + 1) * 64 + l];
        f32x4 uacc = {0.f, 0.f, 0.f, 0.f};
        uacc = __builtin_amdgcn_mfma_f32_16x16x32_bf16(a0.b, b0.b, uacc, 0, 0, 0);
        uacc = __builtin_amdgcn_mfma_f32_16x16x32_bf16(a1.b, b1.b, uacc, 0, 0, 0);
        const int h = w * 16 + (l & 15);
        const float ubh = ub[h];
        #pragma unroll
        for (int r = 0; r < 4; ++r)
            sv[((l >> 4) * 4 + r) * 68 + h] = silu_f(uacc[r] + ubh);
    }
    __syncthreads();
    const float4 s = *reinterpret_cast<const float4*>(&sv[g * 68 + q * 4]);
    float4 xn;
    xn.x = xq.x + s.x; xn.y = xq.y + s.y;
    xn.z = xq.z + s.z; xn.w = xq.w + s.w;
    if (valid && !LAST) Xv[nidx] = xn;
    if (!LAST) {
        uint2 xo;
        xo.x = pack2(xn.x, xn.y);
        xo.y = pack2(xn.z, xn.w);
        *reinterpret_cast<uint2*>(&vb[g * 72 + q * 4]) = xo;
        __syncthreads();
        U16 a0, a1, bA0, bA1, bB0, bB1;
        a0.u = *reinterpret_cast<const uint4*>(&vb[(l & 15) * 72 + (l >> 4) * 8]);
        a1.u = *reinterpret_cast<const uint4*>(&vb[(l & 15) * 72 + 32 + (l >> 4) * 8]);
        bA0.u = iFn[(w * 2 + 0) * 64 + l];
        bA1.u = iFn[(w * 2 + 1) * 64 + l];
        bB0.u = iFn[((w + 4) * 2 + 0) * 64 + l];
        bB1.u = iFn[((w + 4) * 2 + 1) * 64 + l];
        f32x4 accA = {0.f, 0.f, 0.f, 0.f}, accB = {0.f, 0.f, 0.f, 0.f};
        accA = __builtin_amdgcn_mfma_f32_16x16x32_bf16(a0.b, bA0.b, accA, 0, 0, 0);
        accA = __builtin_amdgcn_mfma_f32_16x16x32_bf16(a1.b, bA1.b, accA, 0, 0, 0);
        accB = __builtin_amdgcn_mfma_f32_16x16x32_bf16(a0.b, bB0.b, accB, 0, 0, 0);
        accB = __builtin_amdgcn_mfma_f32_16x16x32_bf16(a1.b, bB1.b, accB, 0, 0, 0);
        const int colA = w * 16 + (l & 15);
        const float biasA = ibn[colA];
        #pragma unroll
        for (int r = 0; r < 4; ++r) {
            int gn = blockIdx.x * 16 + (l >> 4) * 4 + r;
            if (gn < N) {
                Aout[(size_t)gn * 64 + colA] = accA[r] + biasA;
                Bout[(size_t)gn * 64 + colA] = (unsigned short)bf16r(accB[r]);
            }
        }
    } else {
        const float4 x0q = reinterpret_cast<const float4*>(x0)[nidx];
        float f0 = xn.x + x0q.x, f1 = xn.y + x0q.y, f2 = xn.z + x0q.z, f3 = xn.w + x0q.w;
        float p0 = 0.f, p1 = 0.f, p2 = 0.f;
        const int k0 = 4 * q;
        p0 = fmaf(f0, oW[(k0 + 0) * 3 + 0], p0); p1 = fmaf(f0, oW[(k0 + 0) * 3 + 1], p1); p2 = fmaf(f0, oW[(k0 + 0) * 3 + 2], p2);
        p0 = fmaf(f1, oW[(k0 + 1) * 3 + 0], p0); p1 = fmaf(f1, oW[(k0 + 1) * 3 + 1], p1); p2 = fmaf(f1, oW[(k0 + 1) * 3 + 2], p2);
        p0 = fmaf(f2, oW[(k0 + 2) * 3 + 0], p0); p1 = fmaf(f2, oW[(k0 + 2) * 3 + 1], p1); p2 = fmaf(f2, oW[(k0 + 2) * 3 + 2], p2);
        p0 = fmaf(f3, oW[(k0 + 3) * 3 + 0], p0); p1 = fmaf(f3, oW[(k0 + 3) * 3 + 1], p1); p2 = fmaf(f3, oW[(k0 + 3) * 3 + 2], p2);
        #pragma unroll
        for (int off = 8; off; off >>= 1) {
            p0 += __shfl_xor(p0, off, 16);
            p1 += __shfl_xor(p1, off, 16);
            p2 += __shfl_xor(p2, off, 16);
        }
        if (valid && q == 0) {
            out[node * 3 + 0] = p0 + ob[0];
            out[node * 3 + 1] = p1 + ob[1];
            out[node * 3 + 2] = p2 + ob[2];
        }
    }
}

extern "C" void kernel_launch(void* const* d_in, const int* in_sizes, int n_in,
                              void* d_out, int out_size, void* d_ws, size_t ws_size,
                              hipStream_t stream)
{
    const float* oneh = (const float*)d_in[0];
    const float* pos  = (const float*)d_in[1];
    const int*   ei   = (const int*)d_in[2];
    const float* embW = (const float*)d_in[3];
    const float* embB = (const float*)d_in[4];
    const float* iW   = (const float*)d_in[5];   // [4][128][64]
    const float* iB   = (const float*)d_in[6];   // [4][64]
    const float* uW   = (const float*)d_in[7];   // [4][64][64]
    const float* uB   = (const float*)d_in[8];   // [4][64]
    const float* oW   = (const float*)d_in[9];   // [64][3]
    const float* oB   = (const float*)d_in[10];  // [3]

    const int N = in_sizes[0] / 118;
    const int E = in_sizes[2] / 2;
    const int* src = ei;
    const int* dst = ei + E;

    float* ws = (float*)d_ws;
    const size_t NH = (size_t)N * H;
    float* x  = ws;
    float* x0 = ws + NH;
    float* A0 = ws + 2 * NH;
    float* A1 = ws + 3 * NH;
    unsigned short* Bb0  = (unsigned short*)(ws + 4 * NH);   // NH bf16
    unsigned short* Bb1  = Bb0 + NH;                          // NH bf16
    unsigned short* embF = Bb1 + NH;                          // 8192
    unsigned short* iF   = embF + 8192;                       // 32768
    unsigned short* uFf  = iF + 32768;                        // 16384
    int* ibase = (int*)(uFf + 16384);
    int* cnt   = ibase;               // N
    int* rp    = ibase + N;           // N+1
    int* col   = ibase + 2 * N + 1;   // E
    int* texc  = col + E;             // N
    int* bsum  = texc + N;            // <=256
    int* bcnt  = bsum + 256;          // NB
    int* bbase = bcnt + 256;          // NB+1
    int* bcur  = bbase + 257;         // NB
    uint2* tmp = (uint2*)A1;          // aliased: CSR build finishes before A1 is written

    const int nbm = (N + 31) / 32;
    const int nbf = (N + 15) / 16;
    const int NB  = (N + 255) / 256;  // = scan block count too

    k_wpack<<<128, 256, 0, stream>>>(embW, iW, uW, embF, iF, uFf);

    // CSR build (bucket-grouped, write-coalesced)
    hipMemsetAsync(bcnt, 0, 256 * sizeof(int), stream);
    k_bcount<<<128, 256, 0, stream>>>(src, bcnt, E, NB);
    k_bscan<<<1, 256, 0, stream>>>(bcnt, bbase, bcur, NB, E);
    k_bucketA<<<(E + ACHUNK - 1) / ACHUNK, 256, 0, stream>>>(src, dst, bcur, tmp, E);
    k_hist2<<<NB, 256, 0, stream>>>(tmp, bbase, cnt, N);
    k_scan1<<<NB, 256, 0, stream>>>(cnt, texc, bsum, N);
    k_scan2<<<1, 256, 0, stream>>>(bsum, NB);
    k_scan3<<<NB, 256, 0, stream>>>(texc, bsum, rp, N, E);
    k_bucketB<<<NB, 256, 0, stream>>>(tmp, bbase, rp, col, N);

    // embed + layer-0 interact -> A0/Bb0
    k_embed_mfma<<<nbm, 256, 0, stream>>>(oneh, pos, (const uint4*)embF, embB,
                                          (const uint4*)iF, iB, x, x0, A0, Bb0, N);

    float* Ain[4]  = {A0, A1, A0, A1};
    float* Aout[4] = {A1, A0, A1, A0};
    unsigned short* Bin[4]  = {Bb0, Bb1, Bb0, Bb1};
    unsigned short* Bout[4] = {Bb1, Bb0, Bb1, Bb0};

    for (int l = 0; l < 4; ++l) {
        const uint4* uFl = (const uint4*)(uFf + (size_t)l * 4096);
        const uint4* iFn = (l < 3) ? (const uint4*)(iF + (size_t)(l + 1) * 8192) : (const uint4*)iF;
        const float* ibn = (l < 3) ? iB + (l + 1) * 64 : iB;
        if (l < 3)
            k_edge_upd<false><<<nbf, 256, 0, stream>>>(rp, col, Ain[l], (const unsigned*)Bin[l], x,
                uFl, uB + l * 64, iFn, ibn, Aout[l], Bout[l], x0, oW, oB, (float*)d_out, N);
        else
            k_edge_upd<true><<<nbf, 256, 0, stream>>>(rp, col, Ain[l], (const unsigned*)Bin[l], x,
                uFl, uB + l * 64, iFn, ibn, Aout[l], Bout[l], x0, oW, oB, (float*)d_out, N);
    }
}

// Round 11
// 188.163 us; speedup vs baseline: 16.5852x; 1.1085x over previous
//
#include <hip/hip_runtime.h>

#define H 64
#define ACHUNK 4096

typedef __attribute__((ext_vector_type(8))) __bf16 bf16x8;
typedef __attribute__((ext_vector_type(4))) float f32x4;
union U16 { uint4 u; bf16x8 b; };

__device__ __forceinline__ float silu_f(float v) {
    return v * __builtin_amdgcn_rcpf(1.0f + __expf(-v));
}

__device__ __forceinline__ unsigned bf16r(float f) {
    unsigned b = __float_as_uint(f);
    return (b + 0x7fffu + ((b >> 16) & 1u)) >> 16;   // RTNE (inputs finite)
}
__device__ __forceinline__ unsigned pack2(float lo, float hi) {
    return bf16r(lo) | (bf16r(hi) << 16);
}
__device__ __forceinline__ float4 unpack4(uint2 u) {
    float4 r;
    r.x = __uint_as_float(u.x << 16);
    r.y = __uint_as_float(u.x & 0xffff0000u);
    r.z = __uint_as_float(u.y << 16);
    r.w = __uint_as_float(u.y & 0xffff0000u);
    return r;
}

// ---------------- Fused: weight pre-pack (blocks 0-127) + bucket-count partials (128-255) ----------
__global__ __launch_bounds__(256) void k_prep(
    const float* __restrict__ embW, const float* __restrict__ iW, const float* __restrict__ uW,
    unsigned short* __restrict__ embF, unsigned short* __restrict__ iF, unsigned short* __restrict__ uF,
    const int* __restrict__ src, int* __restrict__ bpart, int E)
{
    if (blockIdx.x < 128) {
        int t = blockIdx.x * 256 + threadIdx.x;
        if (t < 8192) {   // embF: ct(4) x kt(4) x lane(64) x e(8); K=128 pad of 121, N=64
            int e = t & 7, l = (t >> 3) & 63, kt = (t >> 9) & 3, ct = (t >> 11) & 3;
            int k = kt * 32 + (l >> 4) * 8 + e;
            int n = ct * 16 + (l & 15);
            float v = (k < 121) ? embW[k * 64 + n] : 0.f;
            embF[t] = (unsigned short)bf16r(v);
        }
        if (t < 16384) {  // uF: layer(4) x ct(4) x kt(2) x lane(64) x e(8)
            int e = t & 7, l = (t >> 3) & 63, kt = (t >> 9) & 1, ct = (t >> 10) & 3, ly = (t >> 12) & 3;
            int k = kt * 32 + (l >> 4) * 8 + e;
            int n = ct * 16 + (l & 15);
            uF[t] = (unsigned short)bf16r(uW[(size_t)ly * 4096 + k * 64 + n]);
        }
        if (t < 32768) {  // iF: layer(4) x ct(8) x kt(2) x lane(64) x e(8); [Wt|Wb]
            int e = t & 7, l = (t >> 3) & 63, kt = (t >> 9) & 1, ct = (t >> 10) & 7, ly = (t >> 13) & 3;
            int k = kt * 32 + (l >> 4) * 8 + e;
            int n = ct * 16 + (l & 15);
            const float* W = iW + (size_t)ly * 128 * 64;
            float v = (n < 64) ? W[k * 64 + n] : W[(64 + k) * 64 + (n - 64)];
            iF[t] = (unsigned short)bf16r(v);
        }
    } else {
        __shared__ int lc[256];
        const int t = threadIdx.x;
        const int blk = blockIdx.x - 128;
        lc[t] = 0;
        __syncthreads();
        for (int e = blk * 256 + t; e < E; e += 128 * 256)
            atomicAdd(&lc[src[e] >> 8], 1);
        __syncthreads();
        bpart[blk * 256 + t] = lc[t];
    }
}

// reduce bpart -> exclusive bucket bases
__global__ __launch_bounds__(256) void k_bscan(const int* __restrict__ bpart,
                                               int* __restrict__ bbase, int* __restrict__ bcur,
                                               int NB, int E)
{
    __shared__ int s[256];
    const int t = threadIdx.x;
    int v = 0;
    for (int b = 0; b < 128; ++b) v += bpart[b * 256 + t];
    s[t] = v;
    __syncthreads();
    for (int off = 1; off < 256; off <<= 1) {
        int u = (t >= off) ? s[t - off] : 0;
        __syncthreads();
        s[t] += u;
        __syncthreads();
    }
    if (t < NB) {
        int ex = s[t] - v;
        bbase[t] = ex;
        bcur[t] = ex;
    }
    if (t == 0) bbase[NB] = E;
}

// Stage ACHUNK edges in LDS grouped by bucket; write each group contiguously.
__global__ __launch_bounds__(256) void k_bucketA(const int* __restrict__ src, const int* __restrict__ dst,
                                                 int* __restrict__ bcur, uint2* __restrict__ tmp, int E)
{
    __shared__ int lscan[256], lrun[256], gbase[256];
    __shared__ uint2 stage[ACHUNK];
    const int t = threadIdx.x;
    const int c0 = blockIdx.x * ACHUNK;
    const int cend = min(c0 + ACHUNK, E);
    const int n = cend - c0;
    lscan[t] = 0;
    __syncthreads();
    for (int i = c0 + t; i < cend; i += 256)
        atomicAdd(&lscan[src[i] >> 8], 1);
    __syncthreads();
    int v = lscan[t];
    __syncthreads();
    lscan[t] = v;
    __syncthreads();
    for (int off = 1; off < 256; off <<= 1) {
        int u = (t >= off) ? lscan[t - off] : 0;
        __syncthreads();
        lscan[t] += u;
        __syncthreads();
    }
    int ex = lscan[t] - v;
    lscan[t] = ex;
    lrun[t] = ex;
    if (v > 0) gbase[t] = atomicAdd(&bcur[t], v);
    __syncthreads();
    for (int i = c0 + t; i < cend; i += 256) {
        int s_ = src[i];
        int b = s_ >> 8;
        int p = atomicAdd(&lrun[b], 1);
        stage[p] = make_uint2((unsigned)s_, (unsigned)dst[i]);
    }
    __syncthreads();
    for (int i = t; i < n; i += 256) {
        uint2 e = stage[i];
        int b = (int)(e.x >> 8);
        tmp[gbase[b] + i - lscan[b]] = e;
    }
}

// Fused: per-node counts from bucketed tmp + in-block exclusive scan -> texc, bsum
__global__ __launch_bounds__(256) void k_hist2scan(const uint2* __restrict__ tmp, const int* __restrict__ bbase,
                                                   int* __restrict__ texc, int* __restrict__ bsum, int N)
{
    __shared__ int lc[256];
    const int b = blockIdx.x, t = threadIdx.x;
    lc[t] = 0;
    __syncthreads();
    const int beg = bbase[b], end = bbase[b + 1];
    for (int i = beg + t; i < end; i += 256)
        atomicAdd(&lc[tmp[i].x & 255], 1);
    __syncthreads();
    int v = lc[t];
    __syncthreads();
    for (int off = 1; off < 256; off <<= 1) {
        int u = (t >= off) ? lc[t - off] : 0;
        __syncthreads();
        lc[t] += u;
        __syncthreads();
    }
    const int node = b * 256 + t;
    if (node < N) texc[node] = lc[t] - v;
    if (t == 255) bsum[b] = lc[255];
}

__global__ __launch_bounds__(256) void k_scan2(int* __restrict__ bsum, int nb)
{
    __shared__ int s[256];
    const int t = threadIdx.x;
    int v = (t < nb) ? bsum[t] : 0;
    s[t] = v;
    __syncthreads();
    for (int off = 1; off < 256; off <<= 1) {
        int u = (t >= off) ? s[t - off] : 0;
        __syncthreads();
        s[t] += u;
        __syncthreads();
    }
    if (t < nb) bsum[t] = s[t] - v;
}

// Fused: rp = texc + bsum[b] (written to global) + in-bucket scatter with LDS cursors.
__global__ __launch_bounds__(256) void k_scan3B(const uint2* __restrict__ tmp, const int* __restrict__ bbase,
                                                const int* __restrict__ texc, const int* __restrict__ bsum,
                                                int* __restrict__ rp, int* __restrict__ col, int N, int E)
{
    __shared__ int curL[256];
    const int b = blockIdx.x, t = threadIdx.x;
    const int node = b * 256 + t;
    int r = 0;
    if (node < N) {
        r = texc[node] + bsum[b];
        rp[node] = r;
    }
    if (node == 0) rp[N] = E;
    curL[t] = r;
    __syncthreads();
    const int beg = bbase[b], end = bbase[b + 1];
    for (int i = beg + t; i < end; i += 256) {
        uint2 e = tmp[i];
        int p = atomicAdd(&curL[e.x & 255], 1);
        col[p] = (int)e.y;
    }
}

// ---------------- Embedding + layer-0 interact (MFMA); A output bf16 ----------------
__global__ __launch_bounds__(256) void k_embed_mfma(
    const float* __restrict__ oneh, const float* __restrict__ pos,
    const uint4* __restrict__ Wf, const float* __restrict__ eb,
    const uint4* __restrict__ iFn, const float* __restrict__ ibn,
    float* __restrict__ x, float* __restrict__ x0,
    unsigned short* __restrict__ Aout, unsigned short* __restrict__ Bout, int N)
{
    __shared__ float ot[32 * 68];
    __shared__ unsigned short xbuf[32 * 72];
    unsigned short* xin = (unsigned short*)ot;   // 32*136 ushorts == 8704 B (aliased)
    const int t = threadIdx.x;
    const int w = t >> 6, l = t & 63;
    const int n0 = blockIdx.x * 32;
    const int nvalid = min(32, N - n0);
    const int validf = nvalid * 118;
    {   // zero xin (covers k padding and invalid nodes)
        uint4* xz = (uint4*)xin;
        for (int i = t; i < 544; i += 256) xz[i] = make_uint4(0, 0, 0, 0);
    }
    __syncthreads();
    {   // flat float4 one-hot load: 32 rows * 118 = 3776 floats, 16B-aligned
        const float4* oh4 = reinterpret_cast<const float4*>(oneh + (size_t)n0 * 118);
        for (int i = t; i < 944; i += 256) {
            int base = i * 4;
            if (base + 4 <= validf) {
                float4 v = oh4[i];
                #pragma unroll
                for (int c = 0; c < 4; ++c) {
                    int li = base + c;
                    int nd = li / 118, kk = li - nd * 118;
                    float vc = (c == 0) ? v.x : (c == 1) ? v.y : (c == 2) ? v.z : v.w;
                    xin[nd * 136 + kk] = (unsigned short)bf16r(vc);
                }
            } else if (base < validf) {
                for (int c = 0; c < 4 && base + c < validf; ++c) {
                    int li = base + c;
                    int nd = li / 118, kk = li - nd * 118;
                    xin[nd * 136 + kk] = (unsigned short)bf16r(oneh[(size_t)n0 * 118 + li]);
                }
            }
        }
        if (t < 96) {
            int nd = t / 3, c = t - nd * 3;
            if (nd < nvalid)
                xin[nd * 136 + 118 + c] = (unsigned short)bf16r(pos[(size_t)(n0 + nd) * 3 + c]);
        }
    }
    __syncthreads();
    const int rt = w & 1, ctb = (w >> 1) * 2;
    U16 af[4];
    #pragma unroll
    for (int kt = 0; kt < 4; ++kt)
        af[kt].u = *reinterpret_cast<const uint4*>(
            &xin[(rt * 16 + (l & 15)) * 136 + kt * 32 + (l >> 4) * 8]);
    f32x4 acc0 = {0.f, 0.f, 0.f, 0.f}, acc1 = {0.f, 0.f, 0.f, 0.f};
    #pragma unroll
    for (int kt = 0; kt < 4; ++kt) {
        U16 b0, b1;
        b0.u = Wf[((ctb + 0) * 4 + kt) * 64 + l];
        b1.u = Wf[((ctb + 1) * 4 + kt) * 64 + l];
        acc0 = __builtin_amdgcn_mfma_f32_16x16x32_bf16(af[kt].b, b0.b, acc0, 0, 0, 0);
        acc1 = __builtin_amdgcn_mfma_f32_16x16x32_bf16(af[kt].b, b1.b, acc1, 0, 0, 0);
    }
    __syncthreads();   // done with xin; reuse as ot
    #pragma unroll
    for (int r = 0; r < 4; ++r) {
        ot[(rt * 16 + (l >> 4) * 4 + r) * 68 + (ctb + 0) * 16 + (l & 15)] = acc0[r];
        ot[(rt * 16 + (l >> 4) * 4 + r) * 68 + (ctb + 1) * 16 + (l & 15)] = acc1[r];
    }
    __syncthreads();
    for (int v = t; v < 512; v += 256) {
        int node = v >> 4, q = v & 15;
        float4 bq = reinterpret_cast<const float4*>(eb)[q];
        float* p = &ot[node * 68 + q * 4];
        float4 o;
        o.x = silu_f(p[0] + bq.x); o.y = silu_f(p[1] + bq.y);
        o.z = silu_f(p[2] + bq.z); o.w = silu_f(p[3] + bq.w);
        int g = n0 + node;
        if (g < N) {
            reinterpret_cast<float4*>(x)[(size_t)g * 16 + q] = o;
            reinterpret_cast<float4*>(x0)[(size_t)g * 16 + q] = o;
        }
        p[0] = o.x; p[1] = o.y; p[2] = o.z; p[3] = o.w;
    }
    __syncthreads();
    {   // pack x rows bf16 into xbuf (stride 72)
        int node = t >> 3, j = t & 7;
        const float* p = &ot[node * 68 + j * 8];
        uint4 o;
        o.x = pack2(p[0], p[1]); o.y = pack2(p[2], p[3]);
        o.z = pack2(p[4], p[5]); o.w = pack2(p[6], p[7]);
        *reinterpret_cast<uint4*>(&xbuf[node * 72 + j * 8]) = o;
    }
    __syncthreads();
    // layer-0 interact: 2 M-tiles, wave w handles ct_A=w and ct_B=w+4
    #pragma unroll
    for (int mt = 0; mt < 2; ++mt) {
        U16 a0, a1, bA0, bA1, bB0, bB1;
        a0.u = *reinterpret_cast<const uint4*>(&xbuf[(mt * 16 + (l & 15)) * 72 + (l >> 4) * 8]);
        a1.u = *reinterpret_cast<const uint4*>(&xbuf[(mt * 16 + (l & 15)) * 72 + 32 + (l >> 4) * 8]);
        bA0.u = iFn[(w * 2 + 0) * 64 + l];
        bA1.u = iFn[(w * 2 + 1) * 64 + l];
        bB0.u = iFn[((w + 4) * 2 + 0) * 64 + l];
        bB1.u = iFn[((w + 4) * 2 + 1) * 64 + l];
        f32x4 accA = {0.f, 0.f, 0.f, 0.f}, accB = {0.f, 0.f, 0.f, 0.f};
        accA = __builtin_amdgcn_mfma_f32_16x16x32_bf16(a0.b, bA0.b, accA, 0, 0, 0);
        accA = __builtin_amdgcn_mfma_f32_16x16x32_bf16(a1.b, bA1.b, accA, 0, 0, 0);
        accB = __builtin_amdgcn_mfma_f32_16x16x32_bf16(a0.b, bB0.b, accB, 0, 0, 0);
        accB = __builtin_amdgcn_mfma_f32_16x16x32_bf16(a1.b, bB1.b, accB, 0, 0, 0);
        const int colA = w * 16 + (l & 15);
        const float biasA = ibn[colA];
        #pragma unroll
        for (int r = 0; r < 4; ++r) {
            int gn = n0 + mt * 16 + (l >> 4) * 4 + r;
            if (gn < N) {
                Aout[(size_t)gn * 64 + colA] = (unsigned short)bf16r(accA[r] + biasA);
                Bout[(size_t)gn * 64 + colA] = (unsigned short)bf16r(accB[r]);
            }
        }
    }
}

// ---------------- Fused edge + MFMA update + next-layer interact (+ final out) ----------------
template <bool LAST>
__global__ __launch_bounds__(256) void k_edge_upd(
    const int* __restrict__ rp, const int* __restrict__ col,
    const unsigned* __restrict__ Ab, const unsigned* __restrict__ Bb,
    float* __restrict__ x,
    const uint4* __restrict__ uFf, const float* __restrict__ ub,
    const uint4* __restrict__ iFn, const float* __restrict__ ibn,
    unsigned short* __restrict__ Aout, unsigned short* __restrict__ Bout,
    const float* __restrict__ x0, const float* __restrict__ oW, const float* __restrict__ ob,
    float* __restrict__ out, int N)
{
    __shared__ unsigned short vb[16 * 72];   // bf16 rows, stride 72
    __shared__ float sv[16 * 68];            // silu(update) rows, stride 68
    const int t = threadIdx.x;
    const int g = t >> 4, q = t & 15;
    const int w = t >> 6, l = t & 63;
    const int node = blockIdx.x * 16 + g;
    const bool valid = node < N;
    const size_t nidx = (size_t)(valid ? node : 0) * 16 + q;
    const uint2* __restrict__ Avb = reinterpret_cast<const uint2*>(Ab);
    const uint2* __restrict__ Bv = reinterpret_cast<const uint2*>(Bb);
    float4* __restrict__ Xv = reinterpret_cast<float4*>(x);

    const float4 a = unpack4(Avb[nidx]);
    const float4 xq = Xv[nidx];
    const int beg = valid ? rp[node] : 0;
    const int end = valid ? rp[node + 1] : 0;

    float4 acc = make_float4(0.f, 0.f, 0.f, 0.f);
    int j = beg;
    for (; j + 4 <= end; j += 4) {
        int d0 = col[j], d1 = col[j + 1], d2 = col[j + 2], d3 = col[j + 3];
        float4 b0 = unpack4(Bv[(size_t)d0 * 16 + q]);
        float4 b1 = unpack4(Bv[(size_t)d1 * 16 + q]);
        float4 b2 = unpack4(Bv[(size_t)d2 * 16 + q]);
        float4 b3 = unpack4(Bv[(size_t)d3 * 16 + q]);
        acc.x += silu_f(a.x + b0.x) + silu_f(a.x + b1.x) + silu_f(a.x + b2.x) + silu_f(a.x + b3.x);
        acc.y += silu_f(a.y + b0.y) + silu_f(a.y + b1.y) + silu_f(a.y + b2.y) + silu_f(a.y + b3.y);
        acc.z += silu_f(a.z + b0.z) + silu_f(a.z + b1.z) + silu_f(a.z + b2.z) + silu_f(a.z + b3.z);
        acc.w += silu_f(a.w + b0.w) + silu_f(a.w + b1.w) + silu_f(a.w + b2.w) + silu_f(a.w + b3.w);
    }
    for (; j < end; ++j) {
        int d = col[j];
        float4 b = unpack4(Bv[(size_t)d * 16 + q]);
        acc.x += silu_f(a.x + b.x); acc.y += silu_f(a.y + b.y);
        acc.z += silu_f(a.z + b.z); acc.w += silu_f(a.w + b.w);
    }
    float4 v;
    v.x = fmaf(0.25f, acc.x, xq.x); v.y = fmaf(0.25f, acc.y, xq.y);
    v.z = fmaf(0.25f, acc.z, xq.z); v.w = fmaf(0.25f, acc.w, xq.w);
    {
        uint2 vo;
        vo.x = pack2(v.x, v.y);
        vo.y = pack2(v.z, v.w);
        *reinterpret_cast<uint2*>(&vb[g * 72 + q * 4]) = vo;
    }
    __syncthreads();
    // update MFMA: A-frag = vb rows, B-frag = uW tile ct=w
    {
        U16 a0, a1, b0, b1;
        a0.u = *reinterpret_cast<const uint4*>(&vb[(l & 15) * 72 + (l >> 4) * 8]);
        a1.u = *reinterpret_cast<const uint4*>(&vb[(l & 15) * 72 + 32 + (l >> 4) * 8]);
        b0.u = uFf[(w * 2 + 0) * 64 + l];
        b1.u = uFf[(w * 2 + 1) * 64 + l];
        f32x4 uacc = {0.f, 0.f, 0.f, 0.f};
        uacc = __builtin_amdgcn_mfma_f32_16x16x32_bf16(a0.b, b0.b, uacc, 0, 0, 0);
        uacc = __builtin_amdgcn_mfma_f32_16x16x32_bf16(a1.b, b1.b, uacc, 0, 0, 0);
        const int h = w * 16 + (l & 15);
        const float ubh = ub[h];
        #pragma unroll
        for (int r = 0; r < 4; ++r)
            sv[((l >> 4) * 4 + r) * 68 + h] = silu_f(uacc[r] + ubh);
    }
    __syncthreads();
    const float4 s = *reinterpret_cast<const float4*>(&sv[g * 68 + q * 4]);
    float4 xn;
    xn.x = xq.x + s.x; xn.y = xq.y + s.y;
    xn.z = xq.z + s.z; xn.w = xq.w + s.w;
    if (valid && !LAST) Xv[nidx] = xn;
    if (!LAST) {
        uint2 xo;
        xo.x = pack2(xn.x, xn.y);
        xo.y = pack2(xn.z, xn.w);
        *reinterpret_cast<uint2*>(&vb[g * 72 + q * 4]) = xo;
        __syncthreads();
        U16 a0, a1, bA0, bA1, bB0, bB1;
        a0.u = *reinterpret_cast<const uint4*>(&vb[(l & 15) * 72 + (l >> 4) * 8]);
        a1.u = *reinterpret_cast<const uint4*>(&vb[(l & 15) * 72 + 32 + (l >> 4) * 8]);
        bA0.u = iFn[(w * 2 + 0) * 64 + l];
        bA1.u = iFn[(w * 2 + 1) * 64 + l];
        bB0.u = iFn[((w + 4) * 2 + 0) * 64 + l];
        bB1.u = iFn[((w + 4) * 2 + 1) * 64 + l];
        f32x4 accA = {0.f, 0.f, 0.f, 0.f}, accB = {0.f, 0.f, 0.f, 0.f};
        accA = __builtin_amdgcn_mfma_f32_16x16x32_bf16(a0.b, bA0.b, accA, 0, 0, 0);
        accA = __builtin_amdgcn_mfma_f32_16x16x32_bf16(a1.b, bA1.b, accA, 0, 0, 0);
        accB = __builtin_amdgcn_mfma_f32_16x16x32_bf16(a0.b, bB0.b, accB, 0, 0, 0);
        accB = __builtin_amdgcn_mfma_f32_16x16x32_bf16(a1.b, bB1.b, accB, 0, 0, 0);
        const int colA = w * 16 + (l & 15);
        const float biasA = ibn[colA];
        #pragma unroll
        for (int r = 0; r < 4; ++r) {
            int gn = blockIdx.x * 16 + (l >> 4) * 4 + r;
            if (gn < N) {
                Aout[(size_t)gn * 64 + colA] = (unsigned short)bf16r(accA[r] + biasA);
                Bout[(size_t)gn * 64 + colA] = (unsigned short)bf16r(accB[r]);
            }
        }
    } else {
        const float4 x0q = reinterpret_cast<const float4*>(x0)[nidx];
        float f0 = xn.x + x0q.x, f1 = xn.y + x0q.y, f2 = xn.z + x0q.z, f3 = xn.w + x0q.w;
        float p0 = 0.f, p1 = 0.f, p2 = 0.f;
        const int k0 = 4 * q;
        p0 = fmaf(f0, oW[(k0 + 0) * 3 + 0], p0); p1 = fmaf(f0, oW[(k0 + 0) * 3 + 1], p1); p2 = fmaf(f0, oW[(k0 + 0) * 3 + 2], p2);
        p0 = fmaf(f1, oW[(k0 + 1) * 3 + 0], p0); p1 = fmaf(f1, oW[(k0 + 1) * 3 + 1], p1); p2 = fmaf(f1, oW[(k0 + 1) * 3 + 2], p2);
        p0 = fmaf(f2, oW[(k0 + 2) * 3 + 0], p0); p1 = fmaf(f2, oW[(k0 + 2) * 3 + 1], p1); p2 = fmaf(f2, oW[(k0 + 2) * 3 + 2], p2);
        p0 = fmaf(f3, oW[(k0 + 3) * 3 + 0], p0); p1 = fmaf(f3, oW[(k0 + 3) * 3 + 1], p1); p2 = fmaf(f3, oW[(k0 + 3) * 3 + 2], p2);
        #pragma unroll
        for (int off = 8; off; off >>= 1) {
            p0 += __shfl_xor(p0, off, 16);
            p1 += __shfl_xor(p1, off, 16);
            p2 += __shfl_xor(p2, off, 16);
        }
        if (valid && q == 0) {
            out[node * 3 + 0] = p0 + ob[0];
            out[node * 3 + 1] = p1 + ob[1];
            out[node * 3 + 2] = p2 + ob[2];
        }
    }
}

extern "C" void kernel_launch(void* const* d_in, const int* in_sizes, int n_in,
                              void* d_out, int out_size, void* d_ws, size_t ws_size,
                              hipStream_t stream)
{
    const float* oneh = (const float*)d_in[0];
    const float* pos  = (const float*)d_in[1];
    const int*   ei   = (const int*)d_in[2];
    const float* embW = (const float*)d_in[3];
    const float* embB = (const float*)d_in[4];
    const float* iW   = (const float*)d_in[5];   // [4][128][64]
    const float* iB   = (const float*)d_in[6];   // [4][64]
    const float* uW   = (const float*)d_in[7];   // [4][64][64]
    const float* uB   = (const float*)d_in[8];   // [4][64]
    const float* oW   = (const float*)d_in[9];   // [64][3]
    const float* oB   = (const float*)d_in[10];  // [3]

    const int N = in_sizes[0] / 118;
    const int E = in_sizes[2] / 2;
    const int* src = ei;
    const int* dst = ei + E;

    float* ws = (float*)d_ws;
    const size_t NH = (size_t)N * H;
    float* x  = ws;
    float* x0 = ws + NH;
    unsigned short* A0   = (unsigned short*)(ws + 2 * NH);   // NH bf16
    unsigned short* A1   = A0 + NH;                           // NH bf16
    unsigned short* Bb0  = A1 + NH;                           // NH bf16
    unsigned short* Bb1  = Bb0 + NH;                          // NH bf16
    unsigned short* embF = Bb1 + NH;                          // 8192
    unsigned short* iF   = embF + 8192;                       // 32768
    unsigned short* uFf  = iF + 32768;                        // 16384
    int* ibase = (int*)(uFf + 16384);
    int* rp    = ibase;               // N+1
    int* col   = ibase + N + 1;       // E
    int* texc  = col + E;             // N
    int* bsum  = texc + N;            // <=256
    int* bbase = bsum + 256;          // NB+1
    int* bcur  = bbase + 257;         // NB
    int* bpart = bcur + 256;          // 128*256
    uint2* tmp = (uint2*)A0;          // aliased: tmp dead before embed writes A0

    const int nbm = (N + 31) / 32;
    const int nbf = (N + 15) / 16;
    const int NB  = (N + 255) / 256;

    // prep (weight pack || bucket partial counts) + CSR build
    k_prep<<<256, 256, 0, stream>>>(embW, iW, uW, embF, iF, uFf, src, bpart, E);
    k_bscan<<<1, 256, 0, stream>>>(bpart, bbase, bcur, NB, E);
    k_bucketA<<<(E + ACHUNK - 1) / ACHUNK, 256, 0, stream>>>(src, dst, bcur, tmp, E);
    k_hist2scan<<<NB, 256, 0, stream>>>(tmp, bbase, texc, bsum, N);
    k_scan2<<<1, 256, 0, stream>>>(bsum, NB);
    k_scan3B<<<NB, 256, 0, stream>>>(tmp, bbase, texc, bsum, rp, col, N, E);

    // embed + layer-0 interact -> A0/Bb0
    k_embed_mfma<<<nbm, 256, 0, stream>>>(oneh, pos, (const uint4*)embF, embB,
                                          (const uint4*)iF, iB, x, x0, A0, Bb0, N);

    unsigned short* Ain[4]  = {A0, A1, A0, A1};
    unsigned short* Aout[4] = {A1, A0, A1, A0};
    unsigned short* Bin[4]  = {Bb0, Bb1, Bb0, Bb1};
    unsigned short* Bout[4] = {Bb1, Bb0, Bb1, Bb0};

    for (int l = 0; l < 4; ++l) {
        const uint4* uFl = (const uint4*)(uFf + (size_t)l * 4096);
        const uint4* iFn = (l < 3) ? (const uint4*)(iF + (size_t)(l + 1) * 8192) : (const uint4*)iF;
        const float* ibn = (l < 3) ? iB + (l + 1) * 64 : iB;
        if (l < 3)
            k_edge_upd<false><<<nbf, 256, 0, stream>>>(rp, col, (const unsigned*)Ain[l], (const unsigned*)Bin[l], x,
                uFl, uB + l * 64, iFn, ibn, Aout[l], Bout[l], x0, oW, oB, (float*)d_out, N);
        else
            k_edge_upd<true><<<nbf, 256, 0, stream>>>(rp, col, (const unsigned*)Ain[l], (const unsigned*)Bin[l], x,
                uFl, uB + l * 64, iFn, ibn, Aout[l], Bout[l], x0, oW, oB, (float*)d_out, N);
    }
}

// Round 12
// 175.494 us; speedup vs baseline: 17.7825x; 1.0722x over previous
//
#include <hip/hip_runtime.h>

#define H 64
#define ACHUNK 4096

typedef __attribute__((ext_vector_type(8))) __bf16 bf16x8;
typedef __attribute__((ext_vector_type(4))) float f32x4;
union U16 { uint4 u; bf16x8 b; };

__device__ __forceinline__ float silu_f(float v) {
    return v * __builtin_amdgcn_rcpf(1.0f + __expf(-v));
}

__device__ __forceinline__ unsigned bf16r(float f) {
    unsigned b = __float_as_uint(f);
    return (b + 0x7fffu + ((b >> 16) & 1u)) >> 16;   // RTNE (inputs finite)
}
__device__ __forceinline__ unsigned pack2(float lo, float hi) {
    return bf16r(lo) | (bf16r(hi) << 16);
}
__device__ __forceinline__ float4 unpack4(uint2 u) {
    float4 r;
    r.x = __uint_as_float(u.x << 16);
    r.y = __uint_as_float(u.x & 0xffff0000u);
    r.z = __uint_as_float(u.y << 16);
    r.w = __uint_as_float(u.y & 0xffff0000u);
    return r;
}

// ---------------- Fused: weight pre-pack (blocks 0-127) + bucket-count partials (128-255) ----------
__global__ __launch_bounds__(256) void k_prep(
    const float* __restrict__ embW, const float* __restrict__ iW, const float* __restrict__ uW,
    unsigned short* __restrict__ embF, unsigned short* __restrict__ iF, unsigned short* __restrict__ uF,
    const int* __restrict__ src, int* __restrict__ bpart, int E)
{
    if (blockIdx.x < 128) {
        int t = blockIdx.x * 256 + threadIdx.x;
        if (t < 8192) {   // embF: ct(4) x kt(4) x lane(64) x e(8); K=128 pad of 121, N=64
            int e = t & 7, l = (t >> 3) & 63, kt = (t >> 9) & 3, ct = (t >> 11) & 3;
            int k = kt * 32 + (l >> 4) * 8 + e;
            int n = ct * 16 + (l & 15);
            float v = (k < 121) ? embW[k * 64 + n] : 0.f;
            embF[t] = (unsigned short)bf16r(v);
        }
        if (t < 16384) {  // uF: layer(4) x ct(4) x kt(2) x lane(64) x e(8)
            int e = t & 7, l = (t >> 3) & 63, kt = (t >> 9) & 1, ct = (t >> 10) & 3, ly = (t >> 12) & 3;
            int k = kt * 32 + (l >> 4) * 8 + e;
            int n = ct * 16 + (l & 15);
            uF[t] = (unsigned short)bf16r(uW[(size_t)ly * 4096 + k * 64 + n]);
        }
        if (t < 32768) {  // iF: layer(4) x ct(8) x kt(2) x lane(64) x e(8); [Wt|Wb]
            int e = t & 7, l = (t >> 3) & 63, kt = (t >> 9) & 1, ct = (t >> 10) & 7, ly = (t >> 13) & 3;
            int k = kt * 32 + (l >> 4) * 8 + e;
            int n = ct * 16 + (l & 15);
            const float* W = iW + (size_t)ly * 128 * 64;
            float v = (n < 64) ? W[k * 64 + n] : W[(64 + k) * 64 + (n - 64)];
            iF[t] = (unsigned short)bf16r(v);
        }
    } else {
        __shared__ int lc[256];
        const int t = threadIdx.x;
        const int blk = blockIdx.x - 128;
        lc[t] = 0;
        __syncthreads();
        for (int e = blk * 256 + t; e < E; e += 128 * 256)
            atomicAdd(&lc[src[e] >> 8], 1);
        __syncthreads();
        bpart[blk * 256 + t] = lc[t];
    }
}

// reduce bpart -> exclusive bucket bases
__global__ __launch_bounds__(256) void k_bscan(const int* __restrict__ bpart,
                                               int* __restrict__ bbase, int* __restrict__ bcur,
                                               int NB, int E)
{
    __shared__ int s[256];
    const int t = threadIdx.x;
    int v = 0;
    for (int b = 0; b < 128; ++b) v += bpart[b * 256 + t];
    s[t] = v;
    __syncthreads();
    for (int off = 1; off < 256; off <<= 1) {
        int u = (t >= off) ? s[t - off] : 0;
        __syncthreads();
        s[t] += u;
        __syncthreads();
    }
    if (t < NB) {
        int ex = s[t] - v;
        bbase[t] = ex;
        bcur[t] = ex;
    }
    if (t == 0) bbase[NB] = E;
}

// Stage ACHUNK edges in LDS grouped by bucket; write each group contiguously.
__global__ __launch_bounds__(256) void k_bucketA(const int* __restrict__ src, const int* __restrict__ dst,
                                                 int* __restrict__ bcur, uint2* __restrict__ tmp, int E)
{
    __shared__ int lscan[256], lrun[256], gbase[256];
    __shared__ uint2 stage[ACHUNK];
    const int t = threadIdx.x;
    const int c0 = blockIdx.x * ACHUNK;
    const int cend = min(c0 + ACHUNK, E);
    const int n = cend - c0;
    lscan[t] = 0;
    __syncthreads();
    for (int i = c0 + t; i < cend; i += 256)
        atomicAdd(&lscan[src[i] >> 8], 1);
    __syncthreads();
    int v = lscan[t];
    __syncthreads();
    lscan[t] = v;
    __syncthreads();
    for (int off = 1; off < 256; off <<= 1) {
        int u = (t >= off) ? lscan[t - off] : 0;
        __syncthreads();
        lscan[t] += u;
        __syncthreads();
    }
    int ex = lscan[t] - v;
    lscan[t] = ex;
    lrun[t] = ex;
    if (v > 0) gbase[t] = atomicAdd(&bcur[t], v);
    __syncthreads();
    for (int i = c0 + t; i < cend; i += 256) {
        int s_ = src[i];
        int b = s_ >> 8;
        int p = atomicAdd(&lrun[b], 1);
        stage[p] = make_uint2((unsigned)s_, (unsigned)dst[i]);
    }
    __syncthreads();
    for (int i = t; i < n; i += 256) {
        uint2 e = stage[i];
        int b = (int)(e.x >> 8);
        tmp[gbase[b] + i - lscan[b]] = e;
    }
}

// ---------------- Fused CSR finalize (blocks 0..NB-1) + embed/layer-0 interact (blocks NB..) ----
struct SmemEmbed {
    float ot[32 * 68];                 // 8704 B (aliased with xin)
    unsigned short xbuf[32 * 72];      // 4608 B
};
struct SmemCsr { int lc[256]; int curL[256]; };
union SmemU { SmemEmbed e; SmemCsr c; };

__global__ __launch_bounds__(256) void k_csr_embed(
    // csr part
    const uint2* __restrict__ tmp, const int* __restrict__ bbase,
    int* __restrict__ rp, int* __restrict__ col, int NB, int E,
    // embed part
    const float* __restrict__ oneh, const float* __restrict__ pos,
    const uint4* __restrict__ Wf, const float* __restrict__ eb,
    const uint4* __restrict__ iFn, const float* __restrict__ ibn,
    float* __restrict__ x, float* __restrict__ x0,
    unsigned short* __restrict__ Aout, unsigned short* __restrict__ Bout, int N)
{
    __shared__ SmemU sm;
    const int t = threadIdx.x;
    if ((int)blockIdx.x < NB) {
        // ---- CSR: per-bucket hist + scan + rp + scatter (bucket-local => global offsets) ----
        int* lc = sm.c.lc;
        int* curL = sm.c.curL;
        const int b = blockIdx.x;
        lc[t] = 0;
        __syncthreads();
        const int beg = bbase[b], end = bbase[b + 1];
        for (int i = beg + t; i < end; i += 256)
            atomicAdd(&lc[tmp[i].x & 255], 1);
        __syncthreads();
        int v = lc[t];
        __syncthreads();
        for (int off = 1; off < 256; off <<= 1) {
            int u = (t >= off) ? lc[t - off] : 0;
            __syncthreads();
            lc[t] += u;
            __syncthreads();
        }
        const int r = beg + lc[t] - v;   // global CSR offset for node b*256+t
        const int node = b * 256 + t;
        if (node < N) rp[node] = r;
        if (node == 0) rp[N] = E;
        curL[t] = r;
        __syncthreads();
        for (int i = beg + t; i < end; i += 256) {
            uint2 e = tmp[i];
            int p = atomicAdd(&curL[e.x & 255], 1);
            col[p] = (int)e.y;
        }
        return;
    }
    // ---- embed + layer-0 interact ----
    float* ot = sm.e.ot;
    unsigned short* xbuf = sm.e.xbuf;
    unsigned short* xin = (unsigned short*)ot;   // 32*136 ushorts == 8704 B
    const int w = t >> 6, l = t & 63;
    const int n0 = ((int)blockIdx.x - NB) * 32;
    const int nvalid = min(32, N - n0);
    const int validf = nvalid * 118;
    {
        uint4* xz = (uint4*)xin;
        for (int i = t; i < 544; i += 256) xz[i] = make_uint4(0, 0, 0, 0);
    }
    __syncthreads();
    {
        const float4* oh4 = reinterpret_cast<const float4*>(oneh + (size_t)n0 * 118);
        for (int i = t; i < 944; i += 256) {
            int base = i * 4;
            if (base + 4 <= validf) {
                float4 v = oh4[i];
                #pragma unroll
                for (int c = 0; c < 4; ++c) {
                    int li = base + c;
                    int nd = li / 118, kk = li - nd * 118;
                    float vc = (c == 0) ? v.x : (c == 1) ? v.y : (c == 2) ? v.z : v.w;
                    xin[nd * 136 + kk] = (unsigned short)bf16r(vc);
                }
            } else if (base < validf) {
                for (int c = 0; c < 4 && base + c < validf; ++c) {
                    int li = base + c;
                    int nd = li / 118, kk = li - nd * 118;
                    xin[nd * 136 + kk] = (unsigned short)bf16r(oneh[(size_t)n0 * 118 + li]);
                }
            }
        }
        if (t < 96) {
            int nd = t / 3, c = t - nd * 3;
            if (nd < nvalid)
                xin[nd * 136 + 118 + c] = (unsigned short)bf16r(pos[(size_t)(n0 + nd) * 3 + c]);
        }
    }
    __syncthreads();
    const int rt = w & 1, ctb = (w >> 1) * 2;
    U16 af[4];
    #pragma unroll
    for (int kt = 0; kt < 4; ++kt)
        af[kt].u = *reinterpret_cast<const uint4*>(
            &xin[(rt * 16 + (l & 15)) * 136 + kt * 32 + (l >> 4) * 8]);
    f32x4 acc0 = {0.f, 0.f, 0.f, 0.f}, acc1 = {0.f, 0.f, 0.f, 0.f};
    #pragma unroll
    for (int kt = 0; kt < 4; ++kt) {
        U16 b0, b1;
        b0.u = Wf[((ctb + 0) * 4 + kt) * 64 + l];
        b1.u = Wf[((ctb + 1) * 4 + kt) * 64 + l];
        acc0 = __builtin_amdgcn_mfma_f32_16x16x32_bf16(af[kt].b, b0.b, acc0, 0, 0, 0);
        acc1 = __builtin_amdgcn_mfma_f32_16x16x32_bf16(af[kt].b, b1.b, acc1, 0, 0, 0);
    }
    __syncthreads();   // done with xin; reuse as ot
    #pragma unroll
    for (int r = 0; r < 4; ++r) {
        ot[(rt * 16 + (l >> 4) * 4 + r) * 68 + (ctb + 0) * 16 + (l & 15)] = acc0[r];
        ot[(rt * 16 + (l >> 4) * 4 + r) * 68 + (ctb + 1) * 16 + (l & 15)] = acc1[r];
    }
    __syncthreads();
    for (int v = t; v < 512; v += 256) {
        int node = v >> 4, q = v & 15;
        float4 bq = reinterpret_cast<const float4*>(eb)[q];
        float* p = &ot[node * 68 + q * 4];
        float4 o;
        o.x = silu_f(p[0] + bq.x); o.y = silu_f(p[1] + bq.y);
        o.z = silu_f(p[2] + bq.z); o.w = silu_f(p[3] + bq.w);
        int g = n0 + node;
        if (g < N) {
            reinterpret_cast<float4*>(x)[(size_t)g * 16 + q] = o;
            reinterpret_cast<float4*>(x0)[(size_t)g * 16 + q] = o;
        }
        p[0] = o.x; p[1] = o.y; p[2] = o.z; p[3] = o.w;
    }
    __syncthreads();
    {
        int node = t >> 3, j = t & 7;
        const float* p = &ot[node * 68 + j * 8];
        uint4 o;
        o.x = pack2(p[0], p[1]); o.y = pack2(p[2], p[3]);
        o.z = pack2(p[4], p[5]); o.w = pack2(p[6], p[7]);
        *reinterpret_cast<uint4*>(&xbuf[node * 72 + j * 8]) = o;
    }
    __syncthreads();
    #pragma unroll
    for (int mt = 0; mt < 2; ++mt) {
        U16 a0, a1, bA0, bA1, bB0, bB1;
        a0.u = *reinterpret_cast<const uint4*>(&xbuf[(mt * 16 + (l & 15)) * 72 + (l >> 4) * 8]);
        a1.u = *reinterpret_cast<const uint4*>(&xbuf[(mt * 16 + (l & 15)) * 72 + 32 + (l >> 4) * 8]);
        bA0.u = iFn[(w * 2 + 0) * 64 + l];
        bA1.u = iFn[(w * 2 + 1) * 64 + l];
        bB0.u = iFn[((w + 4) * 2 + 0) * 64 + l];
        bB1.u = iFn[((w + 4) * 2 + 1) * 64 + l];
        f32x4 accA = {0.f, 0.f, 0.f, 0.f}, accB = {0.f, 0.f, 0.f, 0.f};
        accA = __builtin_amdgcn_mfma_f32_16x16x32_bf16(a0.b, bA0.b, accA, 0, 0, 0);
        accA = __builtin_amdgcn_mfma_f32_16x16x32_bf16(a1.b, bA1.b, accA, 0, 0, 0);
        accB = __builtin_amdgcn_mfma_f32_16x16x32_bf16(a0.b, bB0.b, accB, 0, 0, 0);
        accB = __builtin_amdgcn_mfma_f32_16x16x32_bf16(a1.b, bB1.b, accB, 0, 0, 0);
        const int colA = w * 16 + (l & 15);
        const float biasA = ibn[colA];
        #pragma unroll
        for (int r = 0; r < 4; ++r) {
            int gn = n0 + mt * 16 + (l >> 4) * 4 + r;
            if (gn < N) {
                Aout[(size_t)gn * 64 + colA] = (unsigned short)bf16r(accA[r] + biasA);
                Bout[(size_t)gn * 64 + colA] = (unsigned short)bf16r(accB[r]);
            }
        }
    }
}

// ---------------- Fused edge + MFMA update + next-layer interact (+ final out) ----------------
template <bool LAST>
__global__ __launch_bounds__(256) void k_edge_upd(
    const int* __restrict__ rp, const int* __restrict__ col,
    const unsigned* __restrict__ Ab, const unsigned* __restrict__ Bb,
    float* __restrict__ x,
    const uint4* __restrict__ uFf, const float* __restrict__ ub,
    const uint4* __restrict__ iFn, const float* __restrict__ ibn,
    unsigned short* __restrict__ Aout, unsigned short* __restrict__ Bout,
    const float* __restrict__ x0, const float* __restrict__ oW, const float* __restrict__ ob,
    float* __restrict__ out, int N)
{
    __shared__ unsigned short vb[16 * 72];   // bf16 rows, stride 72
    __shared__ float sv[16 * 68];            // silu(update) rows, stride 68
    const int t = threadIdx.x;
    const int g = t >> 4, q = t & 15;
    const int w = t >> 6, l = t & 63;
    const int node = blockIdx.x * 16 + g;
    const bool valid = node < N;
    const size_t nidx = (size_t)(valid ? node : 0) * 16 + q;
    const uint2* __restrict__ Avb = reinterpret_cast<const uint2*>(Ab);
    const uint2* __restrict__ Bv = reinterpret_cast<const uint2*>(Bb);
    float4* __restrict__ Xv = reinterpret_cast<float4*>(x);

    const float4 a = unpack4(Avb[nidx]);
    const float4 xq = Xv[nidx];
    const int beg = valid ? rp[node] : 0;
    const int end = valid ? rp[node + 1] : 0;

    float4 acc = make_float4(0.f, 0.f, 0.f, 0.f);
    int j = beg;
    for (; j + 4 <= end; j += 4) {
        int d0 = col[j], d1 = col[j + 1], d2 = col[j + 2], d3 = col[j + 3];
        float4 b0 = unpack4(Bv[(size_t)d0 * 16 + q]);
        float4 b1 = unpack4(Bv[(size_t)d1 * 16 + q]);
        float4 b2 = unpack4(Bv[(size_t)d2 * 16 + q]);
        float4 b3 = unpack4(Bv[(size_t)d3 * 16 + q]);
        acc.x += silu_f(a.x + b0.x) + silu_f(a.x + b1.x) + silu_f(a.x + b2.x) + silu_f(a.x + b3.x);
        acc.y += silu_f(a.y + b0.y) + silu_f(a.y + b1.y) + silu_f(a.y + b2.y) + silu_f(a.y + b3.y);
        acc.z += silu_f(a.z + b0.z) + silu_f(a.z + b1.z) + silu_f(a.z + b2.z) + silu_f(a.z + b3.z);
        acc.w += silu_f(a.w + b0.w) + silu_f(a.w + b1.w) + silu_f(a.w + b2.w) + silu_f(a.w + b3.w);
    }
    for (; j < end; ++j) {
        int d = col[j];
        float4 b = unpack4(Bv[(size_t)d * 16 + q]);
        acc.x += silu_f(a.x + b.x); acc.y += silu_f(a.y + b.y);
        acc.z += silu_f(a.z + b.z); acc.w += silu_f(a.w + b.w);
    }
    float4 v;
    v.x = fmaf(0.25f, acc.x, xq.x); v.y = fmaf(0.25f, acc.y, xq.y);
    v.z = fmaf(0.25f, acc.z, xq.z); v.w = fmaf(0.25f, acc.w, xq.w);
    {
        uint2 vo;
        vo.x = pack2(v.x, v.y);
        vo.y = pack2(v.z, v.w);
        *reinterpret_cast<uint2*>(&vb[g * 72 + q * 4]) = vo;
    }
    __syncthreads();
    {
        U16 a0, a1, b0, b1;
        a0.u = *reinterpret_cast<const uint4*>(&vb[(l & 15) * 72 + (l >> 4) * 8]);
        a1.u = *reinterpret_cast<const uint4*>(&vb[(l & 15) * 72 + 32 + (l >> 4) * 8]);
        b0.u = uFf[(w * 2 + 0) * 64 + l];
        b1.u = uFf[(w * 2 + 1) * 64 + l];
        f32x4 uacc = {0.f, 0.f, 0.f, 0.f};
        uacc = __builtin_amdgcn_mfma_f32_16x16x32_bf16(a0.b, b0.b, uacc, 0, 0, 0);
        uacc = __builtin_amdgcn_mfma_f32_16x16x32_bf16(a1.b, b1.b, uacc, 0, 0, 0);
        const int h = w * 16 + (l & 15);
        const float ubh = ub[h];
        #pragma unroll
        for (int r = 0; r < 4; ++r)
            sv[((l >> 4) * 4 + r) * 68 + h] = silu_f(uacc[r] + ubh);
    }
    __syncthreads();
    const float4 s = *reinterpret_cast<const float4*>(&sv[g * 68 + q * 4]);
    float4 xn;
    xn.x = xq.x + s.x; xn.y = xq.y + s.y;
    xn.z = xq.z + s.z; xn.w = xq.w + s.w;
    if (valid && !LAST) Xv[nidx] = xn;
    if (!LAST) {
        uint2 xo;
        xo.x = pack2(xn.x, xn.y);
        xo.y = pack2(xn.z, xn.w);
        *reinterpret_cast<uint2*>(&vb[g * 72 + q * 4]) = xo;
        __syncthreads();
        U16 a0, a1, bA0, bA1, bB0, bB1;
        a0.u = *reinterpret_cast<const uint4*>(&vb[(l & 15) * 72 + (l >> 4) * 8]);
        a1.u = *reinterpret_cast<const uint4*>(&vb[(l & 15) * 72 + 32 + (l >> 4) * 8]);
        bA0.u = iFn[(w * 2 + 0) * 64 + l];
        bA1.u = iFn[(w * 2 + 1) * 64 + l];
        bB0.u = iFn[((w + 4) * 2 + 0) * 64 + l];
        bB1.u = iFn[((w + 4) * 2 + 1) * 64 + l];
        f32x4 accA = {0.f, 0.f, 0.f, 0.f}, accB = {0.f, 0.f, 0.f, 0.f};
        accA = __builtin_amdgcn_mfma_f32_16x16x32_bf16(a0.b, bA0.b, accA, 0, 0, 0);
        accA = __builtin_amdgcn_mfma_f32_16x16x32_bf16(a1.b, bA1.b, accA, 0, 0, 0);
        accB = __builtin_amdgcn_mfma_f32_16x16x32_bf16(a0.b, bB0.b, accB, 0, 0, 0);
        accB = __builtin_amdgcn_mfma_f32_16x16x32_bf16(a1.b, bB1.b, accB, 0, 0, 0);
        const int colA = w * 16 + (l & 15);
        const float biasA = ibn[colA];
        #pragma unroll
        for (int r = 0; r < 4; ++r) {
            int gn = blockIdx.x * 16 + (l >> 4) * 4 + r;
            if (gn < N) {
                Aout[(size_t)gn * 64 + colA] = (unsigned short)bf16r(accA[r] + biasA);
                Bout[(size_t)gn * 64 + colA] = (unsigned short)bf16r(accB[r]);
            }
        }
    } else {
        const float4 x0q = reinterpret_cast<const float4*>(x0)[nidx];
        float f0 = xn.x + x0q.x, f1 = xn.y + x0q.y, f2 = xn.z + x0q.z, f3 = xn.w + x0q.w;
        float p0 = 0.f, p1 = 0.f, p2 = 0.f;
        const int k0 = 4 * q;
        p0 = fmaf(f0, oW[(k0 + 0) * 3 + 0], p0); p1 = fmaf(f0, oW[(k0 + 0) * 3 + 1], p1); p2 = fmaf(f0, oW[(k0 + 0) * 3 + 2], p2);
        p0 = fmaf(f1, oW[(k0 + 1) * 3 + 0], p0); p1 = fmaf(f1, oW[(k0 + 1) * 3 + 1], p1); p2 = fmaf(f1, oW[(k0 + 1) * 3 + 2], p2);
        p0 = fmaf(f2, oW[(k0 + 2) * 3 + 0], p0); p1 = fmaf(f2, oW[(k0 + 2) * 3 + 1], p1); p2 = fmaf(f2, oW[(k0 + 2) * 3 + 2], p2);
        p0 = fmaf(f3, oW[(k0 + 3) * 3 + 0], p0); p1 = fmaf(f3, oW[(k0 + 3) * 3 + 1], p1); p2 = fmaf(f3, oW[(k0 + 3) * 3 + 2], p2);
        #pragma unroll
        for (int off = 8; off; off >>= 1) {
            p0 += __shfl_xor(p0, off, 16);
            p1 += __shfl_xor(p1, off, 16);
            p2 += __shfl_xor(p2, off, 16);
        }
        if (valid && q == 0) {
            out[node * 3 + 0] = p0 + ob[0];
            out[node * 3 + 1] = p1 + ob[1];
            out[node * 3 + 2] = p2 + ob[2];
        }
    }
}

extern "C" void kernel_launch(void* const* d_in, const int* in_sizes, int n_in,
                              void* d_out, int out_size, void* d_ws, size_t ws_size,
                              hipStream_t stream)
{
    const float* oneh = (const float*)d_in[0];
    const float* pos  = (const float*)d_in[1];
    const int*   ei   = (const int*)d_in[2];
    const float* embW = (const float*)d_in[3];
    const float* embB = (const float*)d_in[4];
    const float* iW   = (const float*)d_in[5];   // [4][128][64]
    const float* iB   = (const float*)d_in[6];   // [4][64]
    const float* uW   = (const float*)d_in[7];   // [4][64][64]
    const float* uB   = (const float*)d_in[8];   // [4][64]
    const float* oW   = (const float*)d_in[9];   // [64][3]
    const float* oB   = (const float*)d_in[10];  // [3]

    const int N = in_sizes[0] / 118;
    const int E = in_sizes[2] / 2;
    const int* src = ei;
    const int* dst = ei + E;

    float* ws = (float*)d_ws;
    const size_t NH = (size_t)N * H;
    float* x  = ws;
    float* x0 = ws + NH;
    unsigned short* A0   = (unsigned short*)(ws + 2 * NH);   // NH bf16
    unsigned short* A1   = A0 + NH;                           // NH bf16
    unsigned short* Bb0  = A1 + NH;                           // NH bf16
    unsigned short* Bb1  = Bb0 + NH;                          // NH bf16
    unsigned short* embF = Bb1 + NH;                          // 8192
    unsigned short* iF   = embF + 8192;                       // 32768
    unsigned short* uFf  = iF + 32768;                        // 16384
    int* ibase = (int*)(uFf + 16384);
    int* rp    = ibase;               // N+1
    int* col   = ibase + N + 1;       // E
    int* bbase = col + E;             // NB+1
    int* bcur  = bbase + 257;         // NB
    int* bpart = bcur + 256;          // 128*256
    uint2* tmp = (uint2*)(bpart + 128 * 256);  // E (own buffer: embed runs concurrently)

    const int nbm = (N + 31) / 32;
    const int nbf = (N + 15) / 16;
    const int NB  = (N + 255) / 256;

    // prep (weight pack || bucket partial counts) -> bucket bases -> bucketize
    k_prep<<<256, 256, 0, stream>>>(embW, iW, uW, embF, iF, uFf, src, bpart, E);
    k_bscan<<<1, 256, 0, stream>>>(bpart, bbase, bcur, NB, E);
    k_bucketA<<<(E + ACHUNK - 1) / ACHUNK, 256, 0, stream>>>(src, dst, bcur, tmp, E);
    // CSR finalize (bucket-local scan gives global offsets) || embed + layer-0 interact
    k_csr_embed<<<NB + nbm, 256, 0, stream>>>(tmp, bbase, rp, col, NB, E,
                                              oneh, pos, (const uint4*)embF, embB,
                                              (const uint4*)iF, iB, x, x0, A0, Bb0, N);

    unsigned short* Ain[4]  = {A0, A1, A0, A1};
    unsigned short* Aout[4] = {A1, A0, A1, A0};
    unsigned short* Bin[4]  = {Bb0, Bb1, Bb0, Bb1};
    unsigned short* Bout[4] = {Bb1, Bb0, Bb1, Bb0};

    for (int l = 0; l < 4; ++l) {
        const uint4* uFl = (const uint4*)(uFf + (size_t)l * 4096);
        const uint4* iFn = (l < 3) ? (const uint4*)(iF + (size_t)(l + 1) * 8192) : (const uint4*)iF;
        const float* ibn = (l < 3) ? iB + (l + 1) * 64 : iB;
        if (l < 3)
            k_edge_upd<false><<<nbf, 256, 0, stream>>>(rp, col, (const unsigned*)Ain[l], (const unsigned*)Bin[l], x,
                uFl, uB + l * 64, iFn, ibn, Aout[l], Bout[l], x0, oW, oB, (float*)d_out, N);
        else
            k_edge_upd<true><<<nbf, 256, 0, stream>>>(rp, col, (const unsigned*)Ain[l], (const unsigned*)Bin[l], x,
                uFl, uB + l * 64, iFn, ibn, Aout[l], Bout[l], x0, oW, oB, (float*)d_out, N);
    }
}